// Round 1
// baseline (1868.375 us; speedup 1.0000x reference)
//
#include <hip/hip_runtime.h>
#include <hip/hip_bf16.h>
#include <math.h>

#define D 128
#define H 8
#define DH 16

// ---------------- helpers ----------------

__device__ __forceinline__ void atomicMaxFloat(float* addr, float val) {
    // bit-trick: int max for >=0, unsigned min for <0 (works with -inf init)
    if (val >= 0.0f) {
        atomicMax((int*)addr, __float_as_int(val));
    } else {
        atomicMin((unsigned int*)addr, __float_as_uint(val));
    }
}

// ---------------- K0: init ----------------

__global__ __launch_bounds__(256) void init_kernel(float* __restrict__ agg,
                                                   float* __restrict__ m,
                                                   float* __restrict__ denom,
                                                   int n_nodes) {
    int gid = blockIdx.x * blockDim.x + threadIdx.x;
    int total = n_nodes * D;
    if (gid < total) agg[gid] = 0.0f;
    if (gid < n_nodes * H) {
        m[gid] = -INFINITY;
        denom[gid] = 0.0f;
    }
}

// ---------------- K1: QKV GEMM ----------------
// block: 256 threads, 64 rows x 128 cols, K=128 in chunks of 32.
// thread t: cg=t&31 -> cols 4*cg..4*cg+3 ; rg=t>>5 -> rows rg+8*ri (ri 0..7)

__global__ __launch_bounds__(256) void qkv_kernel(
    const float* __restrict__ x,
    const float* __restrict__ Wq, const float* __restrict__ bq,
    const float* __restrict__ Wk, const float* __restrict__ bk,
    const float* __restrict__ Wv, const float* __restrict__ bv,
    float* __restrict__ q, float* __restrict__ k, float* __restrict__ v,
    int n_rows)
{
    __shared__ __align__(16) float xs[64][D];
    __shared__ __align__(16) float wsh[32][D];
    const int t = threadIdx.x;
    const int block_row = blockIdx.x * 64;
    const int cg = t & 31, rg = t >> 5;
    const int col = cg * 4;

    // load x tile (64x128): 2048 float4s, 8 per thread
    {
        const float4* xg = (const float4*)x;
        #pragma unroll
        for (int it = 0; it < 8; ++it) {
            int f4 = t + it * 256;
            int r = f4 >> 5, c4 = f4 & 31;
            int gr = block_row + r;
            float4 val = (gr < n_rows) ? xg[(size_t)gr * 32 + c4]
                                       : make_float4(0.f, 0.f, 0.f, 0.f);
            *((float4*)&xs[r][c4 * 4]) = val;
        }
    }

    const float* Ws[3] = {Wq, Wk, Wv};
    const float* Bs[3] = {bq, bk, bv};
    float* Os[3] = {q, k, v};

    #pragma unroll
    for (int mat = 0; mat < 3; ++mat) {
        float acc[8][4];
        #pragma unroll
        for (int i = 0; i < 8; ++i)
            #pragma unroll
            for (int j = 0; j < 4; ++j) acc[i][j] = 0.f;

        for (int kk = 0; kk < D; kk += 32) {
            __syncthreads();
            // load W chunk (32x128): 1024 float4s, 4 per thread
            const float4* wg = (const float4*)(Ws[mat] + (size_t)kk * D);
            #pragma unroll
            for (int it = 0; it < 4; ++it) {
                int f4 = t + it * 256;
                int r = f4 >> 5, c4 = f4 & 31;
                *((float4*)&wsh[r][c4 * 4]) = wg[f4];
            }
            __syncthreads();
            #pragma unroll
            for (int k4 = 0; k4 < 32; k4 += 4) {
                float4 w0 = *((const float4*)&wsh[k4 + 0][col]);
                float4 w1 = *((const float4*)&wsh[k4 + 1][col]);
                float4 w2 = *((const float4*)&wsh[k4 + 2][col]);
                float4 w3 = *((const float4*)&wsh[k4 + 3][col]);
                #pragma unroll
                for (int ri = 0; ri < 8; ++ri) {
                    int r = rg + ri * 8;
                    float4 xv = *((const float4*)&xs[r][kk + k4]);
                    acc[ri][0] += xv.x * w0.x + xv.y * w1.x + xv.z * w2.x + xv.w * w3.x;
                    acc[ri][1] += xv.x * w0.y + xv.y * w1.y + xv.z * w2.y + xv.w * w3.y;
                    acc[ri][2] += xv.x * w0.z + xv.y * w1.z + xv.z * w2.z + xv.w * w3.z;
                    acc[ri][3] += xv.x * w0.w + xv.y * w1.w + xv.z * w2.w + xv.w * w3.w;
                }
            }
        }
        float4 bias = *((const float4*)&Bs[mat][col]);
        #pragma unroll
        for (int ri = 0; ri < 8; ++ri) {
            int gr = block_row + rg + ri * 8;
            if (gr < n_rows) {
                float4 o;
                o.x = acc[ri][0] + bias.x;
                o.y = acc[ri][1] + bias.y;
                o.z = acc[ri][2] + bias.z;
                o.w = acc[ri][3] + bias.w;
                *((float4*)&Os[mat][(size_t)gr * D + col]) = o;
            }
        }
    }
}

// ---------------- K2: edge scores + segment max ----------------
// 32 lanes per edge; lane L reads floats 4L..4L+3 (head = L/4)

__global__ __launch_bounds__(256) void edge_score_kernel(
    const float* __restrict__ q, const float* __restrict__ k,
    const int* __restrict__ idx_i, const int* __restrict__ idx_j,
    float* __restrict__ e, float* __restrict__ m, int n_edges)
{
    int lane = threadIdx.x & 31;
    int edge = (blockIdx.x * blockDim.x + threadIdx.x) >> 5;
    if (edge >= n_edges) return;
    int i = idx_i[edge], j = idx_j[edge];
    float4 qv = *((const float4*)&q[(size_t)i * D + lane * 4]);
    float4 kv = *((const float4*)&k[(size_t)j * D + lane * 4]);
    float d = qv.x * kv.x + qv.y * kv.y + qv.z * kv.z + qv.w * kv.w;
    d += __shfl_xor(d, 1);
    d += __shfl_xor(d, 2);
    if ((lane & 3) == 0) {
        int h = lane >> 2;
        float score = d * 0.25f;   // 1/sqrt(16)
        e[(size_t)edge * H + h] = score;
        atomicMaxFloat(&m[(size_t)i * H + h], score);
    }
}

// ---------------- K3: a = exp(e - m[i]); denom += a ----------------

__global__ __launch_bounds__(256) void exp_kernel(
    float* __restrict__ e, const int* __restrict__ idx_i,
    const float* __restrict__ m, float* __restrict__ denom, int total)
{
    int gid = blockIdx.x * blockDim.x + threadIdx.x;
    if (gid >= total) return;
    int edge = gid >> 3, h = gid & 7;
    int i = idx_i[edge];
    float a = __expf(e[gid] - m[(size_t)i * H + h]);
    e[gid] = a;
    atomicAdd(&denom[(size_t)i * H + h], a);
}

// ---------------- K4: agg[i] += a * v[j] (unnormalized) ----------------

__global__ __launch_bounds__(256) void agg_kernel(
    const float* __restrict__ a, const float* __restrict__ v,
    const int* __restrict__ idx_i, const int* __restrict__ idx_j,
    float* __restrict__ agg, int n_edges)
{
    int lane = threadIdx.x & 31;
    int edge = (blockIdx.x * blockDim.x + threadIdx.x) >> 5;
    if (edge >= n_edges) return;
    int i = idx_i[edge], j = idx_j[edge];
    int h = lane >> 2;
    float w = a[(size_t)edge * H + h];
    float4 vv = *((const float4*)&v[(size_t)j * D + lane * 4]);
    float* dst = &agg[(size_t)i * D + lane * 4];
    atomicAdd(dst + 0, w * vv.x);
    atomicAdd(dst + 1, w * vv.y);
    atomicAdd(dst + 2, w * vv.z);
    atomicAdd(dst + 3, w * vv.w);
}

// ---------------- K5: x1 = (agg/denom)@Wo + bo ; h = LN(x + x1) ----------------

__global__ __launch_bounds__(256) void oproj_ln_kernel(
    const float* __restrict__ agg, const float* __restrict__ denom,
    const float* __restrict__ x,
    const float* __restrict__ Wo, const float* __restrict__ bo,
    const float* __restrict__ g1, const float* __restrict__ be1,
    float* __restrict__ hout, int n_rows)
{
    __shared__ __align__(16) float xs[64][D];
    __shared__ __align__(16) float wsh[32][D];
    const int t = threadIdx.x;
    const int block_row = blockIdx.x * 64;
    const int cg = t & 31, rg = t >> 5;
    const int col = cg * 4;

    // load (agg/denom) tile
    {
        const float4* ag = (const float4*)agg;
        #pragma unroll
        for (int it = 0; it < 8; ++it) {
            int f4 = t + it * 256;
            int r = f4 >> 5, c4 = f4 & 31;
            int gr = block_row + r;
            float4 val = make_float4(0.f, 0.f, 0.f, 0.f);
            if (gr < n_rows) {
                int head = c4 >> 2;   // 4 cols all within one 16-col head
                float dn = denom[(size_t)gr * H + head];
                float s = (dn > 0.f) ? (1.0f / dn) : 0.f;
                float4 a4 = ag[(size_t)gr * 32 + c4];
                val = make_float4(a4.x * s, a4.y * s, a4.z * s, a4.w * s);
            }
            *((float4*)&xs[r][c4 * 4]) = val;
        }
    }

    float acc[8][4];
    #pragma unroll
    for (int i = 0; i < 8; ++i)
        #pragma unroll
        for (int j = 0; j < 4; ++j) acc[i][j] = 0.f;

    for (int kk = 0; kk < D; kk += 32) {
        __syncthreads();
        const float4* wg = (const float4*)(Wo + (size_t)kk * D);
        #pragma unroll
        for (int it = 0; it < 4; ++it) {
            int f4 = t + it * 256;
            int r = f4 >> 5, c4 = f4 & 31;
            *((float4*)&wsh[r][c4 * 4]) = wg[f4];
        }
        __syncthreads();
        #pragma unroll
        for (int k4 = 0; k4 < 32; k4 += 4) {
            float4 w0 = *((const float4*)&wsh[k4 + 0][col]);
            float4 w1 = *((const float4*)&wsh[k4 + 1][col]);
            float4 w2 = *((const float4*)&wsh[k4 + 2][col]);
            float4 w3 = *((const float4*)&wsh[k4 + 3][col]);
            #pragma unroll
            for (int ri = 0; ri < 8; ++ri) {
                int r = rg + ri * 8;
                float4 xv = *((const float4*)&xs[r][kk + k4]);
                acc[ri][0] += xv.x * w0.x + xv.y * w1.x + xv.z * w2.x + xv.w * w3.x;
                acc[ri][1] += xv.x * w0.y + xv.y * w1.y + xv.z * w2.y + xv.w * w3.y;
                acc[ri][2] += xv.x * w0.z + xv.y * w1.z + xv.z * w2.z + xv.w * w3.z;
                acc[ri][3] += xv.x * w0.w + xv.y * w1.w + xv.z * w2.w + xv.w * w3.w;
            }
        }
    }

    float4 bias = *((const float4*)&bo[col]);
    float4 gv = *((const float4*)&g1[col]);
    float4 bv = *((const float4*)&be1[col]);

    #pragma unroll
    for (int ri = 0; ri < 8; ++ri) {
        int gr = block_row + rg + ri * 8;
        if (gr >= n_rows) continue;
        float4 xr = *((const float4*)&x[(size_t)gr * D + col]);
        float4 o;
        o.x = acc[ri][0] + bias.x + xr.x;
        o.y = acc[ri][1] + bias.y + xr.y;
        o.z = acc[ri][2] + bias.z + xr.z;
        o.w = acc[ri][3] + bias.w + xr.w;
        // LN across the 32 threads holding this row
        float s = o.x + o.y + o.z + o.w;
        float ss = o.x * o.x + o.y * o.y + o.z * o.z + o.w * o.w;
        #pragma unroll
        for (int msk = 1; msk <= 16; msk <<= 1) {
            s += __shfl_xor(s, msk);
            ss += __shfl_xor(ss, msk);
        }
        float mean = s * (1.0f / D);
        float var = ss * (1.0f / D) - mean * mean;
        float inv = rsqrtf(var + 1e-5f);
        float4 r;
        r.x = (o.x - mean) * inv * gv.x + bv.x;
        r.y = (o.y - mean) * inv * gv.y + bv.y;
        r.z = (o.z - mean) * inv * gv.z + bv.z;
        r.w = (o.w - mean) * inv * gv.w + bv.w;
        *((float4*)&hout[(size_t)gr * D + col]) = r;
    }
}

// ---------------- K6: y = relu(h@W1+bb1)@W2 + bb2 ; out = LN(h+y) ----------------
// 32 rows per block; rg = t>>5 -> rows rg+8*ri (ri 0..3); cg = t&31

__global__ __launch_bounds__(256) void ffn_ln_kernel(
    const float* __restrict__ h,
    const float* __restrict__ W1, const float* __restrict__ bb1,
    const float* __restrict__ W2, const float* __restrict__ bb2,
    const float* __restrict__ g2, const float* __restrict__ be2,
    float* __restrict__ out, int n_rows)
{
    __shared__ __align__(16) float hs[32][D];
    __shared__ __align__(16) float ts[32][D];
    __shared__ __align__(16) float wsh[32][D];
    const int t = threadIdx.x;
    const int block_row = blockIdx.x * 32;
    const int cg = t & 31, rg = t >> 5;
    const int col = cg * 4;

    // load h tile (32x128): 1024 float4s, 4 per thread
    {
        const float4* hg = (const float4*)h;
        #pragma unroll
        for (int it = 0; it < 4; ++it) {
            int f4 = t + it * 256;
            int r = f4 >> 5, c4 = f4 & 31;
            int gr = block_row + r;
            float4 val = (gr < n_rows) ? hg[(size_t)gr * 32 + c4]
                                       : make_float4(0.f, 0.f, 0.f, 0.f);
            *((float4*)&hs[r][c4 * 4]) = val;
        }
    }

    // ---- phase 1: t = relu(h@W1 + bb1) ----
    float acc[4][4];
    #pragma unroll
    for (int i = 0; i < 4; ++i)
        #pragma unroll
        for (int j = 0; j < 4; ++j) acc[i][j] = 0.f;

    for (int kk = 0; kk < D; kk += 32) {
        __syncthreads();
        const float4* wg = (const float4*)(W1 + (size_t)kk * D);
        #pragma unroll
        for (int it = 0; it < 4; ++it) {
            int f4 = t + it * 256;
            int r = f4 >> 5, c4 = f4 & 31;
            *((float4*)&wsh[r][c4 * 4]) = wg[f4];
        }
        __syncthreads();
        #pragma unroll
        for (int k4 = 0; k4 < 32; k4 += 4) {
            float4 w0 = *((const float4*)&wsh[k4 + 0][col]);
            float4 w1 = *((const float4*)&wsh[k4 + 1][col]);
            float4 w2 = *((const float4*)&wsh[k4 + 2][col]);
            float4 w3 = *((const float4*)&wsh[k4 + 3][col]);
            #pragma unroll
            for (int ri = 0; ri < 4; ++ri) {
                int r = rg + ri * 8;
                float4 xv = *((const float4*)&hs[r][kk + k4]);
                acc[ri][0] += xv.x * w0.x + xv.y * w1.x + xv.z * w2.x + xv.w * w3.x;
                acc[ri][1] += xv.x * w0.y + xv.y * w1.y + xv.z * w2.y + xv.w * w3.y;
                acc[ri][2] += xv.x * w0.z + xv.y * w1.z + xv.z * w2.z + xv.w * w3.z;
                acc[ri][3] += xv.x * w0.w + xv.y * w1.w + xv.z * w2.w + xv.w * w3.w;
            }
        }
    }
    {
        float4 b1 = *((const float4*)&bb1[col]);
        #pragma unroll
        for (int ri = 0; ri < 4; ++ri) {
            int r = rg + ri * 8;
            float4 o;
            o.x = fmaxf(acc[ri][0] + b1.x, 0.f);
            o.y = fmaxf(acc[ri][1] + b1.y, 0.f);
            o.z = fmaxf(acc[ri][2] + b1.z, 0.f);
            o.w = fmaxf(acc[ri][3] + b1.w, 0.f);
            *((float4*)&ts[r][col]) = o;
        }
    }

    // ---- phase 2: y = t@W2 + bb2 ----
    #pragma unroll
    for (int i = 0; i < 4; ++i)
        #pragma unroll
        for (int j = 0; j < 4; ++j) acc[i][j] = 0.f;

    for (int kk = 0; kk < D; kk += 32) {
        __syncthreads();   // also protects ts writes on first iter
        const float4* wg = (const float4*)(W2 + (size_t)kk * D);
        #pragma unroll
        for (int it = 0; it < 4; ++it) {
            int f4 = t + it * 256;
            int r = f4 >> 5, c4 = f4 & 31;
            *((float4*)&wsh[r][c4 * 4]) = wg[f4];
        }
        __syncthreads();
        #pragma unroll
        for (int k4 = 0; k4 < 32; k4 += 4) {
            float4 w0 = *((const float4*)&wsh[k4 + 0][col]);
            float4 w1 = *((const float4*)&wsh[k4 + 1][col]);
            float4 w2 = *((const float4*)&wsh[k4 + 2][col]);
            float4 w3 = *((const float4*)&wsh[k4 + 3][col]);
            #pragma unroll
            for (int ri = 0; ri < 4; ++ri) {
                int r = rg + ri * 8;
                float4 xv = *((const float4*)&ts[r][kk + k4]);
                acc[ri][0] += xv.x * w0.x + xv.y * w1.x + xv.z * w2.x + xv.w * w3.x;
                acc[ri][1] += xv.x * w0.y + xv.y * w1.y + xv.z * w2.y + xv.w * w3.y;
                acc[ri][2] += xv.x * w0.z + xv.y * w1.z + xv.z * w2.z + xv.w * w3.z;
                acc[ri][3] += xv.x * w0.w + xv.y * w1.w + xv.z * w2.w + xv.w * w3.w;
            }
        }
    }

    float4 b2 = *((const float4*)&bb2[col]);
    float4 gv = *((const float4*)&g2[col]);
    float4 bv = *((const float4*)&be2[col]);

    #pragma unroll
    for (int ri = 0; ri < 4; ++ri) {
        int r = rg + ri * 8;
        int gr = block_row + r;
        if (gr >= n_rows) continue;
        float4 hr = *((const float4*)&hs[r][col]);
        float4 o;
        o.x = acc[ri][0] + b2.x + hr.x;
        o.y = acc[ri][1] + b2.y + hr.y;
        o.z = acc[ri][2] + b2.z + hr.z;
        o.w = acc[ri][3] + b2.w + hr.w;
        float s = o.x + o.y + o.z + o.w;
        float ss = o.x * o.x + o.y * o.y + o.z * o.z + o.w * o.w;
        #pragma unroll
        for (int msk = 1; msk <= 16; msk <<= 1) {
            s += __shfl_xor(s, msk);
            ss += __shfl_xor(ss, msk);
        }
        float mean = s * (1.0f / D);
        float var = ss * (1.0f / D) - mean * mean;
        float inv = rsqrtf(var + 1e-5f);
        float4 r4;
        r4.x = (o.x - mean) * inv * gv.x + bv.x;
        r4.y = (o.y - mean) * inv * gv.y + bv.y;
        r4.z = (o.z - mean) * inv * gv.z + bv.z;
        r4.w = (o.w - mean) * inv * gv.w + bv.w;
        *((float4*)&out[(size_t)gr * D + col]) = r4;
    }
}

// ---------------- launch ----------------

extern "C" void kernel_launch(void* const* d_in, const int* in_sizes, int n_in,
                              void* d_out, int out_size, void* d_ws, size_t ws_size,
                              hipStream_t stream) {
    const float* x     = (const float*)d_in[0];
    const int*   idx_i = (const int*)d_in[1];
    const int*   idx_j = (const int*)d_in[2];
    const float* Wq = (const float*)d_in[3];
    const float* bq = (const float*)d_in[4];
    const float* Wk = (const float*)d_in[5];
    const float* bk = (const float*)d_in[6];
    const float* Wv = (const float*)d_in[7];
    const float* bv = (const float*)d_in[8];
    const float* Wo = (const float*)d_in[9];
    const float* bo = (const float*)d_in[10];
    const float* g1 = (const float*)d_in[11];
    const float* be1 = (const float*)d_in[12];
    const float* W1 = (const float*)d_in[13];
    const float* bb1 = (const float*)d_in[14];
    const float* W2 = (const float*)d_in[15];
    const float* bb2 = (const float*)d_in[16];
    const float* g2 = (const float*)d_in[17];
    const float* be2 = (const float*)d_in[18];

    const int N_ = in_sizes[0] / D;
    const int E_ = in_sizes[1];

    float* ws = (float*)d_ws;
    float* q     = ws;                      // N*D
    float* k     = q + (size_t)N_ * D;      // N*D
    float* v     = k + (size_t)N_ * D;      // N*D
    float* agg   = v + (size_t)N_ * D;      // N*D
    float* e     = agg + (size_t)N_ * D;    // E*H
    float* m     = e + (size_t)E_ * H;      // N*H
    float* denom = m + (size_t)N_ * H;      // N*H
    float* h     = (float*)d_out;           // reuse d_out as h buffer

    // K0: init
    {
        int total = N_ * D;
        int blocks = (total + 255) / 256;
        init_kernel<<<blocks, 256, 0, stream>>>(agg, m, denom, N_);
    }
    // K1: QKV
    {
        int blocks = (N_ + 63) / 64;
        qkv_kernel<<<blocks, 256, 0, stream>>>(x, Wq, bq, Wk, bk, Wv, bv, q, k, v, N_);
    }
    // K2: edge scores + segment max
    {
        int blocks = ((size_t)E_ * 32 + 255) / 256;
        edge_score_kernel<<<blocks, 256, 0, stream>>>(q, k, idx_i, idx_j, e, m, E_);
    }
    // K3: exp + denom
    {
        int total = E_ * H;
        int blocks = (total + 255) / 256;
        exp_kernel<<<blocks, 256, 0, stream>>>(e, idx_i, m, denom, total);
    }
    // K4: aggregate
    {
        int blocks = ((size_t)E_ * 32 + 255) / 256;
        agg_kernel<<<blocks, 256, 0, stream>>>(e, v, idx_i, idx_j, agg, E_);
    }
    // K5: out-proj + LN1 -> h (in d_out)
    {
        int blocks = (N_ + 63) / 64;
        oproj_ln_kernel<<<blocks, 256, 0, stream>>>(agg, denom, x, Wo, bo, g1, be1, h, N_);
    }
    // K6: FFN + LN2 -> out
    {
        int blocks = (N_ + 31) / 32;
        ffn_ln_kernel<<<blocks, 256, 0, stream>>>(h, W1, bb1, W2, bb2, g2, be2,
                                                  (float*)d_out, N_);
    }
}

// Round 2
// 612.047 us; speedup vs baseline: 3.0527x; 3.0527x over previous
//
#include <hip/hip_runtime.h>
#include <hip/hip_bf16.h>
#include <math.h>

#define D 128
#define H 8
#define DH 16

// ---------------- K0: zero histogram ----------------

__global__ __launch_bounds__(256) void zero_kernel(int* __restrict__ count, int n) {
    int gid = blockIdx.x * blockDim.x + threadIdx.x;
    if (gid < n) count[gid] = 0;
}

// ---------------- K1: QKV GEMM ----------------
// block: 256 threads, 64 rows x 128 cols, K=128 in chunks of 32.

__global__ __launch_bounds__(256) void qkv_kernel(
    const float* __restrict__ x,
    const float* __restrict__ Wq, const float* __restrict__ bq,
    const float* __restrict__ Wk, const float* __restrict__ bk,
    const float* __restrict__ Wv, const float* __restrict__ bv,
    float* __restrict__ q, float* __restrict__ k, float* __restrict__ v,
    int n_rows)
{
    __shared__ __align__(16) float xs[64][D];
    __shared__ __align__(16) float wsh[32][D];
    const int t = threadIdx.x;
    const int block_row = blockIdx.x * 64;
    const int cg = t & 31, rg = t >> 5;
    const int col = cg * 4;

    {
        const float4* xg = (const float4*)x;
        #pragma unroll
        for (int it = 0; it < 8; ++it) {
            int f4 = t + it * 256;
            int r = f4 >> 5, c4 = f4 & 31;
            int gr = block_row + r;
            float4 val = (gr < n_rows) ? xg[(size_t)gr * 32 + c4]
                                       : make_float4(0.f, 0.f, 0.f, 0.f);
            *((float4*)&xs[r][c4 * 4]) = val;
        }
    }

    const float* Ws[3] = {Wq, Wk, Wv};
    const float* Bs[3] = {bq, bk, bv};
    float* Os[3] = {q, k, v};

    #pragma unroll
    for (int mat = 0; mat < 3; ++mat) {
        float acc[8][4];
        #pragma unroll
        for (int i = 0; i < 8; ++i)
            #pragma unroll
            for (int j = 0; j < 4; ++j) acc[i][j] = 0.f;

        for (int kk = 0; kk < D; kk += 32) {
            __syncthreads();
            const float4* wg = (const float4*)(Ws[mat] + (size_t)kk * D);
            #pragma unroll
            for (int it = 0; it < 4; ++it) {
                int f4 = t + it * 256;
                int r = f4 >> 5, c4 = f4 & 31;
                *((float4*)&wsh[r][c4 * 4]) = wg[f4];
            }
            __syncthreads();
            #pragma unroll
            for (int k4 = 0; k4 < 32; k4 += 4) {
                float4 w0 = *((const float4*)&wsh[k4 + 0][col]);
                float4 w1 = *((const float4*)&wsh[k4 + 1][col]);
                float4 w2 = *((const float4*)&wsh[k4 + 2][col]);
                float4 w3 = *((const float4*)&wsh[k4 + 3][col]);
                #pragma unroll
                for (int ri = 0; ri < 8; ++ri) {
                    int r = rg + ri * 8;
                    float4 xv = *((const float4*)&xs[r][kk + k4]);
                    acc[ri][0] += xv.x * w0.x + xv.y * w1.x + xv.z * w2.x + xv.w * w3.x;
                    acc[ri][1] += xv.x * w0.y + xv.y * w1.y + xv.z * w2.y + xv.w * w3.y;
                    acc[ri][2] += xv.x * w0.z + xv.y * w1.z + xv.z * w2.z + xv.w * w3.z;
                    acc[ri][3] += xv.x * w0.w + xv.y * w1.w + xv.z * w2.w + xv.w * w3.w;
                }
            }
        }
        float4 bias = *((const float4*)&Bs[mat][col]);
        #pragma unroll
        for (int ri = 0; ri < 8; ++ri) {
            int gr = block_row + rg + ri * 8;
            if (gr < n_rows) {
                float4 o;
                o.x = acc[ri][0] + bias.x;
                o.y = acc[ri][1] + bias.y;
                o.z = acc[ri][2] + bias.z;
                o.w = acc[ri][3] + bias.w;
                *((float4*)&Os[mat][(size_t)gr * D + col]) = o;
            }
        }
    }
}

// ---------------- K2: histogram of destinations ----------------

__global__ __launch_bounds__(256) void hist_kernel(
    const int* __restrict__ idx_i, int* __restrict__ count, int n_edges)
{
    int e = blockIdx.x * blockDim.x + threadIdx.x;
    if (e < n_edges) atomicAdd(&count[idx_i[e]], 1);
}

// ---------------- K3: exclusive scan (single block, wave-scan based) ----------------

__global__ __launch_bounds__(1024) void scan_kernel(
    const int* __restrict__ count, int* __restrict__ row_start,
    int* __restrict__ cursor, int n)
{
    __shared__ int wtot[16];
    __shared__ int wbase[16];
    __shared__ int carry;
    const int t = threadIdx.x;
    const int lane = t & 63, w = t >> 6;
    if (t == 0) carry = 0;
    __syncthreads();
    for (int start = 0; start < n; start += 1024) {
        int idx = start + t;
        int iv = (idx < n) ? count[idx] : 0;
        int vv = iv;
        #pragma unroll
        for (int off = 1; off < 64; off <<= 1) {
            int u = __shfl_up(vv, off);
            if (lane >= off) vv += u;
        }
        if (lane == 63) wtot[w] = vv;
        __syncthreads();
        if (t == 0) {
            int b = carry;
            #pragma unroll
            for (int i = 0; i < 16; ++i) { wbase[i] = b; b += wtot[i]; }
            carry = b;
        }
        __syncthreads();
        int excl = wbase[w] + vv - iv;
        if (idx < n) { row_start[idx] = excl; cursor[idx] = excl; }
        __syncthreads();   // protect wtot/wbase/carry before next chunk
    }
    if (t == 0) row_start[n] = carry;
}

// ---------------- K4: scatter sources into dest-sorted order ----------------

__global__ __launch_bounds__(256) void scatter_kernel(
    const int* __restrict__ idx_i, const int* __restrict__ idx_j,
    int* __restrict__ cursor, int* __restrict__ ejs, int n_edges)
{
    int e = blockIdx.x * blockDim.x + threadIdx.x;
    if (e < n_edges) {
        int i = idx_i[e];
        int pos = atomicAdd(&cursor[i], 1);
        ejs[pos] = idx_j[e];
    }
}

// ---------------- K5: fused per-node attention (online softmax) ----------------
// one 64-lane wave per node; lane holds floats [2*lane, 2*lane+1];
// head h lives in lanes 8h..8h+7 (16 floats)

__global__ __launch_bounds__(256) void fused_agg_kernel(
    const float* __restrict__ q, const float* __restrict__ k,
    const float* __restrict__ v, const int* __restrict__ row_start,
    const int* __restrict__ ejs, float* __restrict__ agg, int n_nodes)
{
    const int lane = threadIdx.x & 63;
    const int node = (blockIdx.x * blockDim.x + threadIdx.x) >> 6;
    if (node >= n_nodes) return;
    const int beg = row_start[node], end = row_start[node + 1];
    const int c2 = lane * 2;
    const float2 qv = *(const float2*)&q[(size_t)node * D + c2];
    float m = -INFINITY, l = 0.f;
    float ax = 0.f, ay = 0.f;
    int j0 = (beg < end) ? ejs[beg] : 0;
    float2 kv = *(const float2*)&k[(size_t)j0 * D + c2];
    float2 vv = *(const float2*)&v[(size_t)j0 * D + c2];
    for (int p = beg; p < end; ++p) {
        float2 kc = kv, vc = vv;
        if (p + 1 < end) {
            int jn = ejs[p + 1];
            kv = *(const float2*)&k[(size_t)jn * D + c2];
            vv = *(const float2*)&v[(size_t)jn * D + c2];
        }
        float d = qv.x * kc.x + qv.y * kc.y;
        d += __shfl_xor(d, 1);
        d += __shfl_xor(d, 2);
        d += __shfl_xor(d, 4);
        float s = d * 0.25f;           // 1/sqrt(16)
        float mn = fmaxf(m, s);
        float c = __expf(m - mn);      // exp(-inf) = 0 on first edge
        float pe = __expf(s - mn);
        l = l * c + pe;
        ax = ax * c + pe * vc.x;
        ay = ay * c + pe * vc.y;
        m = mn;
    }
    float invl = (l > 0.f) ? (1.0f / l) : 0.f;
    float2 o;
    o.x = ax * invl;
    o.y = ay * invl;
    *(float2*)&agg[(size_t)node * D + c2] = o;
}

// ---------------- K6: x1 = agg@Wo + bo ; h = LN(x + x1) ----------------

__global__ __launch_bounds__(256) void oproj_ln_kernel(
    const float* __restrict__ agg, const float* __restrict__ x,
    const float* __restrict__ Wo, const float* __restrict__ bo,
    const float* __restrict__ g1, const float* __restrict__ be1,
    float* __restrict__ hout, int n_rows)
{
    __shared__ __align__(16) float xs[64][D];
    __shared__ __align__(16) float wsh[32][D];
    const int t = threadIdx.x;
    const int block_row = blockIdx.x * 64;
    const int cg = t & 31, rg = t >> 5;
    const int col = cg * 4;

    {
        const float4* ag = (const float4*)agg;
        #pragma unroll
        for (int it = 0; it < 8; ++it) {
            int f4 = t + it * 256;
            int r = f4 >> 5, c4 = f4 & 31;
            int gr = block_row + r;
            float4 val = (gr < n_rows) ? ag[(size_t)gr * 32 + c4]
                                       : make_float4(0.f, 0.f, 0.f, 0.f);
            *((float4*)&xs[r][c4 * 4]) = val;
        }
    }

    float acc[8][4];
    #pragma unroll
    for (int i = 0; i < 8; ++i)
        #pragma unroll
        for (int j = 0; j < 4; ++j) acc[i][j] = 0.f;

    for (int kk = 0; kk < D; kk += 32) {
        __syncthreads();
        const float4* wg = (const float4*)(Wo + (size_t)kk * D);
        #pragma unroll
        for (int it = 0; it < 4; ++it) {
            int f4 = t + it * 256;
            int r = f4 >> 5, c4 = f4 & 31;
            *((float4*)&wsh[r][c4 * 4]) = wg[f4];
        }
        __syncthreads();
        #pragma unroll
        for (int k4 = 0; k4 < 32; k4 += 4) {
            float4 w0 = *((const float4*)&wsh[k4 + 0][col]);
            float4 w1 = *((const float4*)&wsh[k4 + 1][col]);
            float4 w2 = *((const float4*)&wsh[k4 + 2][col]);
            float4 w3 = *((const float4*)&wsh[k4 + 3][col]);
            #pragma unroll
            for (int ri = 0; ri < 8; ++ri) {
                int r = rg + ri * 8;
                float4 xv = *((const float4*)&xs[r][kk + k4]);
                acc[ri][0] += xv.x * w0.x + xv.y * w1.x + xv.z * w2.x + xv.w * w3.x;
                acc[ri][1] += xv.x * w0.y + xv.y * w1.y + xv.z * w2.y + xv.w * w3.y;
                acc[ri][2] += xv.x * w0.z + xv.y * w1.z + xv.z * w2.z + xv.w * w3.z;
                acc[ri][3] += xv.x * w0.w + xv.y * w1.w + xv.z * w2.w + xv.w * w3.w;
            }
        }
    }

    float4 bias = *((const float4*)&bo[col]);
    float4 gv = *((const float4*)&g1[col]);
    float4 bv = *((const float4*)&be1[col]);

    #pragma unroll
    for (int ri = 0; ri < 8; ++ri) {
        int gr = block_row + rg + ri * 8;
        if (gr >= n_rows) continue;
        float4 xr = *((const float4*)&x[(size_t)gr * D + col]);
        float4 o;
        o.x = acc[ri][0] + bias.x + xr.x;
        o.y = acc[ri][1] + bias.y + xr.y;
        o.z = acc[ri][2] + bias.z + xr.z;
        o.w = acc[ri][3] + bias.w + xr.w;
        float s = o.x + o.y + o.z + o.w;
        float ss = o.x * o.x + o.y * o.y + o.z * o.z + o.w * o.w;
        #pragma unroll
        for (int msk = 1; msk <= 16; msk <<= 1) {
            s += __shfl_xor(s, msk);
            ss += __shfl_xor(ss, msk);
        }
        float mean = s * (1.0f / D);
        float var = ss * (1.0f / D) - mean * mean;
        float inv = rsqrtf(var + 1e-5f);
        float4 r;
        r.x = (o.x - mean) * inv * gv.x + bv.x;
        r.y = (o.y - mean) * inv * gv.y + bv.y;
        r.z = (o.z - mean) * inv * gv.z + bv.z;
        r.w = (o.w - mean) * inv * gv.w + bv.w;
        *((float4*)&hout[(size_t)gr * D + col]) = r;
    }
}

// ---------------- K7: y = relu(h@W1+bb1)@W2 + bb2 ; out = LN(h+y) ----------------

__global__ __launch_bounds__(256) void ffn_ln_kernel(
    const float* __restrict__ h,
    const float* __restrict__ W1, const float* __restrict__ bb1,
    const float* __restrict__ W2, const float* __restrict__ bb2,
    const float* __restrict__ g2, const float* __restrict__ be2,
    float* __restrict__ out, int n_rows)
{
    __shared__ __align__(16) float hs[32][D];
    __shared__ __align__(16) float ts[32][D];
    __shared__ __align__(16) float wsh[32][D];
    const int t = threadIdx.x;
    const int block_row = blockIdx.x * 32;
    const int cg = t & 31, rg = t >> 5;
    const int col = cg * 4;

    {
        const float4* hg = (const float4*)h;
        #pragma unroll
        for (int it = 0; it < 4; ++it) {
            int f4 = t + it * 256;
            int r = f4 >> 5, c4 = f4 & 31;
            int gr = block_row + r;
            float4 val = (gr < n_rows) ? hg[(size_t)gr * 32 + c4]
                                       : make_float4(0.f, 0.f, 0.f, 0.f);
            *((float4*)&hs[r][c4 * 4]) = val;
        }
    }

    // ---- phase 1: t = relu(h@W1 + bb1) ----
    float acc[4][4];
    #pragma unroll
    for (int i = 0; i < 4; ++i)
        #pragma unroll
        for (int j = 0; j < 4; ++j) acc[i][j] = 0.f;

    for (int kk = 0; kk < D; kk += 32) {
        __syncthreads();
        const float4* wg = (const float4*)(W1 + (size_t)kk * D);
        #pragma unroll
        for (int it = 0; it < 4; ++it) {
            int f4 = t + it * 256;
            int r = f4 >> 5, c4 = f4 & 31;
            *((float4*)&wsh[r][c4 * 4]) = wg[f4];
        }
        __syncthreads();
        #pragma unroll
        for (int k4 = 0; k4 < 32; k4 += 4) {
            float4 w0 = *((const float4*)&wsh[k4 + 0][col]);
            float4 w1 = *((const float4*)&wsh[k4 + 1][col]);
            float4 w2 = *((const float4*)&wsh[k4 + 2][col]);
            float4 w3 = *((const float4*)&wsh[k4 + 3][col]);
            #pragma unroll
            for (int ri = 0; ri < 4; ++ri) {
                int r = rg + ri * 8;
                float4 xv = *((const float4*)&hs[r][kk + k4]);
                acc[ri][0] += xv.x * w0.x + xv.y * w1.x + xv.z * w2.x + xv.w * w3.x;
                acc[ri][1] += xv.x * w0.y + xv.y * w1.y + xv.z * w2.y + xv.w * w3.y;
                acc[ri][2] += xv.x * w0.z + xv.y * w1.z + xv.z * w2.z + xv.w * w3.z;
                acc[ri][3] += xv.x * w0.w + xv.y * w1.w + xv.z * w2.w + xv.w * w3.w;
            }
        }
    }
    {
        float4 b1 = *((const float4*)&bb1[col]);
        #pragma unroll
        for (int ri = 0; ri < 4; ++ri) {
            int r = rg + ri * 8;
            float4 o;
            o.x = fmaxf(acc[ri][0] + b1.x, 0.f);
            o.y = fmaxf(acc[ri][1] + b1.y, 0.f);
            o.z = fmaxf(acc[ri][2] + b1.z, 0.f);
            o.w = fmaxf(acc[ri][3] + b1.w, 0.f);
            *((float4*)&ts[r][col]) = o;
        }
    }

    // ---- phase 2: y = t@W2 + bb2 ----
    #pragma unroll
    for (int i = 0; i < 4; ++i)
        #pragma unroll
        for (int j = 0; j < 4; ++j) acc[i][j] = 0.f;

    for (int kk = 0; kk < D; kk += 32) {
        __syncthreads();
        const float4* wg = (const float4*)(W2 + (size_t)kk * D);
        #pragma unroll
        for (int it = 0; it < 4; ++it) {
            int f4 = t + it * 256;
            int r = f4 >> 5, c4 = f4 & 31;
            *((float4*)&wsh[r][c4 * 4]) = wg[f4];
        }
        __syncthreads();
        #pragma unroll
        for (int k4 = 0; k4 < 32; k4 += 4) {
            float4 w0 = *((const float4*)&wsh[k4 + 0][col]);
            float4 w1 = *((const float4*)&wsh[k4 + 1][col]);
            float4 w2 = *((const float4*)&wsh[k4 + 2][col]);
            float4 w3 = *((const float4*)&wsh[k4 + 3][col]);
            #pragma unroll
            for (int ri = 0; ri < 4; ++ri) {
                int r = rg + ri * 8;
                float4 xv = *((const float4*)&ts[r][kk + k4]);
                acc[ri][0] += xv.x * w0.x + xv.y * w1.x + xv.z * w2.x + xv.w * w3.x;
                acc[ri][1] += xv.x * w0.y + xv.y * w1.y + xv.z * w2.y + xv.w * w3.y;
                acc[ri][2] += xv.x * w0.z + xv.y * w1.z + xv.z * w2.z + xv.w * w3.z;
                acc[ri][3] += xv.x * w0.w + xv.y * w1.w + xv.z * w2.w + xv.w * w3.w;
            }
        }
    }

    float4 b2 = *((const float4*)&bb2[col]);
    float4 gv = *((const float4*)&g2[col]);
    float4 bv = *((const float4*)&be2[col]);

    #pragma unroll
    for (int ri = 0; ri < 4; ++ri) {
        int r = rg + ri * 8;
        int gr = block_row + r;
        if (gr >= n_rows) continue;
        float4 hr = *((const float4*)&hs[r][col]);
        float4 o;
        o.x = acc[ri][0] + b2.x + hr.x;
        o.y = acc[ri][1] + b2.y + hr.y;
        o.z = acc[ri][2] + b2.z + hr.z;
        o.w = acc[ri][3] + b2.w + hr.w;
        float s = o.x + o.y + o.z + o.w;
        float ss = o.x * o.x + o.y * o.y + o.z * o.z + o.w * o.w;
        #pragma unroll
        for (int msk = 1; msk <= 16; msk <<= 1) {
            s += __shfl_xor(s, msk);
            ss += __shfl_xor(ss, msk);
        }
        float mean = s * (1.0f / D);
        float var = ss * (1.0f / D) - mean * mean;
        float inv = rsqrtf(var + 1e-5f);
        float4 r4;
        r4.x = (o.x - mean) * inv * gv.x + bv.x;
        r4.y = (o.y - mean) * inv * gv.y + bv.y;
        r4.z = (o.z - mean) * inv * gv.z + bv.z;
        r4.w = (o.w - mean) * inv * gv.w + bv.w;
        *((float4*)&out[(size_t)gr * D + col]) = r4;
    }
}

// ---------------- launch ----------------

extern "C" void kernel_launch(void* const* d_in, const int* in_sizes, int n_in,
                              void* d_out, int out_size, void* d_ws, size_t ws_size,
                              hipStream_t stream) {
    const float* x     = (const float*)d_in[0];
    const int*   idx_i = (const int*)d_in[1];
    const int*   idx_j = (const int*)d_in[2];
    const float* Wq = (const float*)d_in[3];
    const float* bq = (const float*)d_in[4];
    const float* Wk = (const float*)d_in[5];
    const float* bk = (const float*)d_in[6];
    const float* Wv = (const float*)d_in[7];
    const float* bv = (const float*)d_in[8];
    const float* Wo = (const float*)d_in[9];
    const float* bo = (const float*)d_in[10];
    const float* g1 = (const float*)d_in[11];
    const float* be1 = (const float*)d_in[12];
    const float* W1 = (const float*)d_in[13];
    const float* bb1 = (const float*)d_in[14];
    const float* W2 = (const float*)d_in[15];
    const float* bb2 = (const float*)d_in[16];
    const float* g2 = (const float*)d_in[17];
    const float* be2 = (const float*)d_in[18];

    const int N_ = in_sizes[0] / D;
    const int E_ = in_sizes[1];

    float* ws = (float*)d_ws;
    float* q   = ws;                      // N*D
    float* k   = q + (size_t)N_ * D;      // N*D
    float* v   = k + (size_t)N_ * D;      // N*D
    float* agg = v + (size_t)N_ * D;      // N*D
    int* count     = (int*)(agg + (size_t)N_ * D);  // N
    int* row_start = count + N_;                    // N+1
    int* cursor    = row_start + N_ + 1;            // N
    int* ejs       = cursor + N_;                   // E
    float* h = (float*)d_out;

    // K0: zero histogram
    zero_kernel<<<(N_ + 255) / 256, 256, 0, stream>>>(count, N_);
    // K1: QKV GEMMs
    qkv_kernel<<<(N_ + 63) / 64, 256, 0, stream>>>(x, Wq, bq, Wk, bk, Wv, bv,
                                                   q, k, v, N_);
    // K2: histogram of idx_i
    hist_kernel<<<(E_ + 255) / 256, 256, 0, stream>>>(idx_i, count, E_);
    // K3: scan -> row_start, cursor
    scan_kernel<<<1, 1024, 0, stream>>>(count, row_start, cursor, N_);
    // K4: scatter idx_j into dest-sorted ejs
    scatter_kernel<<<(E_ + 255) / 256, 256, 0, stream>>>(idx_i, idx_j, cursor, ejs, E_);
    // K5: fused per-node attention
    fused_agg_kernel<<<(N_ + 3) / 4, 256, 0, stream>>>(q, k, v, row_start, ejs,
                                                       agg, N_);
    // K6: out-proj + LN1 -> h (in d_out)
    oproj_ln_kernel<<<(N_ + 63) / 64, 256, 0, stream>>>(agg, x, Wo, bo, g1, be1,
                                                        h, N_);
    // K7: FFN + LN2 -> out
    ffn_ln_kernel<<<(N_ + 31) / 32, 256, 0, stream>>>(h, W1, bb1, W2, bb2,
                                                      g2, be2, (float*)d_out, N_);
}

// Round 4
// 512.583 us; speedup vs baseline: 3.6450x; 1.1940x over previous
//
#include <hip/hip_runtime.h>
#include <hip/hip_bf16.h>
#include <math.h>

#define D 128
#define H 8
#define DH 16

typedef __attribute__((ext_vector_type(8))) short bf16x8;
typedef __attribute__((ext_vector_type(4))) float f32x4;

__device__ __forceinline__ float bf2f(ushort u) {
    unsigned int x = ((unsigned int)u) << 16;
    float f;
    __builtin_memcpy(&f, &x, 4);
    return f;
}
__device__ __forceinline__ ushort f2bf(float f) {
    __hip_bfloat16 h = __float2bfloat16(f);
    ushort u;
    __builtin_memcpy(&u, &h, 2);
    return u;
}

// ---------------- K0: zero histogram ----------------

__global__ __launch_bounds__(256) void zero_kernel(int* __restrict__ count, int n) {
    int gid = blockIdx.x * blockDim.x + threadIdx.x;
    if (gid < n) count[gid] = 0;
}

// ---------------- prep_x: split x into bf16 hi/lo ----------------

__global__ __launch_bounds__(256) void prep_x_kernel(
    const float* __restrict__ x, ushort* __restrict__ xh, ushort* __restrict__ xl,
    int total4)
{
    int gid = blockIdx.x * blockDim.x + threadIdx.x;
    if (gid >= total4) return;
    float4 v = ((const float4*)x)[gid];
    ushort4 hv, lv;
    hv.x = f2bf(v.x); lv.x = f2bf(v.x - bf2f(hv.x));
    hv.y = f2bf(v.y); lv.y = f2bf(v.y - bf2f(hv.y));
    hv.z = f2bf(v.z); lv.z = f2bf(v.z - bf2f(hv.z));
    hv.w = f2bf(v.w); lv.w = f2bf(v.w - bf2f(hv.w));
    ((ushort4*)xh)[gid] = hv;
    ((ushort4*)xl)[gid] = lv;
}

// ---------------- prep_w: transpose + split 6 weight matrices ----------------
// one block per matrix; out layout WT[c][k] (row-major over c), bf16 hi/lo

__global__ __launch_bounds__(256) void prep_w_kernel(
    const float* __restrict__ w0, const float* __restrict__ w1,
    const float* __restrict__ w2, const float* __restrict__ w3,
    const float* __restrict__ w4, const float* __restrict__ w5,
    ushort* __restrict__ wth, ushort* __restrict__ wtl)
{
    __shared__ __align__(16) float tile[128][132];
    const int m = blockIdx.x;
    const float* W = (m == 0) ? w0 : (m == 1) ? w1 : (m == 2) ? w2
                   : (m == 3) ? w3 : (m == 4) ? w4 : w5;
    const int t = threadIdx.x;
    const float4* wg = (const float4*)W;
    #pragma unroll
    for (int it = 0; it < 16; ++it) {
        int f4 = t + it * 256;            // 0..4095
        int k = f4 >> 5, c4 = f4 & 31;
        *((float4*)&tile[k][c4 * 4]) = wg[f4];
    }
    __syncthreads();
    ushort* oh = wth + m * 16384;
    ushort* ol = wtl + m * 16384;
    #pragma unroll
    for (int it = 0; it < 64; ++it) {
        int idx = t + it * 256;           // 0..16383
        int c = idx >> 7, k = idx & 127;
        float v = tile[k][c];
        ushort hb = f2bf(v);
        oh[idx] = hb;
        ol[idx] = f2bf(v - bf2f(hb));
    }
}

// ---------------- qkv: [N,128]@[128,128]x3 via split-bf16 MFMA ----------------
// block = 256 thr = 4 waves; 64 rows/block; wave w owns rows w*16..w*16+15, all 128 cols.
// A frag: lane holds X[rowb+(l&15)][k0+(l>>4)*8 ..+7]; B frag: WT[col][k] same shape.

__global__ __launch_bounds__(256) void qkv_mfma_kernel(
    const ushort* __restrict__ xh, const ushort* __restrict__ xl,
    const ushort* __restrict__ wth, const ushort* __restrict__ wtl,
    const float* __restrict__ bq, const float* __restrict__ bk,
    const float* __restrict__ bv,
    float* __restrict__ q, float* __restrict__ k, float* __restrict__ v,
    int n_rows)
{
    const int t = threadIdx.x;
    const int w = t >> 6, l = t & 63;
    const int l15 = l & 15, l4 = l >> 4;
    const int rowb = blockIdx.x * 64 + w * 16;
    const size_t abase = (size_t)(rowb + l15) * D + l4 * 8;

    float* outs[3] = {q, k, v};
    const float* biases[3] = {bq, bk, bv};

    #pragma unroll
    for (int m = 0; m < 3; ++m) {
        const ushort* bh_ = wth + m * 16384;
        const ushort* bl_ = wtl + m * 16384;
        f32x4 acc[8];
        #pragma unroll
        for (int n = 0; n < 8; ++n) acc[n] = (f32x4){0.f, 0.f, 0.f, 0.f};

        #pragma unroll
        for (int kk = 0; kk < 4; ++kk) {
            bf16x8 ah = *(const bf16x8*)(xh + abase + kk * 32);
            bf16x8 al = *(const bf16x8*)(xl + abase + kk * 32);
            #pragma unroll
            for (int n = 0; n < 8; ++n) {
                size_t boff = (size_t)(n * 16 + l15) * D + l4 * 8 + kk * 32;
                bf16x8 bh = *(const bf16x8*)(bh_ + boff);
                bf16x8 bl = *(const bf16x8*)(bl_ + boff);
                acc[n] = __builtin_amdgcn_mfma_f32_16x16x32_bf16(ah, bh, acc[n], 0, 0, 0);
                acc[n] = __builtin_amdgcn_mfma_f32_16x16x32_bf16(al, bh, acc[n], 0, 0, 0);
                acc[n] = __builtin_amdgcn_mfma_f32_16x16x32_bf16(ah, bl, acc[n], 0, 0, 0);
            }
        }
        float* out = outs[m];
        const float* bias = biases[m];
        #pragma unroll
        for (int n = 0; n < 8; ++n) {
            int col = n * 16 + l15;
            float bsv = bias[col];
            #pragma unroll
            for (int r = 0; r < 4; ++r) {
                int row = rowb + l4 * 4 + r;
                if (row < n_rows)
                    out[(size_t)row * D + col] = acc[n][r] + bsv;
            }
        }
    }
}

// ---------------- CSR build ----------------

__global__ __launch_bounds__(256) void hist_kernel(
    const int* __restrict__ idx_i, int* __restrict__ count, int n_edges)
{
    int e = blockIdx.x * blockDim.x + threadIdx.x;
    if (e < n_edges) atomicAdd(&count[idx_i[e]], 1);
}

__global__ __launch_bounds__(1024) void scan_kernel(
    const int* __restrict__ count, int* __restrict__ row_start,
    int* __restrict__ cursor, int n)
{
    __shared__ int wtot[16];
    __shared__ int wbase[16];
    __shared__ int carry;
    const int t = threadIdx.x;
    const int lane = t & 63, w = t >> 6;
    if (t == 0) carry = 0;
    __syncthreads();
    for (int start = 0; start < n; start += 1024) {
        int idx = start + t;
        int iv = (idx < n) ? count[idx] : 0;
        int vv = iv;
        #pragma unroll
        for (int off = 1; off < 64; off <<= 1) {
            int u = __shfl_up(vv, off);
            if (lane >= off) vv += u;
        }
        if (lane == 63) wtot[w] = vv;
        __syncthreads();
        if (t == 0) {
            int b = carry;
            #pragma unroll
            for (int i = 0; i < 16; ++i) { wbase[i] = b; b += wtot[i]; }
            carry = b;
        }
        __syncthreads();
        int excl = wbase[w] + vv - iv;
        if (idx < n) { row_start[idx] = excl; cursor[idx] = excl; }
        __syncthreads();
    }
    if (t == 0) row_start[n] = carry;
}

__global__ __launch_bounds__(256) void scatter_kernel(
    const int* __restrict__ idx_i, const int* __restrict__ idx_j,
    int* __restrict__ cursor, int* __restrict__ ejs, int n_edges)
{
    int e = blockIdx.x * blockDim.x + threadIdx.x;
    if (e < n_edges) {
        int i = idx_i[e];
        int pos = atomicAdd(&cursor[i], 1);
        ejs[pos] = idx_j[e];
    }
}

// ---------------- fused per-node attention (online softmax) ----------------
// one wave per node; lane holds floats [2*lane, 2*lane+1]; head h = lanes 8h..8h+7.
// outputs agg as lossless bf16 split (hi/lo).

__global__ __launch_bounds__(256) void fused_agg_kernel(
    const float* __restrict__ q, const float* __restrict__ k,
    const float* __restrict__ v, const int* __restrict__ row_start,
    const int* __restrict__ ejs,
    ushort* __restrict__ aggh, ushort* __restrict__ aggl, int n_nodes)
{
    const int lane = threadIdx.x & 63;
    const int node = (blockIdx.x * blockDim.x + threadIdx.x) >> 6;
    if (node >= n_nodes) return;
    const int beg = row_start[node], end = row_start[node + 1];
    const int c2 = lane * 2;
    const float2 qv = *(const float2*)&q[(size_t)node * D + c2];
    float m = -INFINITY, l = 0.f;
    float ax = 0.f, ay = 0.f;
    int j0 = (beg < end) ? ejs[beg] : 0;
    float2 kv = *(const float2*)&k[(size_t)j0 * D + c2];
    float2 vv = *(const float2*)&v[(size_t)j0 * D + c2];
    for (int p = beg; p < end; ++p) {
        float2 kc = kv, vc = vv;
        if (p + 1 < end) {
            int jn = ejs[p + 1];
            kv = *(const float2*)&k[(size_t)jn * D + c2];
            vv = *(const float2*)&v[(size_t)jn * D + c2];
        }
        float d = qv.x * kc.x + qv.y * kc.y;
        d += __shfl_xor(d, 1);
        d += __shfl_xor(d, 2);
        d += __shfl_xor(d, 4);
        float s = d * 0.25f;           // 1/sqrt(16)
        float mn = fmaxf(m, s);
        float c = __expf(m - mn);
        float pe = __expf(s - mn);
        l = l * c + pe;
        ax = ax * c + pe * vc.x;
        ay = ay * c + pe * vc.y;
        m = mn;
    }
    float invl = (l > 0.f) ? (1.0f / l) : 0.f;
    float ox = ax * invl, oy = ay * invl;
    ushort hx = f2bf(ox); ushort lx = f2bf(ox - bf2f(hx));
    ushort hy = f2bf(oy); ushort ly = f2bf(oy - bf2f(hy));
    ((unsigned int*)aggh)[(size_t)node * 64 + lane] = (unsigned int)hx | ((unsigned int)hy << 16);
    ((unsigned int*)aggl)[(size_t)node * 64 + lane] = (unsigned int)lx | ((unsigned int)ly << 16);
}

// ---------------- oproj + LN1: h = LN(x + agg@Wo + bo) -> bf16 split ----------------

__global__ __launch_bounds__(256) void oproj_mfma_kernel(
    const ushort* __restrict__ aggh, const ushort* __restrict__ aggl,
    const float* __restrict__ x,
    const ushort* __restrict__ wth, const ushort* __restrict__ wtl,  // mat 3 (pre-offset)
    const float* __restrict__ bo, const float* __restrict__ g1,
    const float* __restrict__ be1,
    ushort* __restrict__ hh, ushort* __restrict__ hl, int n_rows)
{
    const int t = threadIdx.x;
    const int w = t >> 6, l = t & 63;
    const int l15 = l & 15, l4 = l >> 4;
    const int rowb = blockIdx.x * 64 + w * 16;
    const size_t abase = (size_t)(rowb + l15) * D + l4 * 8;

    f32x4 acc[8];
    #pragma unroll
    for (int n = 0; n < 8; ++n) acc[n] = (f32x4){0.f, 0.f, 0.f, 0.f};

    #pragma unroll
    for (int kk = 0; kk < 4; ++kk) {
        bf16x8 ah = *(const bf16x8*)(aggh + abase + kk * 32);
        bf16x8 al = *(const bf16x8*)(aggl + abase + kk * 32);
        #pragma unroll
        for (int n = 0; n < 8; ++n) {
            size_t boff = (size_t)(n * 16 + l15) * D + l4 * 8 + kk * 32;
            bf16x8 bh = *(const bf16x8*)(wth + boff);
            bf16x8 bl = *(const bf16x8*)(wtl + boff);
            acc[n] = __builtin_amdgcn_mfma_f32_16x16x32_bf16(ah, bh, acc[n], 0, 0, 0);
            acc[n] = __builtin_amdgcn_mfma_f32_16x16x32_bf16(al, bh, acc[n], 0, 0, 0);
            acc[n] = __builtin_amdgcn_mfma_f32_16x16x32_bf16(ah, bl, acc[n], 0, 0, 0);
        }
    }

    // residual + bias
    float vals[8][4];
    #pragma unroll
    for (int n = 0; n < 8; ++n) {
        int col = n * 16 + l15;
        float bsv = bo[col];
        #pragma unroll
        for (int r = 0; r < 4; ++r) {
            int row = rowb + l4 * 4 + r;
            float xr = (row < n_rows) ? x[(size_t)row * D + col] : 0.f;
            vals[n][r] = acc[n][r] + bsv + xr;
        }
    }
    // LN per row (16-lane groups share the same 4 rows)
    #pragma unroll
    for (int r = 0; r < 4; ++r) {
        int row = rowb + l4 * 4 + r;
        float s = 0.f, ss = 0.f;
        #pragma unroll
        for (int n = 0; n < 8; ++n) { s += vals[n][r]; ss += vals[n][r] * vals[n][r]; }
        #pragma unroll
        for (int msk = 1; msk <= 8; msk <<= 1) {
            s += __shfl_xor(s, msk);
            ss += __shfl_xor(ss, msk);
        }
        float mean = s * (1.0f / D);
        float var = ss * (1.0f / D) - mean * mean;
        float inv = rsqrtf(var + 1e-5f);
        if (row < n_rows) {
            #pragma unroll
            for (int n = 0; n < 8; ++n) {
                int col = n * 16 + l15;
                float y = (vals[n][r] - mean) * inv * g1[col] + be1[col];
                ushort hb = f2bf(y);
                hh[(size_t)row * D + col] = hb;
                hl[(size_t)row * D + col] = f2bf(y - bf2f(hb));
            }
        }
    }
}

// ---------------- FFN + LN2: out = LN(h + relu(h@W1+b1)@W2 + b2) ----------------

__global__ __launch_bounds__(256) void ffn_mfma_kernel(
    const ushort* __restrict__ hh, const ushort* __restrict__ hl,
    const ushort* __restrict__ w1th, const ushort* __restrict__ w1tl,
    const ushort* __restrict__ w2th, const ushort* __restrict__ w2tl,
    const float* __restrict__ bb1, const float* __restrict__ bb2,
    const float* __restrict__ g2, const float* __restrict__ be2,
    float* __restrict__ out, int n_rows)
{
    __shared__ __align__(16) ushort tsh[64][136];
    __shared__ __align__(16) ushort tsl[64][136];
    const int t = threadIdx.x;
    const int w = t >> 6, l = t & 63;
    const int l15 = l & 15, l4 = l >> 4;
    const int rowb = blockIdx.x * 64 + w * 16;
    const size_t abase = (size_t)(rowb + l15) * D + l4 * 8;

    // ---- phase 1: t = relu(h@W1 + bb1), store split bf16 to LDS ----
    {
        f32x4 acc[8];
        #pragma unroll
        for (int n = 0; n < 8; ++n) acc[n] = (f32x4){0.f, 0.f, 0.f, 0.f};
        #pragma unroll
        for (int kk = 0; kk < 4; ++kk) {
            bf16x8 ah = *(const bf16x8*)(hh + abase + kk * 32);
            bf16x8 al = *(const bf16x8*)(hl + abase + kk * 32);
            #pragma unroll
            for (int n = 0; n < 8; ++n) {
                size_t boff = (size_t)(n * 16 + l15) * D + l4 * 8 + kk * 32;
                bf16x8 bh = *(const bf16x8*)(w1th + boff);
                bf16x8 bl = *(const bf16x8*)(w1tl + boff);
                acc[n] = __builtin_amdgcn_mfma_f32_16x16x32_bf16(ah, bh, acc[n], 0, 0, 0);
                acc[n] = __builtin_amdgcn_mfma_f32_16x16x32_bf16(al, bh, acc[n], 0, 0, 0);
                acc[n] = __builtin_amdgcn_mfma_f32_16x16x32_bf16(ah, bl, acc[n], 0, 0, 0);
            }
        }
        #pragma unroll
        for (int n = 0; n < 8; ++n) {
            int col = n * 16 + l15;
            float bsv = bb1[col];
            #pragma unroll
            for (int r = 0; r < 4; ++r) {
                int lrow = w * 16 + l4 * 4 + r;
                float tv = fmaxf(acc[n][r] + bsv, 0.f);
                ushort hb = f2bf(tv);
                tsh[lrow][col] = hb;
                tsl[lrow][col] = f2bf(tv - bf2f(hb));
            }
        }
    }
    __syncthreads();

    // ---- phase 2: y = t@W2 + bb2; residual h; LN ----
    f32x4 acc[8];
    #pragma unroll
    for (int n = 0; n < 8; ++n) acc[n] = (f32x4){0.f, 0.f, 0.f, 0.f};
    #pragma unroll
    for (int kk = 0; kk < 4; ++kk) {
        bf16x8 ah = *(const bf16x8*)&tsh[w * 16 + l15][l4 * 8 + kk * 32];
        bf16x8 al = *(const bf16x8*)&tsl[w * 16 + l15][l4 * 8 + kk * 32];
        #pragma unroll
        for (int n = 0; n < 8; ++n) {
            size_t boff = (size_t)(n * 16 + l15) * D + l4 * 8 + kk * 32;
            bf16x8 bh = *(const bf16x8*)(w2th + boff);
            bf16x8 bl = *(const bf16x8*)(w2tl + boff);
            acc[n] = __builtin_amdgcn_mfma_f32_16x16x32_bf16(ah, bh, acc[n], 0, 0, 0);
            acc[n] = __builtin_amdgcn_mfma_f32_16x16x32_bf16(al, bh, acc[n], 0, 0, 0);
            acc[n] = __builtin_amdgcn_mfma_f32_16x16x32_bf16(ah, bl, acc[n], 0, 0, 0);
        }
    }

    float vals[8][4];
    #pragma unroll
    for (int n = 0; n < 8; ++n) {
        int col = n * 16 + l15;
        float bsv = bb2[col];
        #pragma unroll
        for (int r = 0; r < 4; ++r) {
            int row = rowb + l4 * 4 + r;
            float hr = 0.f;
            if (row < n_rows)
                hr = bf2f(hh[(size_t)row * D + col]) + bf2f(hl[(size_t)row * D + col]);
            vals[n][r] = acc[n][r] + bsv + hr;
        }
    }
    #pragma unroll
    for (int r = 0; r < 4; ++r) {
        int row = rowb + l4 * 4 + r;
        float s = 0.f, ss = 0.f;
        #pragma unroll
        for (int n = 0; n < 8; ++n) { s += vals[n][r]; ss += vals[n][r] * vals[n][r]; }
        #pragma unroll
        for (int msk = 1; msk <= 8; msk <<= 1) {
            s += __shfl_xor(s, msk);
            ss += __shfl_xor(ss, msk);
        }
        float mean = s * (1.0f / D);
        float var = ss * (1.0f / D) - mean * mean;
        float inv = rsqrtf(var + 1e-5f);
        if (row < n_rows) {
            #pragma unroll
            for (int n = 0; n < 8; ++n) {
                int col = n * 16 + l15;
                out[(size_t)row * D + col] = (vals[n][r] - mean) * inv * g2[col] + be2[col];
            }
        }
    }
}

// ---------------- launch ----------------

extern "C" void kernel_launch(void* const* d_in, const int* in_sizes, int n_in,
                              void* d_out, int out_size, void* d_ws, size_t ws_size,
                              hipStream_t stream) {
    const float* x     = (const float*)d_in[0];
    const int*   idx_i = (const int*)d_in[1];
    const int*   idx_j = (const int*)d_in[2];
    const float* Wq = (const float*)d_in[3];
    const float* bq = (const float*)d_in[4];
    const float* Wk = (const float*)d_in[5];
    const float* bk = (const float*)d_in[6];
    const float* Wv = (const float*)d_in[7];
    const float* bv = (const float*)d_in[8];
    const float* Wo = (const float*)d_in[9];
    const float* bo = (const float*)d_in[10];
    const float* g1 = (const float*)d_in[11];
    const float* be1 = (const float*)d_in[12];
    const float* W1 = (const float*)d_in[13];
    const float* bb1 = (const float*)d_in[14];
    const float* W2 = (const float*)d_in[15];
    const float* bb2 = (const float*)d_in[16];
    const float* g2 = (const float*)d_in[17];
    const float* be2 = (const float*)d_in[18];

    const int N_ = in_sizes[0] / D;
    const int E_ = in_sizes[1];
    const size_t ND = (size_t)N_ * D;

    float* ws = (float*)d_ws;
    float* q = ws;                 // N*D f32 (later reused as hh/hl bf16 split)
    float* k = q + ND;             // N*D f32
    float* v = k + ND;             // N*D f32
    int* count     = (int*)(v + ND);       // N
    int* row_start = count + N_;           // N+1
    int* cursor    = row_start + N_ + 1;   // N
    int* ejs       = cursor + N_;          // E
    ushort* xh = (ushort*)(ejs + E_);      // N*D bf16 (later reused as aggh)
    ushort* xl = xh + ND;                  // N*D bf16 (later reused as aggl)
    ushort* wth = xl + ND;                 // 6*128*128
    ushort* wtl = wth + 6 * 16384;         // 6*128*128
    // aliases (non-overlapping lifetimes)
    ushort* aggh = xh;
    ushort* aggl = xl;
    ushort* hh = (ushort*)q;
    ushort* hl = hh + ND;

    zero_kernel<<<(N_ + 255) / 256, 256, 0, stream>>>(count, N_);
    prep_x_kernel<<<((int)(ND / 4) + 255) / 256, 256, 0, stream>>>(x, xh, xl, (int)(ND / 4));
    prep_w_kernel<<<6, 256, 0, stream>>>(Wq, Wk, Wv, Wo, W1, W2, wth, wtl);
    qkv_mfma_kernel<<<(N_ + 63) / 64, 256, 0, stream>>>(xh, xl, wth, wtl,
                                                        bq, bk, bv, q, k, v, N_);
    hist_kernel<<<(E_ + 255) / 256, 256, 0, stream>>>(idx_i, count, E_);
    scan_kernel<<<1, 1024, 0, stream>>>(count, row_start, cursor, N_);
    scatter_kernel<<<(E_ + 255) / 256, 256, 0, stream>>>(idx_i, idx_j, cursor, ejs, E_);
    fused_agg_kernel<<<(N_ + 3) / 4, 256, 0, stream>>>(q, k, v, row_start, ejs,
                                                       aggh, aggl, N_);
    oproj_mfma_kernel<<<(N_ + 63) / 64, 256, 0, stream>>>(aggh, aggl, x,
                                                          wth + 3 * 16384, wtl + 3 * 16384,
                                                          bo, g1, be1, hh, hl, N_);
    ffn_mfma_kernel<<<(N_ + 63) / 64, 256, 0, stream>>>(hh, hl,
                                                        wth + 4 * 16384, wtl + 4 * 16384,
                                                        wth + 5 * 16384, wtl + 5 * 16384,
                                                        bb1, bb2, g2, be2,
                                                        (float*)d_out, N_);
}

// Round 5
// 475.419 us; speedup vs baseline: 3.9300x; 1.0782x over previous
//
#include <hip/hip_runtime.h>
#include <hip/hip_bf16.h>
#include <math.h>

#define D 128
#define H 8
#define DH 16
#define SCAN_CHUNK 1024

typedef __attribute__((ext_vector_type(8))) short bf16x8;
typedef __attribute__((ext_vector_type(4))) float f32x4;

__device__ __forceinline__ float bf2f(ushort u) {
    unsigned int x = ((unsigned int)u) << 16;
    float f;
    __builtin_memcpy(&f, &x, 4);
    return f;
}
__device__ __forceinline__ ushort f2bf(float f) {
    __hip_bfloat16 h = __float2bfloat16(f);
    ushort u;
    __builtin_memcpy(&u, &h, 2);
    return u;
}

// ---------------- K0: zero histogram ----------------

__global__ __launch_bounds__(256) void zero_kernel(int* __restrict__ count, int n) {
    int gid = blockIdx.x * blockDim.x + threadIdx.x;
    if (gid < n) count[gid] = 0;
}

// ---------------- prep_x: split x into bf16 hi/lo ----------------

__global__ __launch_bounds__(256) void prep_x_kernel(
    const float* __restrict__ x, ushort* __restrict__ xh, ushort* __restrict__ xl,
    int total4)
{
    int gid = blockIdx.x * blockDim.x + threadIdx.x;
    if (gid >= total4) return;
    float4 v = ((const float4*)x)[gid];
    ushort4 hv, lv;
    hv.x = f2bf(v.x); lv.x = f2bf(v.x - bf2f(hv.x));
    hv.y = f2bf(v.y); lv.y = f2bf(v.y - bf2f(hv.y));
    hv.z = f2bf(v.z); lv.z = f2bf(v.z - bf2f(hv.z));
    hv.w = f2bf(v.w); lv.w = f2bf(v.w - bf2f(hv.w));
    ((ushort4*)xh)[gid] = hv;
    ((ushort4*)xl)[gid] = lv;
}

// ---------------- prep_w: transpose + split 6 weight matrices ----------------

__global__ __launch_bounds__(256) void prep_w_kernel(
    const float* __restrict__ w0, const float* __restrict__ w1,
    const float* __restrict__ w2, const float* __restrict__ w3,
    const float* __restrict__ w4, const float* __restrict__ w5,
    ushort* __restrict__ wth, ushort* __restrict__ wtl)
{
    __shared__ __align__(16) float tile[128][132];
    const int m = blockIdx.x;
    const float* W = (m == 0) ? w0 : (m == 1) ? w1 : (m == 2) ? w2
                   : (m == 3) ? w3 : (m == 4) ? w4 : w5;
    const int t = threadIdx.x;
    const float4* wg = (const float4*)W;
    #pragma unroll
    for (int it = 0; it < 16; ++it) {
        int f4 = t + it * 256;
        int k = f4 >> 5, c4 = f4 & 31;
        *((float4*)&tile[k][c4 * 4]) = wg[f4];
    }
    __syncthreads();
    ushort* oh = wth + m * 16384;
    ushort* ol = wtl + m * 16384;
    #pragma unroll
    for (int it = 0; it < 64; ++it) {
        int idx = t + it * 256;
        int c = idx >> 7, k = idx & 127;
        float v = tile[k][c];
        ushort hb = f2bf(v);
        oh[idx] = hb;
        ol[idx] = f2bf(v - bf2f(hb));
    }
}

// ---------------- qkv: [N,128]@[128,128]x3 via split-bf16 MFMA ----------------

__global__ __launch_bounds__(256) void qkv_mfma_kernel(
    const ushort* __restrict__ xh, const ushort* __restrict__ xl,
    const ushort* __restrict__ wth, const ushort* __restrict__ wtl,
    const float* __restrict__ bq, const float* __restrict__ bk,
    const float* __restrict__ bv,
    float* __restrict__ q, float* __restrict__ k, float* __restrict__ v,
    int n_rows)
{
    const int t = threadIdx.x;
    const int w = t >> 6, l = t & 63;
    const int l15 = l & 15, l4 = l >> 4;
    const int rowb = blockIdx.x * 64 + w * 16;
    const size_t abase = (size_t)(rowb + l15) * D + l4 * 8;

    float* outs[3] = {q, k, v};
    const float* biases[3] = {bq, bk, bv};

    #pragma unroll
    for (int m = 0; m < 3; ++m) {
        const ushort* bh_ = wth + m * 16384;
        const ushort* bl_ = wtl + m * 16384;
        f32x4 acc[8];
        #pragma unroll
        for (int n = 0; n < 8; ++n) acc[n] = (f32x4){0.f, 0.f, 0.f, 0.f};

        #pragma unroll
        for (int kk = 0; kk < 4; ++kk) {
            bf16x8 ah = *(const bf16x8*)(xh + abase + kk * 32);
            bf16x8 al = *(const bf16x8*)(xl + abase + kk * 32);
            #pragma unroll
            for (int n = 0; n < 8; ++n) {
                size_t boff = (size_t)(n * 16 + l15) * D + l4 * 8 + kk * 32;
                bf16x8 bh = *(const bf16x8*)(bh_ + boff);
                bf16x8 bl = *(const bf16x8*)(bl_ + boff);
                acc[n] = __builtin_amdgcn_mfma_f32_16x16x32_bf16(ah, bh, acc[n], 0, 0, 0);
                acc[n] = __builtin_amdgcn_mfma_f32_16x16x32_bf16(al, bh, acc[n], 0, 0, 0);
                acc[n] = __builtin_amdgcn_mfma_f32_16x16x32_bf16(ah, bl, acc[n], 0, 0, 0);
            }
        }
        float* out = outs[m];
        const float* bias = biases[m];
        #pragma unroll
        for (int n = 0; n < 8; ++n) {
            int col = n * 16 + l15;
            float bsv = bias[col];
            #pragma unroll
            for (int r = 0; r < 4; ++r) {
                int row = rowb + l4 * 4 + r;
                if (row < n_rows)
                    out[(size_t)row * D + col] = acc[n][r] + bsv;
            }
        }
    }
}

// ---------------- CSR build ----------------

__global__ __launch_bounds__(256) void hist_kernel(
    const int* __restrict__ idx_i, int* __restrict__ count, int n_edges)
{
    int e = blockIdx.x * blockDim.x + threadIdx.x;
    if (e < n_edges) atomicAdd(&count[idx_i[e]], 1);
}

// two-level parallel scan: (a) per-1024-chunk reduce, (b) single-wave scan of
// chunk sums (requires nb <= 64, i.e. n <= 65536), (c) parallel prefix write.

__global__ __launch_bounds__(256) void scan_reduce_kernel(
    const int* __restrict__ count, int* __restrict__ bsum, int n)
{
    __shared__ int wsum[4];
    const int t = threadIdx.x, lane = t & 63, w = t >> 6;
    int base = blockIdx.x * SCAN_CHUNK + t * 4;
    int s = 0;
    #pragma unroll
    for (int i = 0; i < 4; ++i) {
        int idx = base + i;
        if (idx < n) s += count[idx];
    }
    #pragma unroll
    for (int off = 1; off < 64; off <<= 1) s += __shfl_xor(s, off);
    if (lane == 0) wsum[w] = s;
    __syncthreads();
    if (t == 0) bsum[blockIdx.x] = wsum[0] + wsum[1] + wsum[2] + wsum[3];
}

__global__ __launch_bounds__(64) void scan_bsum_kernel(
    int* __restrict__ bsum, int* __restrict__ row_start, int nb, int n)
{
    const int t = threadIdx.x;
    int iv = (t < nb) ? bsum[t] : 0;
    int vv = iv;
    #pragma unroll
    for (int off = 1; off < 64; off <<= 1) {
        int u = __shfl_up(vv, off);
        if (t >= off) vv += u;
    }
    if (t < nb) bsum[t] = vv - iv;     // exclusive
    if (t == 63) row_start[n] = vv;    // grand total
}

__global__ __launch_bounds__(256) void scan_write_kernel(
    const int* __restrict__ count, const int* __restrict__ bsum,
    int* __restrict__ row_start, int* __restrict__ cursor, int n)
{
    __shared__ int wtot[4];
    const int t = threadIdx.x, lane = t & 63, w = t >> 6;
    int base = blockIdx.x * SCAN_CHUNK + t * 4;
    int c0 = 0, c1 = 0, c2 = 0, c3 = 0;
    if (base + 0 < n) c0 = count[base + 0];
    if (base + 1 < n) c1 = count[base + 1];
    if (base + 2 < n) c2 = count[base + 2];
    if (base + 3 < n) c3 = count[base + 3];
    int tsum = c0 + c1 + c2 + c3;
    int inc = tsum;
    #pragma unroll
    for (int off = 1; off < 64; off <<= 1) {
        int u = __shfl_up(inc, off);
        if (lane >= off) inc += u;
    }
    if (lane == 63) wtot[w] = inc;
    __syncthreads();
    int wb = 0;
    for (int i = 0; i < w; ++i) wb += wtot[i];
    int start = bsum[blockIdx.x] + wb + inc - tsum;
    if (base + 0 < n) { row_start[base + 0] = start;            cursor[base + 0] = start; }
    if (base + 1 < n) { row_start[base + 1] = start + c0;       cursor[base + 1] = start + c0; }
    if (base + 2 < n) { row_start[base + 2] = start + c0 + c1;  cursor[base + 2] = start + c0 + c1; }
    if (base + 3 < n) { row_start[base + 3] = start + c0 + c1 + c2; cursor[base + 3] = start + c0 + c1 + c2; }
}

__global__ __launch_bounds__(256) void scatter_kernel(
    const int* __restrict__ idx_i, const int* __restrict__ idx_j,
    int* __restrict__ cursor, int* __restrict__ ejs, int n_edges)
{
    int e = blockIdx.x * blockDim.x + threadIdx.x;
    if (e < n_edges) {
        int i = idx_i[e];
        int pos = atomicAdd(&cursor[i], 1);
        ejs[pos] = idx_j[e];
    }
}

// ---------------- fused per-node attention (online softmax, 2-edge ILP) ----------------
// one wave per node; lane holds floats [2*lane, 2*lane+1]; head h = lanes 8h..8h+7.
// scores kept in log2 domain so exp2f maps to bare v_exp_f32.

__global__ __launch_bounds__(256) void fused_agg_kernel(
    const float* __restrict__ q, const float* __restrict__ k,
    const float* __restrict__ v, const int* __restrict__ row_start,
    const int* __restrict__ ejs,
    ushort* __restrict__ aggh, ushort* __restrict__ aggl, int n_nodes)
{
    const int lane = threadIdx.x & 63;
    const int node = (blockIdx.x * blockDim.x + threadIdx.x) >> 6;
    if (node >= n_nodes) return;
    const int beg = row_start[node], end = row_start[node + 1];
    const int c2 = lane * 2;
    const float2 qv = *(const float2*)&q[(size_t)node * D + c2];
    const float SC = 0.25f * 1.4426950408889634f;  // 1/sqrt(DH) * log2(e)
    float m = -INFINITY, l = 0.f, ax = 0.f, ay = 0.f;

    float2 kc0, vc0, kc1, vc1;
    int p = beg;
    if (p < end) {
        int j = ejs[p];
        kc0 = *(const float2*)&k[(size_t)j * D + c2];
        vc0 = *(const float2*)&v[(size_t)j * D + c2];
    }
    if (p + 1 < end) {
        int j = ejs[p + 1];
        kc1 = *(const float2*)&k[(size_t)j * D + c2];
        vc1 = *(const float2*)&v[(size_t)j * D + c2];
    }
    while (p + 1 < end) {
        float2 ka = kc0, va = vc0, kb = kc1, vb = vc1;
        int np = p + 2;
        if (np < end) {
            int j = ejs[np];
            kc0 = *(const float2*)&k[(size_t)j * D + c2];
            vc0 = *(const float2*)&v[(size_t)j * D + c2];
        }
        if (np + 1 < end) {
            int j = ejs[np + 1];
            kc1 = *(const float2*)&k[(size_t)j * D + c2];
            vc1 = *(const float2*)&v[(size_t)j * D + c2];
        }
        float d1 = qv.x * ka.x + qv.y * ka.y;
        float d2 = qv.x * kb.x + qv.y * kb.y;
        d1 += __shfl_xor(d1, 1);  d2 += __shfl_xor(d2, 1);
        d1 += __shfl_xor(d1, 2);  d2 += __shfl_xor(d2, 2);
        d1 += __shfl_xor(d1, 4);  d2 += __shfl_xor(d2, 4);
        float s1 = d1 * SC, s2 = d2 * SC;
        float mn = fmaxf(m, fmaxf(s1, s2));
        float c  = exp2f(m - mn);
        float p1 = exp2f(s1 - mn);
        float p2 = exp2f(s2 - mn);
        l  = l * c + p1 + p2;
        ax = ax * c + p1 * va.x + p2 * vb.x;
        ay = ay * c + p1 * va.y + p2 * vb.y;
        m = mn;
        p = np;
    }
    if (p < end) {   // odd tail: kc0/vc0 hold edge p
        float d1 = qv.x * kc0.x + qv.y * kc0.y;
        d1 += __shfl_xor(d1, 1);
        d1 += __shfl_xor(d1, 2);
        d1 += __shfl_xor(d1, 4);
        float s1 = d1 * SC;
        float mn = fmaxf(m, s1);
        float c  = exp2f(m - mn);
        float p1 = exp2f(s1 - mn);
        l  = l * c + p1;
        ax = ax * c + p1 * vc0.x;
        ay = ay * c + p1 * vc0.y;
    }
    float invl = (l > 0.f) ? (1.0f / l) : 0.f;
    float ox = ax * invl, oy = ay * invl;
    ushort hx = f2bf(ox); ushort lx = f2bf(ox - bf2f(hx));
    ushort hy = f2bf(oy); ushort ly = f2bf(oy - bf2f(hy));
    ((unsigned int*)aggh)[(size_t)node * 64 + lane] = (unsigned int)hx | ((unsigned int)hy << 16);
    ((unsigned int*)aggl)[(size_t)node * 64 + lane] = (unsigned int)lx | ((unsigned int)ly << 16);
}

// ---------------- oproj + LN1: h = LN(x + agg@Wo + bo) -> bf16 split ----------------

__global__ __launch_bounds__(256) void oproj_mfma_kernel(
    const ushort* __restrict__ aggh, const ushort* __restrict__ aggl,
    const float* __restrict__ x,
    const ushort* __restrict__ wth, const ushort* __restrict__ wtl,
    const float* __restrict__ bo, const float* __restrict__ g1,
    const float* __restrict__ be1,
    ushort* __restrict__ hh, ushort* __restrict__ hl, int n_rows)
{
    const int t = threadIdx.x;
    const int w = t >> 6, l = t & 63;
    const int l15 = l & 15, l4 = l >> 4;
    const int rowb = blockIdx.x * 64 + w * 16;
    const size_t abase = (size_t)(rowb + l15) * D + l4 * 8;

    f32x4 acc[8];
    #pragma unroll
    for (int n = 0; n < 8; ++n) acc[n] = (f32x4){0.f, 0.f, 0.f, 0.f};

    #pragma unroll
    for (int kk = 0; kk < 4; ++kk) {
        bf16x8 ah = *(const bf16x8*)(aggh + abase + kk * 32);
        bf16x8 al = *(const bf16x8*)(aggl + abase + kk * 32);
        #pragma unroll
        for (int n = 0; n < 8; ++n) {
            size_t boff = (size_t)(n * 16 + l15) * D + l4 * 8 + kk * 32;
            bf16x8 bh = *(const bf16x8*)(wth + boff);
            bf16x8 bl = *(const bf16x8*)(wtl + boff);
            acc[n] = __builtin_amdgcn_mfma_f32_16x16x32_bf16(ah, bh, acc[n], 0, 0, 0);
            acc[n] = __builtin_amdgcn_mfma_f32_16x16x32_bf16(al, bh, acc[n], 0, 0, 0);
            acc[n] = __builtin_amdgcn_mfma_f32_16x16x32_bf16(ah, bl, acc[n], 0, 0, 0);
        }
    }

    float vals[8][4];
    #pragma unroll
    for (int n = 0; n < 8; ++n) {
        int col = n * 16 + l15;
        float bsv = bo[col];
        #pragma unroll
        for (int r = 0; r < 4; ++r) {
            int row = rowb + l4 * 4 + r;
            float xr = (row < n_rows) ? x[(size_t)row * D + col] : 0.f;
            vals[n][r] = acc[n][r] + bsv + xr;
        }
    }
    #pragma unroll
    for (int r = 0; r < 4; ++r) {
        int row = rowb + l4 * 4 + r;
        float s = 0.f, ss = 0.f;
        #pragma unroll
        for (int n = 0; n < 8; ++n) { s += vals[n][r]; ss += vals[n][r] * vals[n][r]; }
        #pragma unroll
        for (int msk = 1; msk <= 8; msk <<= 1) {
            s += __shfl_xor(s, msk);
            ss += __shfl_xor(ss, msk);
        }
        float mean = s * (1.0f / D);
        float var = ss * (1.0f / D) - mean * mean;
        float inv = rsqrtf(var + 1e-5f);
        if (row < n_rows) {
            #pragma unroll
            for (int n = 0; n < 8; ++n) {
                int col = n * 16 + l15;
                float y = (vals[n][r] - mean) * inv * g1[col] + be1[col];
                ushort hb = f2bf(y);
                hh[(size_t)row * D + col] = hb;
                hl[(size_t)row * D + col] = f2bf(y - bf2f(hb));
            }
        }
    }
}

// ---------------- FFN + LN2: out = LN(h + relu(h@W1+b1)@W2 + b2) ----------------

__global__ __launch_bounds__(256) void ffn_mfma_kernel(
    const ushort* __restrict__ hh, const ushort* __restrict__ hl,
    const ushort* __restrict__ w1th, const ushort* __restrict__ w1tl,
    const ushort* __restrict__ w2th, const ushort* __restrict__ w2tl,
    const float* __restrict__ bb1, const float* __restrict__ bb2,
    const float* __restrict__ g2, const float* __restrict__ be2,
    float* __restrict__ out, int n_rows)
{
    __shared__ __align__(16) ushort tsh[64][136];
    __shared__ __align__(16) ushort tsl[64][136];
    const int t = threadIdx.x;
    const int w = t >> 6, l = t & 63;
    const int l15 = l & 15, l4 = l >> 4;
    const int rowb = blockIdx.x * 64 + w * 16;
    const size_t abase = (size_t)(rowb + l15) * D + l4 * 8;

    {
        f32x4 acc[8];
        #pragma unroll
        for (int n = 0; n < 8; ++n) acc[n] = (f32x4){0.f, 0.f, 0.f, 0.f};
        #pragma unroll
        for (int kk = 0; kk < 4; ++kk) {
            bf16x8 ah = *(const bf16x8*)(hh + abase + kk * 32);
            bf16x8 al = *(const bf16x8*)(hl + abase + kk * 32);
            #pragma unroll
            for (int n = 0; n < 8; ++n) {
                size_t boff = (size_t)(n * 16 + l15) * D + l4 * 8 + kk * 32;
                bf16x8 bh = *(const bf16x8*)(w1th + boff);
                bf16x8 bl = *(const bf16x8*)(w1tl + boff);
                acc[n] = __builtin_amdgcn_mfma_f32_16x16x32_bf16(ah, bh, acc[n], 0, 0, 0);
                acc[n] = __builtin_amdgcn_mfma_f32_16x16x32_bf16(al, bh, acc[n], 0, 0, 0);
                acc[n] = __builtin_amdgcn_mfma_f32_16x16x32_bf16(ah, bl, acc[n], 0, 0, 0);
            }
        }
        #pragma unroll
        for (int n = 0; n < 8; ++n) {
            int col = n * 16 + l15;
            float bsv = bb1[col];
            #pragma unroll
            for (int r = 0; r < 4; ++r) {
                int lrow = w * 16 + l4 * 4 + r;
                float tv = fmaxf(acc[n][r] + bsv, 0.f);
                ushort hb = f2bf(tv);
                tsh[lrow][col] = hb;
                tsl[lrow][col] = f2bf(tv - bf2f(hb));
            }
        }
    }
    __syncthreads();

    f32x4 acc[8];
    #pragma unroll
    for (int n = 0; n < 8; ++n) acc[n] = (f32x4){0.f, 0.f, 0.f, 0.f};
    #pragma unroll
    for (int kk = 0; kk < 4; ++kk) {
        bf16x8 ah = *(const bf16x8*)&tsh[w * 16 + l15][l4 * 8 + kk * 32];
        bf16x8 al = *(const bf16x8*)&tsl[w * 16 + l15][l4 * 8 + kk * 32];
        #pragma unroll
        for (int n = 0; n < 8; ++n) {
            size_t boff = (size_t)(n * 16 + l15) * D + l4 * 8 + kk * 32;
            bf16x8 bh = *(const bf16x8*)(w2th + boff);
            bf16x8 bl = *(const bf16x8*)(w2tl + boff);
            acc[n] = __builtin_amdgcn_mfma_f32_16x16x32_bf16(ah, bh, acc[n], 0, 0, 0);
            acc[n] = __builtin_amdgcn_mfma_f32_16x16x32_bf16(al, bh, acc[n], 0, 0, 0);
            acc[n] = __builtin_amdgcn_mfma_f32_16x16x32_bf16(ah, bl, acc[n], 0, 0, 0);
        }
    }

    float vals[8][4];
    #pragma unroll
    for (int n = 0; n < 8; ++n) {
        int col = n * 16 + l15;
        float bsv = bb2[col];
        #pragma unroll
        for (int r = 0; r < 4; ++r) {
            int row = rowb + l4 * 4 + r;
            float hr = 0.f;
            if (row < n_rows)
                hr = bf2f(hh[(size_t)row * D + col]) + bf2f(hl[(size_t)row * D + col]);
            vals[n][r] = acc[n][r] + bsv + hr;
        }
    }
    #pragma unroll
    for (int r = 0; r < 4; ++r) {
        int row = rowb + l4 * 4 + r;
        float s = 0.f, ss = 0.f;
        #pragma unroll
        for (int n = 0; n < 8; ++n) { s += vals[n][r]; ss += vals[n][r] * vals[n][r]; }
        #pragma unroll
        for (int msk = 1; msk <= 8; msk <<= 1) {
            s += __shfl_xor(s, msk);
            ss += __shfl_xor(ss, msk);
        }
        float mean = s * (1.0f / D);
        float var = ss * (1.0f / D) - mean * mean;
        float inv = rsqrtf(var + 1e-5f);
        if (row < n_rows) {
            #pragma unroll
            for (int n = 0; n < 8; ++n) {
                int col = n * 16 + l15;
                out[(size_t)row * D + col] = (vals[n][r] - mean) * inv * g2[col] + be2[col];
            }
        }
    }
}

// ---------------- launch ----------------

extern "C" void kernel_launch(void* const* d_in, const int* in_sizes, int n_in,
                              void* d_out, int out_size, void* d_ws, size_t ws_size,
                              hipStream_t stream) {
    const float* x     = (const float*)d_in[0];
    const int*   idx_i = (const int*)d_in[1];
    const int*   idx_j = (const int*)d_in[2];
    const float* Wq = (const float*)d_in[3];
    const float* bq = (const float*)d_in[4];
    const float* Wk = (const float*)d_in[5];
    const float* bk = (const float*)d_in[6];
    const float* Wv = (const float*)d_in[7];
    const float* bv = (const float*)d_in[8];
    const float* Wo = (const float*)d_in[9];
    const float* bo = (const float*)d_in[10];
    const float* g1 = (const float*)d_in[11];
    const float* be1 = (const float*)d_in[12];
    const float* W1 = (const float*)d_in[13];
    const float* bb1 = (const float*)d_in[14];
    const float* W2 = (const float*)d_in[15];
    const float* bb2 = (const float*)d_in[16];
    const float* g2 = (const float*)d_in[17];
    const float* be2 = (const float*)d_in[18];

    const int N_ = in_sizes[0] / D;
    const int E_ = in_sizes[1];
    const size_t ND = (size_t)N_ * D;
    const int nb = (N_ + SCAN_CHUNK - 1) / SCAN_CHUNK;   // 49 for N=50000 (<=64 required)

    float* ws = (float*)d_ws;
    float* q = ws;                 // N*D f32 (later reused as hh/hl bf16 split)
    float* k = q + ND;             // N*D f32
    float* v = k + ND;             // N*D f32
    int* count     = (int*)(v + ND);       // N
    int* row_start = count + N_;           // N+1
    int* cursor    = row_start + N_ + 1;   // N
    int* bsum      = cursor + N_;          // 64
    int* ejs       = bsum + 64;            // E
    ushort* xh = (ushort*)(ejs + E_);      // N*D bf16 (later reused as aggh)
    ushort* xl = xh + ND;                  // N*D bf16 (later reused as aggl)
    ushort* wth = xl + ND;                 // 6*128*128
    ushort* wtl = wth + 6 * 16384;         // 6*128*128
    ushort* aggh = xh;
    ushort* aggl = xl;
    ushort* hh = (ushort*)q;
    ushort* hl = hh + ND;

    zero_kernel<<<(N_ + 255) / 256, 256, 0, stream>>>(count, N_);
    prep_x_kernel<<<((int)(ND / 4) + 255) / 256, 256, 0, stream>>>(x, xh, xl, (int)(ND / 4));
    prep_w_kernel<<<6, 256, 0, stream>>>(Wq, Wk, Wv, Wo, W1, W2, wth, wtl);
    qkv_mfma_kernel<<<(N_ + 63) / 64, 256, 0, stream>>>(xh, xl, wth, wtl,
                                                        bq, bk, bv, q, k, v, N_);
    hist_kernel<<<(E_ + 255) / 256, 256, 0, stream>>>(idx_i, count, E_);
    scan_reduce_kernel<<<nb, 256, 0, stream>>>(count, bsum, N_);
    scan_bsum_kernel<<<1, 64, 0, stream>>>(bsum, row_start, nb, N_);
    scan_write_kernel<<<nb, 256, 0, stream>>>(count, bsum, row_start, cursor, N_);
    scatter_kernel<<<(E_ + 255) / 256, 256, 0, stream>>>(idx_i, idx_j, cursor, ejs, E_);
    fused_agg_kernel<<<(N_ + 3) / 4, 256, 0, stream>>>(q, k, v, row_start, ejs,
                                                       aggh, aggl, N_);
    oproj_mfma_kernel<<<(N_ + 63) / 64, 256, 0, stream>>>(aggh, aggl, x,
                                                          wth + 3 * 16384, wtl + 3 * 16384,
                                                          bo, g1, be1, hh, hl, N_);
    ffn_mfma_kernel<<<(N_ + 63) / 64, 256, 0, stream>>>(hh, hl,
                                                        wth + 4 * 16384, wtl + 4 * 16384,
                                                        wth + 5 * 16384, wtl + 5 * 16384,
                                                        bb1, bb2, g2, be2,
                                                        (float*)d_out, N_);
}

// Round 6
// 430.184 us; speedup vs baseline: 4.3432x; 1.1052x over previous
//
#include <hip/hip_runtime.h>
#include <hip/hip_bf16.h>
#include <math.h>

#define D 128
#define H 8
#define DH 16
#define SCAN_CHUNK 1024

typedef __attribute__((ext_vector_type(8))) short bf16x8;
typedef __attribute__((ext_vector_type(4))) float f32x4;

__device__ __forceinline__ float bf2f(ushort u) {
    unsigned int x = ((unsigned int)u) << 16;
    float f;
    __builtin_memcpy(&f, &x, 4);
    return f;
}
__device__ __forceinline__ ushort f2bf(float f) {
    __hip_bfloat16 h = __float2bfloat16(f);
    ushort u;
    __builtin_memcpy(&u, &h, 2);
    return u;
}

// ---------------- K0: zero histogram ----------------

__global__ __launch_bounds__(256) void zero_kernel(int* __restrict__ count, int n) {
    int gid = blockIdx.x * blockDim.x + threadIdx.x;
    if (gid < n) count[gid] = 0;
}

// ---------------- prep_x: split x into bf16 hi/lo ----------------

__global__ __launch_bounds__(256) void prep_x_kernel(
    const float* __restrict__ x, ushort* __restrict__ xh, ushort* __restrict__ xl,
    int total4)
{
    int gid = blockIdx.x * blockDim.x + threadIdx.x;
    if (gid >= total4) return;
    float4 v = ((const float4*)x)[gid];
    ushort4 hv, lv;
    hv.x = f2bf(v.x); lv.x = f2bf(v.x - bf2f(hv.x));
    hv.y = f2bf(v.y); lv.y = f2bf(v.y - bf2f(hv.y));
    hv.z = f2bf(v.z); lv.z = f2bf(v.z - bf2f(hv.z));
    hv.w = f2bf(v.w); lv.w = f2bf(v.w - bf2f(hv.w));
    ((ushort4*)xh)[gid] = hv;
    ((ushort4*)xl)[gid] = lv;
}

// ---------------- prep_w: transpose + split 6 weight matrices ----------------

__global__ __launch_bounds__(256) void prep_w_kernel(
    const float* __restrict__ w0, const float* __restrict__ w1,
    const float* __restrict__ w2, const float* __restrict__ w3,
    const float* __restrict__ w4, const float* __restrict__ w5,
    ushort* __restrict__ wth, ushort* __restrict__ wtl)
{
    __shared__ __align__(16) float tile[128][132];
    const int m = blockIdx.x;
    const float* W = (m == 0) ? w0 : (m == 1) ? w1 : (m == 2) ? w2
                   : (m == 3) ? w3 : (m == 4) ? w4 : w5;
    const int t = threadIdx.x;
    const float4* wg = (const float4*)W;
    #pragma unroll
    for (int it = 0; it < 16; ++it) {
        int f4 = t + it * 256;
        int k = f4 >> 5, c4 = f4 & 31;
        *((float4*)&tile[k][c4 * 4]) = wg[f4];
    }
    __syncthreads();
    ushort* oh = wth + m * 16384;
    ushort* ol = wtl + m * 16384;
    #pragma unroll
    for (int it = 0; it < 64; ++it) {
        int idx = t + it * 256;
        int c = idx >> 7, k = idx & 127;
        float v = tile[k][c];
        ushort hb = f2bf(v);
        oh[idx] = hb;
        ol[idx] = f2bf(v - bf2f(hb));
    }
}

// ---------------- qkv: [N,128]@[128,128]x3 via split-bf16 MFMA ----------------
// q written f32; k,v written bf16 (consumed by the gather phase).

__global__ __launch_bounds__(256) void qkv_mfma_kernel(
    const ushort* __restrict__ xh, const ushort* __restrict__ xl,
    const ushort* __restrict__ wth, const ushort* __restrict__ wtl,
    const float* __restrict__ bq, const float* __restrict__ bk,
    const float* __restrict__ bv,
    float* __restrict__ q, ushort* __restrict__ k16, ushort* __restrict__ v16,
    int n_rows)
{
    const int t = threadIdx.x;
    const int w = t >> 6, l = t & 63;
    const int l15 = l & 15, l4 = l >> 4;
    const int rowb = blockIdx.x * 64 + w * 16;
    const size_t abase = (size_t)(rowb + l15) * D + l4 * 8;

    const float* biases[3] = {bq, bk, bv};

    #pragma unroll
    for (int m = 0; m < 3; ++m) {
        const ushort* bh_ = wth + m * 16384;
        const ushort* bl_ = wtl + m * 16384;
        f32x4 acc[8];
        #pragma unroll
        for (int n = 0; n < 8; ++n) acc[n] = (f32x4){0.f, 0.f, 0.f, 0.f};

        #pragma unroll
        for (int kk = 0; kk < 4; ++kk) {
            bf16x8 ah = *(const bf16x8*)(xh + abase + kk * 32);
            bf16x8 al = *(const bf16x8*)(xl + abase + kk * 32);
            #pragma unroll
            for (int n = 0; n < 8; ++n) {
                size_t boff = (size_t)(n * 16 + l15) * D + l4 * 8 + kk * 32;
                bf16x8 bh = *(const bf16x8*)(bh_ + boff);
                bf16x8 bl = *(const bf16x8*)(bl_ + boff);
                acc[n] = __builtin_amdgcn_mfma_f32_16x16x32_bf16(ah, bh, acc[n], 0, 0, 0);
                acc[n] = __builtin_amdgcn_mfma_f32_16x16x32_bf16(al, bh, acc[n], 0, 0, 0);
                acc[n] = __builtin_amdgcn_mfma_f32_16x16x32_bf16(ah, bl, acc[n], 0, 0, 0);
            }
        }
        const float* bias = biases[m];
        #pragma unroll
        for (int n = 0; n < 8; ++n) {
            int col = n * 16 + l15;
            float bsv = bias[col];
            #pragma unroll
            for (int r = 0; r < 4; ++r) {
                int row = rowb + l4 * 4 + r;
                if (row < n_rows) {
                    float val = acc[n][r] + bsv;
                    if (m == 0) q[(size_t)row * D + col] = val;
                    else if (m == 1) k16[(size_t)row * D + col] = f2bf(val);
                    else v16[(size_t)row * D + col] = f2bf(val);
                }
            }
        }
    }
}

// ---------------- CSR build ----------------

__global__ __launch_bounds__(256) void hist_kernel(
    const int* __restrict__ idx_i, int* __restrict__ count, int n_edges)
{
    int e = blockIdx.x * blockDim.x + threadIdx.x;
    if (e < n_edges) atomicAdd(&count[idx_i[e]], 1);
}

__global__ __launch_bounds__(256) void scan_reduce_kernel(
    const int* __restrict__ count, int* __restrict__ bsum, int n)
{
    __shared__ int wsum[4];
    const int t = threadIdx.x, lane = t & 63, w = t >> 6;
    int base = blockIdx.x * SCAN_CHUNK + t * 4;
    int s = 0;
    #pragma unroll
    for (int i = 0; i < 4; ++i) {
        int idx = base + i;
        if (idx < n) s += count[idx];
    }
    #pragma unroll
    for (int off = 1; off < 64; off <<= 1) s += __shfl_xor(s, off);
    if (lane == 0) wsum[w] = s;
    __syncthreads();
    if (t == 0) bsum[blockIdx.x] = wsum[0] + wsum[1] + wsum[2] + wsum[3];
}

__global__ __launch_bounds__(64) void scan_bsum_kernel(
    int* __restrict__ bsum, int* __restrict__ row_start, int nb, int n)
{
    const int t = threadIdx.x;
    int iv = (t < nb) ? bsum[t] : 0;
    int vv = iv;
    #pragma unroll
    for (int off = 1; off < 64; off <<= 1) {
        int u = __shfl_up(vv, off);
        if (t >= off) vv += u;
    }
    if (t < nb) bsum[t] = vv - iv;     // exclusive
    if (t == 63) row_start[n] = vv;    // grand total
}

__global__ __launch_bounds__(256) void scan_write_kernel(
    const int* __restrict__ count, const int* __restrict__ bsum,
    int* __restrict__ row_start, int* __restrict__ cursor, int n)
{
    __shared__ int wtot[4];
    const int t = threadIdx.x, lane = t & 63, w = t >> 6;
    int base = blockIdx.x * SCAN_CHUNK + t * 4;
    int c0 = 0, c1 = 0, c2 = 0, c3 = 0;
    if (base + 0 < n) c0 = count[base + 0];
    if (base + 1 < n) c1 = count[base + 1];
    if (base + 2 < n) c2 = count[base + 2];
    if (base + 3 < n) c3 = count[base + 3];
    int tsum = c0 + c1 + c2 + c3;
    int inc = tsum;
    #pragma unroll
    for (int off = 1; off < 64; off <<= 1) {
        int u = __shfl_up(inc, off);
        if (lane >= off) inc += u;
    }
    if (lane == 63) wtot[w] = inc;
    __syncthreads();
    int wb = 0;
    for (int i = 0; i < w; ++i) wb += wtot[i];
    int start = bsum[blockIdx.x] + wb + inc - tsum;
    if (base + 0 < n) { row_start[base + 0] = start;            cursor[base + 0] = start; }
    if (base + 1 < n) { row_start[base + 1] = start + c0;       cursor[base + 1] = start + c0; }
    if (base + 2 < n) { row_start[base + 2] = start + c0 + c1;  cursor[base + 2] = start + c0 + c1; }
    if (base + 3 < n) { row_start[base + 3] = start + c0 + c1 + c2; cursor[base + 3] = start + c0 + c1 + c2; }
}

__global__ __launch_bounds__(256) void scatter_kernel(
    const int* __restrict__ idx_i, const int* __restrict__ idx_j,
    int* __restrict__ cursor, int* __restrict__ ejs, int n_edges)
{
    int e = blockIdx.x * blockDim.x + threadIdx.x;
    if (e < n_edges) {
        int i = idx_i[e];
        int pos = atomicAdd(&cursor[i], 1);
        ejs[pos] = idx_j[e];
    }
}

// ---------------- fused per-node attention (bf16 K/V, half-wave per edge) ----------------
// one wave per node; lanes split into two 32-lane halves, each processing
// alternating edges. Lane covers dims [4*sl, 4*sl+4) (8B bf16 loads).
// Head h = sl/4 (4 lanes per head, shuffle-reduce xor 1,2).
// Independent online softmax per half; one cross-half merge at the end.

__global__ __launch_bounds__(256) void fused_agg_kernel(
    const float* __restrict__ q, const ushort* __restrict__ k16,
    const ushort* __restrict__ v16, const int* __restrict__ row_start,
    const int* __restrict__ ejs,
    ushort* __restrict__ aggh, ushort* __restrict__ aggl, int n_nodes)
{
    const int lane = threadIdx.x & 63;
    const int node = (blockIdx.x * blockDim.x + threadIdx.x) >> 6;
    if (node >= n_nodes) return;
    const int beg = row_start[node], end = row_start[node + 1];
    const int half = lane >> 5, sl = lane & 31;
    const int c4 = sl * 4;

    if (beg >= end) {   // empty segment: agg row = 0
        if (half == 0) {
            ((uint2*)(aggh + (size_t)node * D))[sl] = make_uint2(0u, 0u);
            ((uint2*)(aggl + (size_t)node * D))[sl] = make_uint2(0u, 0u);
        }
        return;
    }

    const float4 qv = *(const float4*)&q[(size_t)node * D + c4];
    const float SC = 0.25f * 1.4426950408889634f;   // 1/sqrt(DH) * log2(e)
    float m = -INFINITY, l = 0.f;
    float a0 = 0.f, a1 = 0.f, a2 = 0.f, a3 = 0.f;

    int p = beg + half;
    uint2 kr0, vr0, kr1, vr1;
    if (p < end) {
        int j = ejs[p];
        kr0 = *(const uint2*)(k16 + (size_t)j * D + c4);
        vr0 = *(const uint2*)(v16 + (size_t)j * D + c4);
    }
    if (p + 2 < end) {
        int j = ejs[p + 2];
        kr1 = *(const uint2*)(k16 + (size_t)j * D + c4);
        vr1 = *(const uint2*)(v16 + (size_t)j * D + c4);
    }
    while (p < end) {
        uint2 kc = kr0, vc = vr0;
        kr0 = kr1; vr0 = vr1;
        if (p + 4 < end) {
            int j = ejs[p + 4];
            kr1 = *(const uint2*)(k16 + (size_t)j * D + c4);
            vr1 = *(const uint2*)(v16 + (size_t)j * D + c4);
        }
        float k0 = bf2f((ushort)kc.x), k1 = bf2f((ushort)(kc.x >> 16));
        float k2 = bf2f((ushort)kc.y), k3 = bf2f((ushort)(kc.y >> 16));
        float d = qv.x * k0 + qv.y * k1 + qv.z * k2 + qv.w * k3;
        d += __shfl_xor(d, 1);
        d += __shfl_xor(d, 2);
        float s = d * SC;
        float mn = fmaxf(m, s);
        float c  = exp2f(m - mn);      // first iter: exp2(-inf) = 0
        float pe = exp2f(s - mn);
        float v0 = bf2f((ushort)vc.x), v1 = bf2f((ushort)(vc.x >> 16));
        float v2 = bf2f((ushort)vc.y), v3 = bf2f((ushort)(vc.y >> 16));
        l  = l  * c + pe;
        a0 = a0 * c + pe * v0;
        a1 = a1 * c + pe * v1;
        a2 = a2 * c + pe * v2;
        a3 = a3 * c + pe * v3;
        m = mn;
        p += 2;
    }

    // merge halves (symmetric -> both halves hold identical results)
    float m2 = __shfl_xor(m, 32);
    float l2 = __shfl_xor(l, 32);
    float b0 = __shfl_xor(a0, 32);
    float b1 = __shfl_xor(a1, 32);
    float b2 = __shfl_xor(a2, 32);
    float b3 = __shfl_xor(a3, 32);
    float mm = fmaxf(m, m2);           // finite: half0 always has >=1 edge
    float cA = exp2f(m - mm);
    float cB = exp2f(m2 - mm);
    float L  = l * cA + l2 * cB;
    float A0 = a0 * cA + b0 * cB;
    float A1 = a1 * cA + b1 * cB;
    float A2 = a2 * cA + b2 * cB;
    float A3 = a3 * cA + b3 * cB;
    float invl = (L > 0.f) ? (1.0f / L) : 0.f;
    float o0 = A0 * invl, o1 = A1 * invl, o2 = A2 * invl, o3 = A3 * invl;

    ushort h0 = f2bf(o0), h1 = f2bf(o1), h2 = f2bf(o2), h3 = f2bf(o3);
    if (half == 0) {
        uint2 hv;
        hv.x = (unsigned int)h0 | ((unsigned int)h1 << 16);
        hv.y = (unsigned int)h2 | ((unsigned int)h3 << 16);
        ((uint2*)(aggh + (size_t)node * D))[sl] = hv;
    } else {
        ushort l0 = f2bf(o0 - bf2f(h0)), l1 = f2bf(o1 - bf2f(h1));
        ushort l2_ = f2bf(o2 - bf2f(h2)), l3 = f2bf(o3 - bf2f(h3));
        uint2 lv;
        lv.x = (unsigned int)l0 | ((unsigned int)l1 << 16);
        lv.y = (unsigned int)l2_ | ((unsigned int)l3 << 16);
        ((uint2*)(aggl + (size_t)node * D))[sl] = lv;
    }
}

// ---------------- oproj + LN1: h = LN(x + agg@Wo + bo) -> bf16 split ----------------

__global__ __launch_bounds__(256) void oproj_mfma_kernel(
    const ushort* __restrict__ aggh, const ushort* __restrict__ aggl,
    const float* __restrict__ x,
    const ushort* __restrict__ wth, const ushort* __restrict__ wtl,
    const float* __restrict__ bo, const float* __restrict__ g1,
    const float* __restrict__ be1,
    ushort* __restrict__ hh, ushort* __restrict__ hl, int n_rows)
{
    const int t = threadIdx.x;
    const int w = t >> 6, l = t & 63;
    const int l15 = l & 15, l4 = l >> 4;
    const int rowb = blockIdx.x * 64 + w * 16;
    const size_t abase = (size_t)(rowb + l15) * D + l4 * 8;

    f32x4 acc[8];
    #pragma unroll
    for (int n = 0; n < 8; ++n) acc[n] = (f32x4){0.f, 0.f, 0.f, 0.f};

    #pragma unroll
    for (int kk = 0; kk < 4; ++kk) {
        bf16x8 ah = *(const bf16x8*)(aggh + abase + kk * 32);
        bf16x8 al = *(const bf16x8*)(aggl + abase + kk * 32);
        #pragma unroll
        for (int n = 0; n < 8; ++n) {
            size_t boff = (size_t)(n * 16 + l15) * D + l4 * 8 + kk * 32;
            bf16x8 bh = *(const bf16x8*)(wth + boff);
            bf16x8 bl = *(const bf16x8*)(wtl + boff);
            acc[n] = __builtin_amdgcn_mfma_f32_16x16x32_bf16(ah, bh, acc[n], 0, 0, 0);
            acc[n] = __builtin_amdgcn_mfma_f32_16x16x32_bf16(al, bh, acc[n], 0, 0, 0);
            acc[n] = __builtin_amdgcn_mfma_f32_16x16x32_bf16(ah, bl, acc[n], 0, 0, 0);
        }
    }

    float vals[8][4];
    #pragma unroll
    for (int n = 0; n < 8; ++n) {
        int col = n * 16 + l15;
        float bsv = bo[col];
        #pragma unroll
        for (int r = 0; r < 4; ++r) {
            int row = rowb + l4 * 4 + r;
            float xr = (row < n_rows) ? x[(size_t)row * D + col] : 0.f;
            vals[n][r] = acc[n][r] + bsv + xr;
        }
    }
    #pragma unroll
    for (int r = 0; r < 4; ++r) {
        int row = rowb + l4 * 4 + r;
        float s = 0.f, ss = 0.f;
        #pragma unroll
        for (int n = 0; n < 8; ++n) { s += vals[n][r]; ss += vals[n][r] * vals[n][r]; }
        #pragma unroll
        for (int msk = 1; msk <= 8; msk <<= 1) {
            s += __shfl_xor(s, msk);
            ss += __shfl_xor(ss, msk);
        }
        float mean = s * (1.0f / D);
        float var = ss * (1.0f / D) - mean * mean;
        float inv = rsqrtf(var + 1e-5f);
        if (row < n_rows) {
            #pragma unroll
            for (int n = 0; n < 8; ++n) {
                int col = n * 16 + l15;
                float y = (vals[n][r] - mean) * inv * g1[col] + be1[col];
                ushort hb = f2bf(y);
                hh[(size_t)row * D + col] = hb;
                hl[(size_t)row * D + col] = f2bf(y - bf2f(hb));
            }
        }
    }
}

// ---------------- FFN + LN2: out = LN(h + relu(h@W1+b1)@W2 + b2) ----------------

__global__ __launch_bounds__(256) void ffn_mfma_kernel(
    const ushort* __restrict__ hh, const ushort* __restrict__ hl,
    const ushort* __restrict__ w1th, const ushort* __restrict__ w1tl,
    const ushort* __restrict__ w2th, const ushort* __restrict__ w2tl,
    const float* __restrict__ bb1, const float* __restrict__ bb2,
    const float* __restrict__ g2, const float* __restrict__ be2,
    float* __restrict__ out, int n_rows)
{
    __shared__ __align__(16) ushort tsh[64][136];
    __shared__ __align__(16) ushort tsl[64][136];
    const int t = threadIdx.x;
    const int w = t >> 6, l = t & 63;
    const int l15 = l & 15, l4 = l >> 4;
    const int rowb = blockIdx.x * 64 + w * 16;
    const size_t abase = (size_t)(rowb + l15) * D + l4 * 8;

    {
        f32x4 acc[8];
        #pragma unroll
        for (int n = 0; n < 8; ++n) acc[n] = (f32x4){0.f, 0.f, 0.f, 0.f};
        #pragma unroll
        for (int kk = 0; kk < 4; ++kk) {
            bf16x8 ah = *(const bf16x8*)(hh + abase + kk * 32);
            bf16x8 al = *(const bf16x8*)(hl + abase + kk * 32);
            #pragma unroll
            for (int n = 0; n < 8; ++n) {
                size_t boff = (size_t)(n * 16 + l15) * D + l4 * 8 + kk * 32;
                bf16x8 bh = *(const bf16x8*)(w1th + boff);
                bf16x8 bl = *(const bf16x8*)(w1tl + boff);
                acc[n] = __builtin_amdgcn_mfma_f32_16x16x32_bf16(ah, bh, acc[n], 0, 0, 0);
                acc[n] = __builtin_amdgcn_mfma_f32_16x16x32_bf16(al, bh, acc[n], 0, 0, 0);
                acc[n] = __builtin_amdgcn_mfma_f32_16x16x32_bf16(ah, bl, acc[n], 0, 0, 0);
            }
        }
        #pragma unroll
        for (int n = 0; n < 8; ++n) {
            int col = n * 16 + l15;
            float bsv = bb1[col];
            #pragma unroll
            for (int r = 0; r < 4; ++r) {
                int lrow = w * 16 + l4 * 4 + r;
                float tv = fmaxf(acc[n][r] + bsv, 0.f);
                ushort hb = f2bf(tv);
                tsh[lrow][col] = hb;
                tsl[lrow][col] = f2bf(tv - bf2f(hb));
            }
        }
    }
    __syncthreads();

    f32x4 acc[8];
    #pragma unroll
    for (int n = 0; n < 8; ++n) acc[n] = (f32x4){0.f, 0.f, 0.f, 0.f};
    #pragma unroll
    for (int kk = 0; kk < 4; ++kk) {
        bf16x8 ah = *(const bf16x8*)&tsh[w * 16 + l15][l4 * 8 + kk * 32];
        bf16x8 al = *(const bf16x8*)&tsl[w * 16 + l15][l4 * 8 + kk * 32];
        #pragma unroll
        for (int n = 0; n < 8; ++n) {
            size_t boff = (size_t)(n * 16 + l15) * D + l4 * 8 + kk * 32;
            bf16x8 bh = *(const bf16x8*)(w2th + boff);
            bf16x8 bl = *(const bf16x8*)(w2tl + boff);
            acc[n] = __builtin_amdgcn_mfma_f32_16x16x32_bf16(ah, bh, acc[n], 0, 0, 0);
            acc[n] = __builtin_amdgcn_mfma_f32_16x16x32_bf16(al, bh, acc[n], 0, 0, 0);
            acc[n] = __builtin_amdgcn_mfma_f32_16x16x32_bf16(ah, bl, acc[n], 0, 0, 0);
        }
    }

    float vals[8][4];
    #pragma unroll
    for (int n = 0; n < 8; ++n) {
        int col = n * 16 + l15;
        float bsv = bb2[col];
        #pragma unroll
        for (int r = 0; r < 4; ++r) {
            int row = rowb + l4 * 4 + r;
            float hr = 0.f;
            if (row < n_rows)
                hr = bf2f(hh[(size_t)row * D + col]) + bf2f(hl[(size_t)row * D + col]);
            vals[n][r] = acc[n][r] + bsv + hr;
        }
    }
    #pragma unroll
    for (int r = 0; r < 4; ++r) {
        int row = rowb + l4 * 4 + r;
        float s = 0.f, ss = 0.f;
        #pragma unroll
        for (int n = 0; n < 8; ++n) { s += vals[n][r]; ss += vals[n][r] * vals[n][r]; }
        #pragma unroll
        for (int msk = 1; msk <= 8; msk <<= 1) {
            s += __shfl_xor(s, msk);
            ss += __shfl_xor(ss, msk);
        }
        float mean = s * (1.0f / D);
        float var = ss * (1.0f / D) - mean * mean;
        float inv = rsqrtf(var + 1e-5f);
        if (row < n_rows) {
            #pragma unroll
            for (int n = 0; n < 8; ++n) {
                int col = n * 16 + l15;
                out[(size_t)row * D + col] = (vals[n][r] - mean) * inv * g2[col] + be2[col];
            }
        }
    }
}

// ---------------- launch ----------------

extern "C" void kernel_launch(void* const* d_in, const int* in_sizes, int n_in,
                              void* d_out, int out_size, void* d_ws, size_t ws_size,
                              hipStream_t stream) {
    const float* x     = (const float*)d_in[0];
    const int*   idx_i = (const int*)d_in[1];
    const int*   idx_j = (const int*)d_in[2];
    const float* Wq = (const float*)d_in[3];
    const float* bq = (const float*)d_in[4];
    const float* Wk = (const float*)d_in[5];
    const float* bk = (const float*)d_in[6];
    const float* Wv = (const float*)d_in[7];
    const float* bv = (const float*)d_in[8];
    const float* Wo = (const float*)d_in[9];
    const float* bo = (const float*)d_in[10];
    const float* g1 = (const float*)d_in[11];
    const float* be1 = (const float*)d_in[12];
    const float* W1 = (const float*)d_in[13];
    const float* bb1 = (const float*)d_in[14];
    const float* W2 = (const float*)d_in[15];
    const float* bb2 = (const float*)d_in[16];
    const float* g2 = (const float*)d_in[17];
    const float* be2 = (const float*)d_in[18];

    const int N_ = in_sizes[0] / D;
    const int E_ = in_sizes[1];
    const size_t ND = (size_t)N_ * D;
    const int nb = (N_ + SCAN_CHUNK - 1) / SCAN_CHUNK;   // 49 for N=50000 (<=64 required)

    float* ws = (float*)d_ws;
    float* q = ws;                         // ND f32 (later reused as hh/hl bf16 split)
    ushort* k16 = (ushort*)(q + ND);       // ND bf16
    ushort* v16 = k16 + ND;                // ND bf16
    int* count     = (int*)(v16 + ND);     // N
    int* row_start = count + N_;           // N+1
    int* cursor    = row_start + N_ + 1;   // N
    int* bsum      = cursor + N_;          // 64
    int* ejs       = bsum + 64;            // E
    ushort* xh = (ushort*)(ejs + E_);      // ND bf16 (later reused as aggh)
    ushort* xl = xh + ND;                  // ND bf16 (later reused as aggl)
    ushort* wth = xl + ND;                 // 6*128*128
    ushort* wtl = wth + 6 * 16384;         // 6*128*128
    ushort* aggh = xh;
    ushort* aggl = xl;
    ushort* hh = (ushort*)q;
    ushort* hl = hh + ND;

    zero_kernel<<<(N_ + 255) / 256, 256, 0, stream>>>(count, N_);
    prep_x_kernel<<<((int)(ND / 4) + 255) / 256, 256, 0, stream>>>(x, xh, xl, (int)(ND / 4));
    prep_w_kernel<<<6, 256, 0, stream>>>(Wq, Wk, Wv, Wo, W1, W2, wth, wtl);
    qkv_mfma_kernel<<<(N_ + 63) / 64, 256, 0, stream>>>(xh, xl, wth, wtl,
                                                        bq, bk, bv, q, k16, v16, N_);
    hist_kernel<<<(E_ + 255) / 256, 256, 0, stream>>>(idx_i, count, E_);
    scan_reduce_kernel<<<nb, 256, 0, stream>>>(count, bsum, N_);
    scan_bsum_kernel<<<1, 64, 0, stream>>>(bsum, row_start, nb, N_);
    scan_write_kernel<<<nb, 256, 0, stream>>>(count, bsum, row_start, cursor, N_);
    scatter_kernel<<<(E_ + 255) / 256, 256, 0, stream>>>(idx_i, idx_j, cursor, ejs, E_);
    fused_agg_kernel<<<(N_ + 3) / 4, 256, 0, stream>>>(q, k16, v16, row_start, ejs,
                                                       aggh, aggl, N_);
    oproj_mfma_kernel<<<(N_ + 63) / 64, 256, 0, stream>>>(aggh, aggl, x,
                                                          wth + 3 * 16384, wtl + 3 * 16384,
                                                          bo, g1, be1, hh, hl, N_);
    ffn_mfma_kernel<<<(N_ + 63) / 64, 256, 0, stream>>>(hh, hl,
                                                        wth + 4 * 16384, wtl + 4 * 16384,
                                                        wth + 5 * 16384, wtl + 5 * 16384,
                                                        bb1, bb2, g2, be2,
                                                        (float*)d_out, N_);
}

// Round 9
// 416.542 us; speedup vs baseline: 4.4854x; 1.0328x over previous
//
#include <hip/hip_runtime.h>
#include <hip/hip_bf16.h>
#include <math.h>

#define D 128
#define H 8
#define DH 16
#define SCAN_CHUNK 1024

typedef __attribute__((ext_vector_type(8))) short bf16x8;
typedef __attribute__((ext_vector_type(4))) float f32x4;

__device__ __forceinline__ float bf2f(ushort u) {
    unsigned int x = ((unsigned int)u) << 16;
    float f;
    __builtin_memcpy(&f, &x, 4);
    return f;
}
__device__ __forceinline__ ushort f2bf(float f) {
    __hip_bfloat16 h = __float2bfloat16(f);
    ushort u;
    __builtin_memcpy(&u, &h, 2);
    return u;
}

// ---------------- K0: zero histogram ----------------

__global__ __launch_bounds__(256) void zero_kernel(int* __restrict__ count, int n) {
    int gid = blockIdx.x * blockDim.x + threadIdx.x;
    if (gid < n) count[gid] = 0;
}

// ---------------- prep_x: split x into bf16 hi/lo ----------------

__global__ __launch_bounds__(256) void prep_x_kernel(
    const float* __restrict__ x, ushort* __restrict__ xh, ushort* __restrict__ xl,
    int total4)
{
    int gid = blockIdx.x * blockDim.x + threadIdx.x;
    if (gid >= total4) return;
    float4 v = ((const float4*)x)[gid];
    ushort4 hv, lv;
    hv.x = f2bf(v.x); lv.x = f2bf(v.x - bf2f(hv.x));
    hv.y = f2bf(v.y); lv.y = f2bf(v.y - bf2f(hv.y));
    hv.z = f2bf(v.z); lv.z = f2bf(v.z - bf2f(hv.z));
    hv.w = f2bf(v.w); lv.w = f2bf(v.w - bf2f(hv.w));
    ((ushort4*)xh)[gid] = hv;
    ((ushort4*)xl)[gid] = lv;
}

// ---------------- prep_w: transpose + split 6 weight matrices ----------------

__global__ __launch_bounds__(256) void prep_w_kernel(
    const float* __restrict__ w0, const float* __restrict__ w1,
    const float* __restrict__ w2, const float* __restrict__ w3,
    const float* __restrict__ w4, const float* __restrict__ w5,
    ushort* __restrict__ wth, ushort* __restrict__ wtl)
{
    __shared__ __align__(16) float tile[128][132];
    const int m = blockIdx.x;
    const float* W = (m == 0) ? w0 : (m == 1) ? w1 : (m == 2) ? w2
                   : (m == 3) ? w3 : (m == 4) ? w4 : w5;
    const int t = threadIdx.x;
    const float4* wg = (const float4*)W;
    #pragma unroll
    for (int it = 0; it < 16; ++it) {
        int f4 = t + it * 256;
        int k = f4 >> 5, c4 = f4 & 31;
        *((float4*)&tile[k][c4 * 4]) = wg[f4];
    }
    __syncthreads();
    ushort* oh = wth + m * 16384;
    ushort* ol = wtl + m * 16384;
    #pragma unroll
    for (int it = 0; it < 64; ++it) {
        int idx = t + it * 256;
        int c = idx >> 7, k = idx & 127;
        float v = tile[k][c];
        ushort hb = f2bf(v);
        oh[idx] = hb;
        ol[idx] = f2bf(v - bf2f(hb));
    }
}

// ---------------- qkv: [N,128]@[128,128]x3 via split-bf16 MFMA ----------------
// A-frags hoisted (shared across mats); B-frags batch-loaded per K-chunk
// for 16-deep load ILP. launch_bounds(256,3) -> VGPR cap ~170.

__global__ __launch_bounds__(256, 3) void qkv_mfma_kernel(
    const ushort* __restrict__ xh, const ushort* __restrict__ xl,
    const ushort* __restrict__ wth, const ushort* __restrict__ wtl,
    const float* __restrict__ bq, const float* __restrict__ bk,
    const float* __restrict__ bv,
    float* __restrict__ q, ushort* __restrict__ k16, ushort* __restrict__ v16,
    int n_rows)
{
    const int t = threadIdx.x;
    const int w = t >> 6, l = t & 63;
    const int l15 = l & 15, l4 = l >> 4;
    const int rowb = blockIdx.x * 64 + w * 16;
    const size_t abase = (size_t)(rowb + l15) * D + l4 * 8;

    // hoist A fragments: identical for all three matrices
    bf16x8 ah[4], al[4];
    #pragma unroll
    for (int kk = 0; kk < 4; ++kk) {
        ah[kk] = *(const bf16x8*)(xh + abase + kk * 32);
        al[kk] = *(const bf16x8*)(xl + abase + kk * 32);
    }

    const float* biases[3] = {bq, bk, bv};

    #pragma unroll
    for (int m = 0; m < 3; ++m) {
        const ushort* bh_ = wth + m * 16384;
        const ushort* bl_ = wtl + m * 16384;
        f32x4 acc[8];
        #pragma unroll
        for (int n = 0; n < 8; ++n) acc[n] = (f32x4){0.f, 0.f, 0.f, 0.f};

        #pragma unroll
        for (int kk = 0; kk < 4; ++kk) {
            bf16x8 bh[8], bl[8];
            #pragma unroll
            for (int n = 0; n < 8; ++n) {
                size_t boff = (size_t)(n * 16 + l15) * D + l4 * 8 + kk * 32;
                bh[n] = *(const bf16x8*)(bh_ + boff);
                bl[n] = *(const bf16x8*)(bl_ + boff);
            }
            #pragma unroll
            for (int n = 0; n < 8; ++n) {
                acc[n] = __builtin_amdgcn_mfma_f32_16x16x32_bf16(ah[kk], bh[n], acc[n], 0, 0, 0);
                acc[n] = __builtin_amdgcn_mfma_f32_16x16x32_bf16(al[kk], bh[n], acc[n], 0, 0, 0);
                acc[n] = __builtin_amdgcn_mfma_f32_16x16x32_bf16(ah[kk], bl[n], acc[n], 0, 0, 0);
            }
        }
        const float* bias = biases[m];
        #pragma unroll
        for (int n = 0; n < 8; ++n) {
            int col = n * 16 + l15;
            float bsv = bias[col];
            #pragma unroll
            for (int r = 0; r < 4; ++r) {
                int row = rowb + l4 * 4 + r;
                if (row < n_rows) {
                    float val = acc[n][r] + bsv;
                    if (m == 0) q[(size_t)row * D + col] = val;
                    else if (m == 1) k16[(size_t)row * D + col] = f2bf(val);
                    else v16[(size_t)row * D + col] = f2bf(val);
                }
            }
        }
    }
}

// ---------------- CSR build ----------------

__global__ __launch_bounds__(256) void hist_kernel(
    const int* __restrict__ idx_i, int* __restrict__ count, int n_edges)
{
    int e = blockIdx.x * blockDim.x + threadIdx.x;
    if (e < n_edges) atomicAdd(&count[idx_i[e]], 1);
}

__global__ __launch_bounds__(256) void scan_reduce_kernel(
    const int* __restrict__ count, int* __restrict__ bsum, int n)
{
    __shared__ int wsum[4];
    const int t = threadIdx.x, lane = t & 63, w = t >> 6;
    int base = blockIdx.x * SCAN_CHUNK + t * 4;
    int s = 0;
    #pragma unroll
    for (int i = 0; i < 4; ++i) {
        int idx = base + i;
        if (idx < n) s += count[idx];
    }
    #pragma unroll
    for (int off = 1; off < 64; off <<= 1) s += __shfl_xor(s, off);
    if (lane == 0) wsum[w] = s;
    __syncthreads();
    if (t == 0) bsum[blockIdx.x] = wsum[0] + wsum[1] + wsum[2] + wsum[3];
}

__global__ __launch_bounds__(64) void scan_bsum_kernel(
    int* __restrict__ bsum, int* __restrict__ row_start, int nb, int n)
{
    const int t = threadIdx.x;
    int iv = (t < nb) ? bsum[t] : 0;
    int vv = iv;
    #pragma unroll
    for (int off = 1; off < 64; off <<= 1) {
        int u = __shfl_up(vv, off);
        if (t >= off) vv += u;
    }
    if (t < nb) bsum[t] = vv - iv;     // exclusive
    if (t == 63) row_start[n] = vv;    // grand total
}

__global__ __launch_bounds__(256) void scan_write_kernel(
    const int* __restrict__ count, const int* __restrict__ bsum,
    int* __restrict__ row_start, int* __restrict__ cursor, int n)
{
    __shared__ int wtot[4];
    const int t = threadIdx.x, lane = t & 63, w = t >> 6;
    int base = blockIdx.x * SCAN_CHUNK + t * 4;
    int c0 = 0, c1 = 0, c2 = 0, c3 = 0;
    if (base + 0 < n) c0 = count[base + 0];
    if (base + 1 < n) c1 = count[base + 1];
    if (base + 2 < n) c2 = count[base + 2];
    if (base + 3 < n) c3 = count[base + 3];
    int tsum = c0 + c1 + c2 + c3;
    int inc = tsum;
    #pragma unroll
    for (int off = 1; off < 64; off <<= 1) {
        int u = __shfl_up(inc, off);
        if (lane >= off) inc += u;
    }
    if (lane == 63) wtot[w] = inc;
    __syncthreads();
    int wb = 0;
    for (int i = 0; i < w; ++i) wb += wtot[i];
    int start = bsum[blockIdx.x] + wb + inc - tsum;
    if (base + 0 < n) { row_start[base + 0] = start;            cursor[base + 0] = start; }
    if (base + 1 < n) { row_start[base + 1] = start + c0;       cursor[base + 1] = start + c0; }
    if (base + 2 < n) { row_start[base + 2] = start + c0 + c1;  cursor[base + 2] = start + c0 + c1; }
    if (base + 3 < n) { row_start[base + 3] = start + c0 + c1 + c2; cursor[base + 3] = start + c0 + c1 + c2; }
}

__global__ __launch_bounds__(256) void scatter_kernel(
    const int* __restrict__ idx_i, const int* __restrict__ idx_j,
    int* __restrict__ cursor, int* __restrict__ ejs, int n_edges)
{
    int e = blockIdx.x * blockDim.x + threadIdx.x;
    if (e < n_edges) {
        int i = idx_i[e];
        int pos = atomicAdd(&cursor[i], 1);
        ejs[pos] = idx_j[e];
    }
}

// ---------------- fused per-node attention (bf16 K/V, half-wave per edge) ----------------

__global__ __launch_bounds__(256) void fused_agg_kernel(
    const float* __restrict__ q, const ushort* __restrict__ k16,
    const ushort* __restrict__ v16, const int* __restrict__ row_start,
    const int* __restrict__ ejs,
    ushort* __restrict__ aggh, ushort* __restrict__ aggl, int n_nodes)
{
    const int lane = threadIdx.x & 63;
    const int node = (blockIdx.x * blockDim.x + threadIdx.x) >> 6;
    if (node >= n_nodes) return;
    const int beg = row_start[node], end = row_start[node + 1];
    const int half = lane >> 5, sl = lane & 31;
    const int c4 = sl * 4;

    if (beg >= end) {   // empty segment: agg row = 0
        if (half == 0) {
            ((uint2*)(aggh + (size_t)node * D))[sl] = make_uint2(0u, 0u);
            ((uint2*)(aggl + (size_t)node * D))[sl] = make_uint2(0u, 0u);
        }
        return;
    }

    const float4 qv = *(const float4*)&q[(size_t)node * D + c4];
    const float SC = 0.25f * 1.4426950408889634f;   // 1/sqrt(DH) * log2(e)
    float m = -INFINITY, l = 0.f;
    float a0 = 0.f, a1 = 0.f, a2 = 0.f, a3 = 0.f;

    int p = beg + half;
    uint2 kr0, vr0, kr1, vr1;
    if (p < end) {
        int j = ejs[p];
        kr0 = *(const uint2*)(k16 + (size_t)j * D + c4);
        vr0 = *(const uint2*)(v16 + (size_t)j * D + c4);
    }
    if (p + 2 < end) {
        int j = ejs[p + 2];
        kr1 = *(const uint2*)(k16 + (size_t)j * D + c4);
        vr1 = *(const uint2*)(v16 + (size_t)j * D + c4);
    }
    while (p < end) {
        uint2 kc = kr0, vc = vr0;
        kr0 = kr1; vr0 = vr1;
        if (p + 4 < end) {
            int j = ejs[p + 4];
            kr1 = *(const uint2*)(k16 + (size_t)j * D + c4);
            vr1 = *(const uint2*)(v16 + (size_t)j * D + c4);
        }
        float k0 = bf2f((ushort)kc.x), k1 = bf2f((ushort)(kc.x >> 16));
        float k2 = bf2f((ushort)kc.y), k3 = bf2f((ushort)(kc.y >> 16));
        float d = qv.x * k0 + qv.y * k1 + qv.z * k2 + qv.w * k3;
        d += __shfl_xor(d, 1);
        d += __shfl_xor(d, 2);
        float s = d * SC;
        float mn = fmaxf(m, s);
        float c  = exp2f(m - mn);      // first iter: exp2(-inf) = 0
        float pe = exp2f(s - mn);
        float v0 = bf2f((ushort)vc.x), v1 = bf2f((ushort)(vc.x >> 16));
        float v2 = bf2f((ushort)vc.y), v3 = bf2f((ushort)(vc.y >> 16));
        l  = l  * c + pe;
        a0 = a0 * c + pe * v0;
        a1 = a1 * c + pe * v1;
        a2 = a2 * c + pe * v2;
        a3 = a3 * c + pe * v3;
        m = mn;
        p += 2;
    }

    // merge halves
    float m2 = __shfl_xor(m, 32);
    float l2 = __shfl_xor(l, 32);
    float b0 = __shfl_xor(a0, 32);
    float b1 = __shfl_xor(a1, 32);
    float b2 = __shfl_xor(a2, 32);
    float b3 = __shfl_xor(a3, 32);
    float mm = fmaxf(m, m2);
    float cA = exp2f(m - mm);
    float cB = exp2f(m2 - mm);
    float L  = l * cA + l2 * cB;
    float A0 = a0 * cA + b0 * cB;
    float A1 = a1 * cA + b1 * cB;
    float A2 = a2 * cA + b2 * cB;
    float A3 = a3 * cA + b3 * cB;
    float invl = (L > 0.f) ? (1.0f / L) : 0.f;
    float o0 = A0 * invl, o1 = A1 * invl, o2 = A2 * invl, o3 = A3 * invl;

    ushort h0 = f2bf(o0), h1 = f2bf(o1), h2 = f2bf(o2), h3 = f2bf(o3);
    if (half == 0) {
        uint2 hv;
        hv.x = (unsigned int)h0 | ((unsigned int)h1 << 16);
        hv.y = (unsigned int)h2 | ((unsigned int)h3 << 16);
        ((uint2*)(aggh + (size_t)node * D))[sl] = hv;
    } else {
        ushort l0 = f2bf(o0 - bf2f(h0)), l1 = f2bf(o1 - bf2f(h1));
        ushort l2_ = f2bf(o2 - bf2f(h2)), l3 = f2bf(o3 - bf2f(h3));
        uint2 lv;
        lv.x = (unsigned int)l0 | ((unsigned int)l1 << 16);
        lv.y = (unsigned int)l2_ | ((unsigned int)l3 << 16);
        ((uint2*)(aggl + (size_t)node * D))[sl] = lv;
    }
}

// ---------------- oproj + LN1: h = LN(x + agg@Wo + bo) -> bf16 split ----------------

__global__ __launch_bounds__(256, 3) void oproj_mfma_kernel(
    const ushort* __restrict__ aggh, const ushort* __restrict__ aggl,
    const float* __restrict__ x,
    const ushort* __restrict__ wth, const ushort* __restrict__ wtl,
    const float* __restrict__ bo, const float* __restrict__ g1,
    const float* __restrict__ be1,
    ushort* __restrict__ hh, ushort* __restrict__ hl, int n_rows)
{
    const int t = threadIdx.x;
    const int w = t >> 6, l = t & 63;
    const int l15 = l & 15, l4 = l >> 4;
    const int rowb = blockIdx.x * 64 + w * 16;
    const size_t abase = (size_t)(rowb + l15) * D + l4 * 8;

    bf16x8 ah[4], al[4];
    #pragma unroll
    for (int kk = 0; kk < 4; ++kk) {
        ah[kk] = *(const bf16x8*)(aggh + abase + kk * 32);
        al[kk] = *(const bf16x8*)(aggl + abase + kk * 32);
    }

    f32x4 acc[8];
    #pragma unroll
    for (int n = 0; n < 8; ++n) acc[n] = (f32x4){0.f, 0.f, 0.f, 0.f};

    #pragma unroll
    for (int kk = 0; kk < 4; ++kk) {
        bf16x8 bh[8], bl[8];
        #pragma unroll
        for (int n = 0; n < 8; ++n) {
            size_t boff = (size_t)(n * 16 + l15) * D + l4 * 8 + kk * 32;
            bh[n] = *(const bf16x8*)(wth + boff);
            bl[n] = *(const bf16x8*)(wtl + boff);
        }
        #pragma unroll
        for (int n = 0; n < 8; ++n) {
            acc[n] = __builtin_amdgcn_mfma_f32_16x16x32_bf16(ah[kk], bh[n], acc[n], 0, 0, 0);
            acc[n] = __builtin_amdgcn_mfma_f32_16x16x32_bf16(al[kk], bh[n], acc[n], 0, 0, 0);
            acc[n] = __builtin_amdgcn_mfma_f32_16x16x32_bf16(ah[kk], bl[n], acc[n], 0, 0, 0);
        }
    }

    float vals[8][4];
    #pragma unroll
    for (int n = 0; n < 8; ++n) {
        int col = n * 16 + l15;
        float bsv = bo[col];
        #pragma unroll
        for (int r = 0; r < 4; ++r) {
            int row = rowb + l4 * 4 + r;
            float xr = (row < n_rows) ? x[(size_t)row * D + col] : 0.f;
            vals[n][r] = acc[n][r] + bsv + xr;
        }
    }
    #pragma unroll
    for (int r = 0; r < 4; ++r) {
        int row = rowb + l4 * 4 + r;
        float s = 0.f, ss = 0.f;
        #pragma unroll
        for (int n = 0; n < 8; ++n) { s += vals[n][r]; ss += vals[n][r] * vals[n][r]; }
        #pragma unroll
        for (int msk = 1; msk <= 8; msk <<= 1) {
            s += __shfl_xor(s, msk);
            ss += __shfl_xor(ss, msk);
        }
        float mean = s * (1.0f / D);
        float var = ss * (1.0f / D) - mean * mean;
        float inv = rsqrtf(var + 1e-5f);
        if (row < n_rows) {
            #pragma unroll
            for (int n = 0; n < 8; ++n) {
                int col = n * 16 + l15;
                float y = (vals[n][r] - mean) * inv * g1[col] + be1[col];
                ushort hb = f2bf(y);
                hh[(size_t)row * D + col] = hb;
                hl[(size_t)row * D + col] = f2bf(y - bf2f(hb));
            }
        }
    }
}

// ---------------- FFN + LN2: out = LN(h + relu(h@W1+b1)@W2 + b2) ----------------

__global__ __launch_bounds__(256, 3) void ffn_mfma_kernel(
    const ushort* __restrict__ hh, const ushort* __restrict__ hl,
    const ushort* __restrict__ w1th, const ushort* __restrict__ w1tl,
    const ushort* __restrict__ w2th, const ushort* __restrict__ w2tl,
    const float* __restrict__ bb1, const float* __restrict__ bb2,
    const float* __restrict__ g2, const float* __restrict__ be2,
    float* __restrict__ out, int n_rows)
{
    __shared__ __align__(16) ushort tsh[64][136];
    __shared__ __align__(16) ushort tsl[64][136];
    const int t = threadIdx.x;
    const int w = t >> 6, l = t & 63;
    const int l15 = l & 15, l4 = l >> 4;
    const int rowb = blockIdx.x * 64 + w * 16;
    const size_t abase = (size_t)(rowb + l15) * D + l4 * 8;

    // ---- phase 1: t = relu(h@W1 + bb1) -> LDS (split bf16) ----
    {
        bf16x8 ah[4], al[4];
        #pragma unroll
        for (int kk = 0; kk < 4; ++kk) {
            ah[kk] = *(const bf16x8*)(hh + abase + kk * 32);
            al[kk] = *(const bf16x8*)(hl + abase + kk * 32);
        }
        f32x4 acc[8];
        #pragma unroll
        for (int n = 0; n < 8; ++n) acc[n] = (f32x4){0.f, 0.f, 0.f, 0.f};
        #pragma unroll
        for (int kk = 0; kk < 4; ++kk) {
            bf16x8 bh[8], bl[8];
            #pragma unroll
            for (int n = 0; n < 8; ++n) {
                size_t boff = (size_t)(n * 16 + l15) * D + l4 * 8 + kk * 32;
                bh[n] = *(const bf16x8*)(w1th + boff);
                bl[n] = *(const bf16x8*)(w1tl + boff);
            }
            #pragma unroll
            for (int n = 0; n < 8; ++n) {
                acc[n] = __builtin_amdgcn_mfma_f32_16x16x32_bf16(ah[kk], bh[n], acc[n], 0, 0, 0);
                acc[n] = __builtin_amdgcn_mfma_f32_16x16x32_bf16(al[kk], bh[n], acc[n], 0, 0, 0);
                acc[n] = __builtin_amdgcn_mfma_f32_16x16x32_bf16(ah[kk], bl[n], acc[n], 0, 0, 0);
            }
        }
        #pragma unroll
        for (int n = 0; n < 8; ++n) {
            int col = n * 16 + l15;
            float bsv = bb1[col];
            #pragma unroll
            for (int r = 0; r < 4; ++r) {
                int lrow = w * 16 + l4 * 4 + r;
                float tv = fmaxf(acc[n][r] + bsv, 0.f);
                ushort hb = f2bf(tv);
                tsh[lrow][col] = hb;
                tsl[lrow][col] = f2bf(tv - bf2f(hb));
            }
        }
    }
    __syncthreads();

    // ---- phase 2: y = t@W2 + bb2; residual h; LN ----
    bf16x8 ah2[4], al2[4];
    #pragma unroll
    for (int kk = 0; kk < 4; ++kk) {
        ah2[kk] = *(const bf16x8*)&tsh[w * 16 + l15][l4 * 8 + kk * 32];
        al2[kk] = *(const bf16x8*)&tsl[w * 16 + l15][l4 * 8 + kk * 32];
    }
    f32x4 acc[8];
    #pragma unroll
    for (int n = 0; n < 8; ++n) acc[n] = (f32x4){0.f, 0.f, 0.f, 0.f};
    #pragma unroll
    for (int kk = 0; kk < 4; ++kk) {
        bf16x8 bh[8], bl[8];
        #pragma unroll
        for (int n = 0; n < 8; ++n) {
            size_t boff = (size_t)(n * 16 + l15) * D + l4 * 8 + kk * 32;
            bh[n] = *(const bf16x8*)(w2th + boff);
            bl[n] = *(const bf16x8*)(w2tl + boff);
        }
        #pragma unroll
        for (int n = 0; n < 8; ++n) {
            acc[n] = __builtin_amdgcn_mfma_f32_16x16x32_bf16(ah2[kk], bh[n], acc[n], 0, 0, 0);
            acc[n] = __builtin_amdgcn_mfma_f32_16x16x32_bf16(al2[kk], bh[n], acc[n], 0, 0, 0);
            acc[n] = __builtin_amdgcn_mfma_f32_16x16x32_bf16(ah2[kk], bl[n], acc[n], 0, 0, 0);
        }
    }

    float vals[8][4];
    #pragma unroll
    for (int n = 0; n < 8; ++n) {
        int col = n * 16 + l15;
        float bsv = bb2[col];
        #pragma unroll
        for (int r = 0; r < 4; ++r) {
            int row = rowb + l4 * 4 + r;
            float hr = 0.f;
            if (row < n_rows)
                hr = bf2f(hh[(size_t)row * D + col]) + bf2f(hl[(size_t)row * D + col]);
            vals[n][r] = acc[n][r] + bsv + hr;
        }
    }
    #pragma unroll
    for (int r = 0; r < 4; ++r) {
        int row = rowb + l4 * 4 + r;
        float s = 0.f, ss = 0.f;
        #pragma unroll
        for (int n = 0; n < 8; ++n) { s += vals[n][r]; ss += vals[n][r] * vals[n][r]; }
        #pragma unroll
        for (int msk = 1; msk <= 8; msk <<= 1) {
            s += __shfl_xor(s, msk);
            ss += __shfl_xor(ss, msk);
        }
        float mean = s * (1.0f / D);
        float var = ss * (1.0f / D) - mean * mean;
        float inv = rsqrtf(var + 1e-5f);
        if (row < n_rows) {
            #pragma unroll
            for (int n = 0; n < 8; ++n) {
                int col = n * 16 + l15;
                out[(size_t)row * D + col] = (vals[n][r] - mean) * inv * g2[col] + be2[col];
            }
        }
    }
}

// ---------------- launch ----------------

extern "C" void kernel_launch(void* const* d_in, const int* in_sizes, int n_in,
                              void* d_out, int out_size, void* d_ws, size_t ws_size,
                              hipStream_t stream) {
    const float* x     = (const float*)d_in[0];
    const int*   idx_i = (const int*)d_in[1];
    const int*   idx_j = (const int*)d_in[2];
    const float* Wq = (const float*)d_in[3];
    const float* bq = (const float*)d_in[4];
    const float* Wk = (const float*)d_in[5];
    const float* bk = (const float*)d_in[6];
    const float* Wv = (const float*)d_in[7];
    const float* bv = (const float*)d_in[8];
    const float* Wo = (const float*)d_in[9];
    const float* bo = (const float*)d_in[10];
    const float* g1 = (const float*)d_in[11];
    const float* be1 = (const float*)d_in[12];
    const float* W1 = (const float*)d_in[13];
    const float* bb1 = (const float*)d_in[14];
    const float* W2 = (const float*)d_in[15];
    const float* bb2 = (const float*)d_in[16];
    const float* g2 = (const float*)d_in[17];
    const float* be2 = (const float*)d_in[18];

    const int N_ = in_sizes[0] / D;
    const int E_ = in_sizes[1];
    const size_t ND = (size_t)N_ * D;
    const int nb = (N_ + SCAN_CHUNK - 1) / SCAN_CHUNK;   // 49 for N=50000 (<=64 required)

    float* ws = (float*)d_ws;
    float* q = ws;                         // ND f32 (later reused as hh/hl bf16 split)
    ushort* k16 = (ushort*)(q + ND);       // ND bf16
    ushort* v16 = k16 + ND;                // ND bf16
    int* count     = (int*)(v16 + ND);     // N
    int* row_start = count + N_;           // N+1
    int* cursor    = row_start + N_ + 1;   // N
    int* bsum      = cursor + N_;          // 64
    int* ejs       = bsum + 64;            // E
    ushort* xh = (ushort*)(ejs + E_);      // ND bf16 (later reused as aggh)
    ushort* xl = xh + ND;                  // ND bf16 (later reused as aggl)
    ushort* wth = xl + ND;                 // 6*128*128
    ushort* wtl = wth + 6 * 16384;         // 6*128*128
    ushort* aggh = xh;
    ushort* aggl = xl;
    ushort* hh = (ushort*)q;
    ushort* hl = hh + ND;

    zero_kernel<<<(N_ + 255) / 256, 256, 0, stream>>>(count, N_);
    prep_x_kernel<<<((int)(ND / 4) + 255) / 256, 256, 0, stream>>>(x, xh, xl, (int)(ND / 4));
    prep_w_kernel<<<6, 256, 0, stream>>>(Wq, Wk, Wv, Wo, W1, W2, wth, wtl);
    qkv_mfma_kernel<<<(N_ + 63) / 64, 256, 0, stream>>>(xh, xl, wth, wtl,
                                                        bq, bk, bv, q, k16, v16, N_);
    hist_kernel<<<(E_ + 255) / 256, 256, 0, stream>>>(idx_i, count, E_);
    scan_reduce_kernel<<<nb, 256, 0, stream>>>(count, bsum, N_);
    scan_bsum_kernel<<<1, 64, 0, stream>>>(bsum, row_start, nb, N_);
    scan_write_kernel<<<nb, 256, 0, stream>>>(count, bsum, row_start, cursor, N_);
    scatter_kernel<<<(E_ + 255) / 256, 256, 0, stream>>>(idx_i, idx_j, cursor, ejs, E_);
    fused_agg_kernel<<<(N_ + 3) / 4, 256, 0, stream>>>(q, k16, v16, row_start, ejs,
                                                       aggh, aggl, N_);
    oproj_mfma_kernel<<<(N_ + 63) / 64, 256, 0, stream>>>(aggh, aggl, x,
                                                          wth + 3 * 16384, wtl + 3 * 16384,
                                                          bo, g1, be1, hh, hl, N_);
    ffn_mfma_kernel<<<(N_ + 63) / 64, 256, 0, stream>>>(hh, hl,
                                                        wth + 4 * 16384, wtl + 4 * 16384,
                                                        wth + 5 * 16384, wtl + 5 * 16384,
                                                        bb1, bb2, g2, be2,
                                                        (float*)d_out, N_);
}

// Round 10
// 309.265 us; speedup vs baseline: 6.0413x; 1.3469x over previous
//
#include <hip/hip_runtime.h>
#include <hip/hip_bf16.h>
#include <math.h>

#define D 128
#define H 8
#define DH 16
#define SCAN_CHUNK 1024

typedef __attribute__((ext_vector_type(8))) short bf16x8;
typedef __attribute__((ext_vector_type(4))) float f32x4;

__device__ __forceinline__ float bf2f(ushort u) {
    unsigned int x = ((unsigned int)u) << 16;
    float f;
    __builtin_memcpy(&f, &x, 4);
    return f;
}
__device__ __forceinline__ ushort f2bf(float f) {
    __hip_bfloat16 h = __float2bfloat16(f);
    ushort u;
    __builtin_memcpy(&u, &h, 2);
    return u;
}

// Stage a 128x128 bf16 matrix (32KB) from global into LDS with per-row XOR
// swizzle on 16B slots: slot' = slot ^ (row&7). Coalesced global reads.
#define STAGE_W(SRC, LDSBUF)                                              \
    {                                                                      \
        _Pragma("unroll")                                                  \
        for (int it_ = 0; it_ < 8; ++it_) {                                \
            int idx16_ = t + it_ * 256;                                    \
            int row_ = idx16_ >> 4, c16_ = idx16_ & 15;                    \
            int d_ = (row_ << 7) + ((c16_ ^ (row_ & 7)) << 3);             \
            *(bf16x8*)((LDSBUF) + d_) = *(const bf16x8*)((SRC) + idx16_ * 8); \
        }                                                                  \
    }

// Swizzled LDS read offset for fragment (rn = B-row, l4 = lane>>4, kk = K-chunk)
#define WOFF(rn, kk) (((rn) << 7) + ((((l4) + (kk) * 4) ^ ((rn) & 7)) << 3))

// ---------------- K0: zero histogram ----------------

__global__ __launch_bounds__(256) void zero_kernel(int* __restrict__ count, int n) {
    int gid = blockIdx.x * blockDim.x + threadIdx.x;
    if (gid < n) count[gid] = 0;
}

// ---------------- prep_x: split x into bf16 hi/lo ----------------

__global__ __launch_bounds__(256) void prep_x_kernel(
    const float* __restrict__ x, ushort* __restrict__ xh, ushort* __restrict__ xl,
    int total4)
{
    int gid = blockIdx.x * blockDim.x + threadIdx.x;
    if (gid >= total4) return;
    float4 v = ((const float4*)x)[gid];
    ushort4 hv, lv;
    hv.x = f2bf(v.x); lv.x = f2bf(v.x - bf2f(hv.x));
    hv.y = f2bf(v.y); lv.y = f2bf(v.y - bf2f(hv.y));
    hv.z = f2bf(v.z); lv.z = f2bf(v.z - bf2f(hv.z));
    hv.w = f2bf(v.w); lv.w = f2bf(v.w - bf2f(hv.w));
    ((ushort4*)xh)[gid] = hv;
    ((ushort4*)xl)[gid] = lv;
}

// ---------------- prep_w: transpose + split 6 weight matrices ----------------

__global__ __launch_bounds__(256) void prep_w_kernel(
    const float* __restrict__ w0, const float* __restrict__ w1,
    const float* __restrict__ w2, const float* __restrict__ w3,
    const float* __restrict__ w4, const float* __restrict__ w5,
    ushort* __restrict__ wth, ushort* __restrict__ wtl)
{
    __shared__ __align__(16) float tile[128][132];
    const int m = blockIdx.x;
    const float* W = (m == 0) ? w0 : (m == 1) ? w1 : (m == 2) ? w2
                   : (m == 3) ? w3 : (m == 4) ? w4 : w5;
    const int t = threadIdx.x;
    const float4* wg = (const float4*)W;
    #pragma unroll
    for (int it = 0; it < 16; ++it) {
        int f4 = t + it * 256;
        int k = f4 >> 5, c4 = f4 & 31;
        *((float4*)&tile[k][c4 * 4]) = wg[f4];
    }
    __syncthreads();
    ushort* oh = wth + m * 16384;
    ushort* ol = wtl + m * 16384;
    #pragma unroll
    for (int it = 0; it < 64; ++it) {
        int idx = t + it * 256;
        int c = idx >> 7, k = idx & 127;
        float v = tile[k][c];
        ushort hb = f2bf(v);
        oh[idx] = hb;
        ol[idx] = f2bf(v - bf2f(hb));
    }
}

// ---------------- qkv: [N,128]@[128,128]x3, LDS-staged B, split-bf16 MFMA ----
// Per matrix: stage Wh (32KB, swizzled) -> pass1 (Ah*Bh + Al*Bh);
//             stage Wl (same buffer)    -> pass2 (Ah*Bl). A-frags in regs.

__global__ __launch_bounds__(256) void qkv_mfma_kernel(
    const ushort* __restrict__ xh, const ushort* __restrict__ xl,
    const ushort* __restrict__ wth, const ushort* __restrict__ wtl,
    const float* __restrict__ bq, const float* __restrict__ bk,
    const float* __restrict__ bv,
    float* __restrict__ q, ushort* __restrict__ k16, ushort* __restrict__ v16,
    int n_rows)
{
    __shared__ __align__(16) ushort wbuf[16384];
    const int t = threadIdx.x;
    const int w = t >> 6, l = t & 63;
    const int l15 = l & 15, l4 = l >> 4;
    const int rowb = blockIdx.x * 64 + w * 16;
    const size_t abase = (size_t)(rowb + l15) * D + l4 * 8;

    bf16x8 ah[4], al[4];
    #pragma unroll
    for (int kk = 0; kk < 4; ++kk) {
        ah[kk] = *(const bf16x8*)(xh + abase + kk * 32);
        al[kk] = *(const bf16x8*)(xl + abase + kk * 32);
    }

    const float* biases[3] = {bq, bk, bv};

    for (int m = 0; m < 3; ++m) {
        STAGE_W(wth + m * 16384, wbuf);
        __syncthreads();
        f32x4 acc[8];
        #pragma unroll
        for (int n = 0; n < 8; ++n) acc[n] = (f32x4){0.f, 0.f, 0.f, 0.f};
        #pragma unroll
        for (int kk = 0; kk < 4; ++kk) {
            #pragma unroll
            for (int n = 0; n < 8; ++n) {
                int rn = n * 16 + l15;
                bf16x8 bh = *(const bf16x8*)(wbuf + WOFF(rn, kk));
                acc[n] = __builtin_amdgcn_mfma_f32_16x16x32_bf16(ah[kk], bh, acc[n], 0, 0, 0);
                acc[n] = __builtin_amdgcn_mfma_f32_16x16x32_bf16(al[kk], bh, acc[n], 0, 0, 0);
            }
        }
        __syncthreads();
        STAGE_W(wtl + m * 16384, wbuf);
        __syncthreads();
        #pragma unroll
        for (int kk = 0; kk < 4; ++kk) {
            #pragma unroll
            for (int n = 0; n < 8; ++n) {
                int rn = n * 16 + l15;
                bf16x8 bl = *(const bf16x8*)(wbuf + WOFF(rn, kk));
                acc[n] = __builtin_amdgcn_mfma_f32_16x16x32_bf16(ah[kk], bl, acc[n], 0, 0, 0);
            }
        }
        const float* bias = biases[m];
        #pragma unroll
        for (int n = 0; n < 8; ++n) {
            int col = n * 16 + l15;
            float bsv = bias[col];
            #pragma unroll
            for (int r = 0; r < 4; ++r) {
                int row = rowb + l4 * 4 + r;
                if (row < n_rows) {
                    float val = acc[n][r] + bsv;
                    if (m == 0) q[(size_t)row * D + col] = val;
                    else if (m == 1) k16[(size_t)row * D + col] = f2bf(val);
                    else v16[(size_t)row * D + col] = f2bf(val);
                }
            }
        }
        __syncthreads();   // wbuf reads done before next matrix restages
    }
}

// ---------------- CSR build ----------------

__global__ __launch_bounds__(256) void hist_kernel(
    const int* __restrict__ idx_i, int* __restrict__ count, int n_edges)
{
    int e = blockIdx.x * blockDim.x + threadIdx.x;
    if (e < n_edges) atomicAdd(&count[idx_i[e]], 1);
}

__global__ __launch_bounds__(256) void scan_reduce_kernel(
    const int* __restrict__ count, int* __restrict__ bsum, int n)
{
    __shared__ int wsum[4];
    const int t = threadIdx.x, lane = t & 63, w = t >> 6;
    int base = blockIdx.x * SCAN_CHUNK + t * 4;
    int s = 0;
    #pragma unroll
    for (int i = 0; i < 4; ++i) {
        int idx = base + i;
        if (idx < n) s += count[idx];
    }
    #pragma unroll
    for (int off = 1; off < 64; off <<= 1) s += __shfl_xor(s, off);
    if (lane == 0) wsum[w] = s;
    __syncthreads();
    if (t == 0) bsum[blockIdx.x] = wsum[0] + wsum[1] + wsum[2] + wsum[3];
}

__global__ __launch_bounds__(64) void scan_bsum_kernel(
    int* __restrict__ bsum, int* __restrict__ row_start, int nb, int n)
{
    const int t = threadIdx.x;
    int iv = (t < nb) ? bsum[t] : 0;
    int vv = iv;
    #pragma unroll
    for (int off = 1; off < 64; off <<= 1) {
        int u = __shfl_up(vv, off);
        if (t >= off) vv += u;
    }
    if (t < nb) bsum[t] = vv - iv;     // exclusive
    if (t == 63) row_start[n] = vv;    // grand total
}

__global__ __launch_bounds__(256) void scan_write_kernel(
    const int* __restrict__ count, const int* __restrict__ bsum,
    int* __restrict__ row_start, int* __restrict__ cursor, int n)
{
    __shared__ int wtot[4];
    const int t = threadIdx.x, lane = t & 63, w = t >> 6;
    int base = blockIdx.x * SCAN_CHUNK + t * 4;
    int c0 = 0, c1 = 0, c2 = 0, c3 = 0;
    if (base + 0 < n) c0 = count[base + 0];
    if (base + 1 < n) c1 = count[base + 1];
    if (base + 2 < n) c2 = count[base + 2];
    if (base + 3 < n) c3 = count[base + 3];
    int tsum = c0 + c1 + c2 + c3;
    int inc = tsum;
    #pragma unroll
    for (int off = 1; off < 64; off <<= 1) {
        int u = __shfl_up(inc, off);
        if (lane >= off) inc += u;
    }
    if (lane == 63) wtot[w] = inc;
    __syncthreads();
    int wb = 0;
    for (int i = 0; i < w; ++i) wb += wtot[i];
    int start = bsum[blockIdx.x] + wb + inc - tsum;
    if (base + 0 < n) { row_start[base + 0] = start;            cursor[base + 0] = start; }
    if (base + 1 < n) { row_start[base + 1] = start + c0;       cursor[base + 1] = start + c0; }
    if (base + 2 < n) { row_start[base + 2] = start + c0 + c1;  cursor[base + 2] = start + c0 + c1; }
    if (base + 3 < n) { row_start[base + 3] = start + c0 + c1 + c2; cursor[base + 3] = start + c0 + c1 + c2; }
}

__global__ __launch_bounds__(256) void scatter_kernel(
    const int* __restrict__ idx_i, const int* __restrict__ idx_j,
    int* __restrict__ cursor, int* __restrict__ ejs, int n_edges)
{
    int e = blockIdx.x * blockDim.x + threadIdx.x;
    if (e < n_edges) {
        int i = idx_i[e];
        int pos = atomicAdd(&cursor[i], 1);
        ejs[pos] = idx_j[e];
    }
}

// ---------------- fused per-node attention (bf16 K/V, half-wave per edge) ----------------

__global__ __launch_bounds__(256) void fused_agg_kernel(
    const float* __restrict__ q, const ushort* __restrict__ k16,
    const ushort* __restrict__ v16, const int* __restrict__ row_start,
    const int* __restrict__ ejs,
    ushort* __restrict__ aggh, ushort* __restrict__ aggl, int n_nodes)
{
    const int lane = threadIdx.x & 63;
    const int node = (blockIdx.x * blockDim.x + threadIdx.x) >> 6;
    if (node >= n_nodes) return;
    const int beg = row_start[node], end = row_start[node + 1];
    const int half = lane >> 5, sl = lane & 31;
    const int c4 = sl * 4;

    if (beg >= end) {   // empty segment: agg row = 0
        if (half == 0) {
            ((uint2*)(aggh + (size_t)node * D))[sl] = make_uint2(0u, 0u);
            ((uint2*)(aggl + (size_t)node * D))[sl] = make_uint2(0u, 0u);
        }
        return;
    }

    const float4 qv = *(const float4*)&q[(size_t)node * D + c4];
    const float SC = 0.25f * 1.4426950408889634f;   // 1/sqrt(DH) * log2(e)
    float m = -INFINITY, l = 0.f;
    float a0 = 0.f, a1 = 0.f, a2 = 0.f, a3 = 0.f;

    int p = beg + half;
    uint2 kr0, vr0, kr1, vr1;
    if (p < end) {
        int j = ejs[p];
        kr0 = *(const uint2*)(k16 + (size_t)j * D + c4);
        vr0 = *(const uint2*)(v16 + (size_t)j * D + c4);
    }
    if (p + 2 < end) {
        int j = ejs[p + 2];
        kr1 = *(const uint2*)(k16 + (size_t)j * D + c4);
        vr1 = *(const uint2*)(v16 + (size_t)j * D + c4);
    }
    while (p < end) {
        uint2 kc = kr0, vc = vr0;
        kr0 = kr1; vr0 = vr1;
        if (p + 4 < end) {
            int j = ejs[p + 4];
            kr1 = *(const uint2*)(k16 + (size_t)j * D + c4);
            vr1 = *(const uint2*)(v16 + (size_t)j * D + c4);
        }
        float k0 = bf2f((ushort)kc.x), k1 = bf2f((ushort)(kc.x >> 16));
        float k2 = bf2f((ushort)kc.y), k3 = bf2f((ushort)(kc.y >> 16));
        float d = qv.x * k0 + qv.y * k1 + qv.z * k2 + qv.w * k3;
        d += __shfl_xor(d, 1);
        d += __shfl_xor(d, 2);
        float s = d * SC;
        float mn = fmaxf(m, s);
        float c  = exp2f(m - mn);      // first iter: exp2(-inf) = 0
        float pe = exp2f(s - mn);
        float v0 = bf2f((ushort)vc.x), v1 = bf2f((ushort)(vc.x >> 16));
        float v2 = bf2f((ushort)vc.y), v3 = bf2f((ushort)(vc.y >> 16));
        l  = l  * c + pe;
        a0 = a0 * c + pe * v0;
        a1 = a1 * c + pe * v1;
        a2 = a2 * c + pe * v2;
        a3 = a3 * c + pe * v3;
        m = mn;
        p += 2;
    }

    // merge halves
    float m2 = __shfl_xor(m, 32);
    float l2 = __shfl_xor(l, 32);
    float b0 = __shfl_xor(a0, 32);
    float b1 = __shfl_xor(a1, 32);
    float b2 = __shfl_xor(a2, 32);
    float b3 = __shfl_xor(a3, 32);
    float mm = fmaxf(m, m2);
    float cA = exp2f(m - mm);
    float cB = exp2f(m2 - mm);
    float L  = l * cA + l2 * cB;
    float A0 = a0 * cA + b0 * cB;
    float A1 = a1 * cA + b1 * cB;
    float A2 = a2 * cA + b2 * cB;
    float A3 = a3 * cA + b3 * cB;
    float invl = (L > 0.f) ? (1.0f / L) : 0.f;
    float o0 = A0 * invl, o1 = A1 * invl, o2 = A2 * invl, o3 = A3 * invl;

    ushort h0 = f2bf(o0), h1 = f2bf(o1), h2 = f2bf(o2), h3 = f2bf(o3);
    if (half == 0) {
        uint2 hv;
        hv.x = (unsigned int)h0 | ((unsigned int)h1 << 16);
        hv.y = (unsigned int)h2 | ((unsigned int)h3 << 16);
        ((uint2*)(aggh + (size_t)node * D))[sl] = hv;
    } else {
        ushort l0 = f2bf(o0 - bf2f(h0)), l1 = f2bf(o1 - bf2f(h1));
        ushort l2_ = f2bf(o2 - bf2f(h2)), l3 = f2bf(o3 - bf2f(h3));
        uint2 lv;
        lv.x = (unsigned int)l0 | ((unsigned int)l1 << 16);
        lv.y = (unsigned int)l2_ | ((unsigned int)l3 << 16);
        ((uint2*)(aggl + (size_t)node * D))[sl] = lv;
    }
}

// ---------------- oproj + LN1: h = LN(x + agg@Wo + bo) -> bf16 split --------

__global__ __launch_bounds__(256) void oproj_mfma_kernel(
    const ushort* __restrict__ aggh, const ushort* __restrict__ aggl,
    const float* __restrict__ x,
    const ushort* __restrict__ wth, const ushort* __restrict__ wtl,
    const float* __restrict__ bo, const float* __restrict__ g1,
    const float* __restrict__ be1,
    ushort* __restrict__ hh, ushort* __restrict__ hl, int n_rows)
{
    __shared__ __align__(16) ushort wbuf[16384];
    const int t = threadIdx.x;
    const int w = t >> 6, l = t & 63;
    const int l15 = l & 15, l4 = l >> 4;
    const int rowb = blockIdx.x * 64 + w * 16;
    const size_t abase = (size_t)(rowb + l15) * D + l4 * 8;

    bf16x8 ah[4], al[4];
    #pragma unroll
    for (int kk = 0; kk < 4; ++kk) {
        ah[kk] = *(const bf16x8*)(aggh + abase + kk * 32);
        al[kk] = *(const bf16x8*)(aggl + abase + kk * 32);
    }

    STAGE_W(wth, wbuf);
    __syncthreads();
    f32x4 acc[8];
    #pragma unroll
    for (int n = 0; n < 8; ++n) acc[n] = (f32x4){0.f, 0.f, 0.f, 0.f};
    #pragma unroll
    for (int kk = 0; kk < 4; ++kk) {
        #pragma unroll
        for (int n = 0; n < 8; ++n) {
            int rn = n * 16 + l15;
            bf16x8 bh = *(const bf16x8*)(wbuf + WOFF(rn, kk));
            acc[n] = __builtin_amdgcn_mfma_f32_16x16x32_bf16(ah[kk], bh, acc[n], 0, 0, 0);
            acc[n] = __builtin_amdgcn_mfma_f32_16x16x32_bf16(al[kk], bh, acc[n], 0, 0, 0);
        }
    }
    __syncthreads();
    STAGE_W(wtl, wbuf);
    __syncthreads();
    #pragma unroll
    for (int kk = 0; kk < 4; ++kk) {
        #pragma unroll
        for (int n = 0; n < 8; ++n) {
            int rn = n * 16 + l15;
            bf16x8 bl = *(const bf16x8*)(wbuf + WOFF(rn, kk));
            acc[n] = __builtin_amdgcn_mfma_f32_16x16x32_bf16(ah[kk], bl, acc[n], 0, 0, 0);
        }
    }

    float vals[8][4];
    #pragma unroll
    for (int n = 0; n < 8; ++n) {
        int col = n * 16 + l15;
        float bsv = bo[col];
        #pragma unroll
        for (int r = 0; r < 4; ++r) {
            int row = rowb + l4 * 4 + r;
            float xr = (row < n_rows) ? x[(size_t)row * D + col] : 0.f;
            vals[n][r] = acc[n][r] + bsv + xr;
        }
    }
    #pragma unroll
    for (int r = 0; r < 4; ++r) {
        int row = rowb + l4 * 4 + r;
        float s = 0.f, ss = 0.f;
        #pragma unroll
        for (int n = 0; n < 8; ++n) { s += vals[n][r]; ss += vals[n][r] * vals[n][r]; }
        #pragma unroll
        for (int msk = 1; msk <= 8; msk <<= 1) {
            s += __shfl_xor(s, msk);
            ss += __shfl_xor(ss, msk);
        }
        float mean = s * (1.0f / D);
        float var = ss * (1.0f / D) - mean * mean;
        float inv = rsqrtf(var + 1e-5f);
        if (row < n_rows) {
            #pragma unroll
            for (int n = 0; n < 8; ++n) {
                int col = n * 16 + l15;
                float y = (vals[n][r] - mean) * inv * g1[col] + be1[col];
                ushort hb = f2bf(y);
                hh[(size_t)row * D + col] = hb;
                hl[(size_t)row * D + col] = f2bf(y - bf2f(hb));
            }
        }
    }
}

// ---------------- FFN + LN2: out = LN(h + relu(h@W1+b1)@W2 + b2) ------------

__global__ __launch_bounds__(256) void ffn_mfma_kernel(
    const ushort* __restrict__ hh, const ushort* __restrict__ hl,
    const ushort* __restrict__ w1th, const ushort* __restrict__ w1tl,
    const ushort* __restrict__ w2th, const ushort* __restrict__ w2tl,
    const float* __restrict__ bb1, const float* __restrict__ bb2,
    const float* __restrict__ g2, const float* __restrict__ be2,
    float* __restrict__ out, int n_rows)
{
    __shared__ __align__(16) ushort wbuf[16384];
    __shared__ __align__(16) ushort tsh[64][136];
    __shared__ __align__(16) ushort tsl[64][136];
    const int t = threadIdx.x;
    const int w = t >> 6, l = t & 63;
    const int l15 = l & 15, l4 = l >> 4;
    const int rowb = blockIdx.x * 64 + w * 16;
    const size_t abase = (size_t)(rowb + l15) * D + l4 * 8;

    // ---- phase 1: t = relu(h@W1 + bb1) -> LDS (split bf16) ----
    {
        bf16x8 ah[4], al[4];
        #pragma unroll
        for (int kk = 0; kk < 4; ++kk) {
            ah[kk] = *(const bf16x8*)(hh + abase + kk * 32);
            al[kk] = *(const bf16x8*)(hl + abase + kk * 32);
        }
        STAGE_W(w1th, wbuf);
        __syncthreads();
        f32x4 acc[8];
        #pragma unroll
        for (int n = 0; n < 8; ++n) acc[n] = (f32x4){0.f, 0.f, 0.f, 0.f};
        #pragma unroll
        for (int kk = 0; kk < 4; ++kk) {
            #pragma unroll
            for (int n = 0; n < 8; ++n) {
                int rn = n * 16 + l15;
                bf16x8 bh = *(const bf16x8*)(wbuf + WOFF(rn, kk));
                acc[n] = __builtin_amdgcn_mfma_f32_16x16x32_bf16(ah[kk], bh, acc[n], 0, 0, 0);
                acc[n] = __builtin_amdgcn_mfma_f32_16x16x32_bf16(al[kk], bh, acc[n], 0, 0, 0);
            }
        }
        __syncthreads();
        STAGE_W(w1tl, wbuf);
        __syncthreads();
        #pragma unroll
        for (int kk = 0; kk < 4; ++kk) {
            #pragma unroll
            for (int n = 0; n < 8; ++n) {
                int rn = n * 16 + l15;
                bf16x8 bl = *(const bf16x8*)(wbuf + WOFF(rn, kk));
                acc[n] = __builtin_amdgcn_mfma_f32_16x16x32_bf16(ah[kk], bl, acc[n], 0, 0, 0);
            }
        }
        #pragma unroll
        for (int n = 0; n < 8; ++n) {
            int col = n * 16 + l15;
            float bsv = bb1[col];
            #pragma unroll
            for (int r = 0; r < 4; ++r) {
                int lrow = w * 16 + l4 * 4 + r;
                float tv = fmaxf(acc[n][r] + bsv, 0.f);
                ushort hb = f2bf(tv);
                tsh[lrow][col] = hb;
                tsl[lrow][col] = f2bf(tv - bf2f(hb));
            }
        }
    }
    __syncthreads();   // t visible; all W1 reads done

    // ---- phase 2: y = t@W2 + bb2; residual h; LN ----
    STAGE_W(w2th, wbuf);
    __syncthreads();
    bf16x8 ah2[4], al2[4];
    #pragma unroll
    for (int kk = 0; kk < 4; ++kk) {
        ah2[kk] = *(const bf16x8*)&tsh[w * 16 + l15][l4 * 8 + kk * 32];
        al2[kk] = *(const bf16x8*)&tsl[w * 16 + l15][l4 * 8 + kk * 32];
    }
    f32x4 acc[8];
    #pragma unroll
    for (int n = 0; n < 8; ++n) acc[n] = (f32x4){0.f, 0.f, 0.f, 0.f};
    #pragma unroll
    for (int kk = 0; kk < 4; ++kk) {
        #pragma unroll
        for (int n = 0; n < 8; ++n) {
            int rn = n * 16 + l15;
            bf16x8 bh = *(const bf16x8*)(wbuf + WOFF(rn, kk));
            acc[n] = __builtin_amdgcn_mfma_f32_16x16x32_bf16(ah2[kk], bh, acc[n], 0, 0, 0);
            acc[n] = __builtin_amdgcn_mfma_f32_16x16x32_bf16(al2[kk], bh, acc[n], 0, 0, 0);
        }
    }
    __syncthreads();
    STAGE_W(w2tl, wbuf);
    __syncthreads();
    #pragma unroll
    for (int kk = 0; kk < 4; ++kk) {
        #pragma unroll
        for (int n = 0; n < 8; ++n) {
            int rn = n * 16 + l15;
            bf16x8 bl = *(const bf16x8*)(wbuf + WOFF(rn, kk));
            acc[n] = __builtin_amdgcn_mfma_f32_16x16x32_bf16(ah2[kk], bl, acc[n], 0, 0, 0);
        }
    }

    float vals[8][4];
    #pragma unroll
    for (int n = 0; n < 8; ++n) {
        int col = n * 16 + l15;
        float bsv = bb2[col];
        #pragma unroll
        for (int r = 0; r < 4; ++r) {
            int row = rowb + l4 * 4 + r;
            float hr = 0.f;
            if (row < n_rows)
                hr = bf2f(hh[(size_t)row * D + col]) + bf2f(hl[(size_t)row * D + col]);
            vals[n][r] = acc[n][r] + bsv + hr;
        }
    }
    #pragma unroll
    for (int r = 0; r < 4; ++r) {
        int row = rowb + l4 * 4 + r;
        float s = 0.f, ss = 0.f;
        #pragma unroll
        for (int n = 0; n < 8; ++n) { s += vals[n][r]; ss += vals[n][r] * vals[n][r]; }
        #pragma unroll
        for (int msk = 1; msk <= 8; msk <<= 1) {
            s += __shfl_xor(s, msk);
            ss += __shfl_xor(ss, msk);
        }
        float mean = s * (1.0f / D);
        float var = ss * (1.0f / D) - mean * mean;
        float inv = rsqrtf(var + 1e-5f);
        if (row < n_rows) {
            #pragma unroll
            for (int n = 0; n < 8; ++n) {
                int col = n * 16 + l15;
                out[(size_t)row * D + col] = (vals[n][r] - mean) * inv * g2[col] + be2[col];
            }
        }
    }
}

// ---------------- launch ----------------

extern "C" void kernel_launch(void* const* d_in, const int* in_sizes, int n_in,
                              void* d_out, int out_size, void* d_ws, size_t ws_size,
                              hipStream_t stream) {
    const float* x     = (const float*)d_in[0];
    const int*   idx_i = (const int*)d_in[1];
    const int*   idx_j = (const int*)d_in[2];
    const float* Wq = (const float*)d_in[3];
    const float* bq = (const float*)d_in[4];
    const float* Wk = (const float*)d_in[5];
    const float* bk = (const float*)d_in[6];
    const float* Wv = (const float*)d_in[7];
    const float* bv = (const float*)d_in[8];
    const float* Wo = (const float*)d_in[9];
    const float* bo = (const float*)d_in[10];
    const float* g1 = (const float*)d_in[11];
    const float* be1 = (const float*)d_in[12];
    const float* W1 = (const float*)d_in[13];
    const float* bb1 = (const float*)d_in[14];
    const float* W2 = (const float*)d_in[15];
    const float* bb2 = (const float*)d_in[16];
    const float* g2 = (const float*)d_in[17];
    const float* be2 = (const float*)d_in[18];

    const int N_ = in_sizes[0] / D;
    const int E_ = in_sizes[1];
    const size_t ND = (size_t)N_ * D;
    const int nb = (N_ + SCAN_CHUNK - 1) / SCAN_CHUNK;   // 49 for N=50000 (<=64 required)

    float* ws = (float*)d_ws;
    float* q = ws;                         // ND f32 (later reused as hh/hl bf16 split)
    ushort* k16 = (ushort*)(q + ND);       // ND bf16
    ushort* v16 = k16 + ND;                // ND bf16
    int* count     = (int*)(v16 + ND);     // N
    int* row_start = count + N_;           // N+1
    int* cursor    = row_start + N_ + 1;   // N
    int* bsum      = cursor + N_;          // 64
    int* ejs       = bsum + 64;            // E
    ushort* xh = (ushort*)(ejs + E_);      // ND bf16 (later reused as aggh)
    ushort* xl = xh + ND;                  // ND bf16 (later reused as aggl)
    ushort* wth = xl + ND;                 // 6*128*128
    ushort* wtl = wth + 6 * 16384;         // 6*128*128
    ushort* aggh = xh;
    ushort* aggl = xl;
    ushort* hh = (ushort*)q;
    ushort* hl = hh + ND;

    zero_kernel<<<(N_ + 255) / 256, 256, 0, stream>>>(count, N_);
    prep_x_kernel<<<((int)(ND / 4) + 255) / 256, 256, 0, stream>>>(x, xh, xl, (int)(ND / 4));
    prep_w_kernel<<<6, 256, 0, stream>>>(Wq, Wk, Wv, Wo, W1, W2, wth, wtl);
    qkv_mfma_kernel<<<(N_ + 63) / 64, 256, 0, stream>>>(xh, xl, wth, wtl,
                                                        bq, bk, bv, q, k16, v16, N_);
    hist_kernel<<<(E_ + 255) / 256, 256, 0, stream>>>(idx_i, count, E_);
    scan_reduce_kernel<<<nb, 256, 0, stream>>>(count, bsum, N_);
    scan_bsum_kernel<<<1, 64, 0, stream>>>(bsum, row_start, nb, N_);
    scan_write_kernel<<<nb, 256, 0, stream>>>(count, bsum, row_start, cursor, N_);
    scatter_kernel<<<(E_ + 255) / 256, 256, 0, stream>>>(idx_i, idx_j, cursor, ejs, E_);
    fused_agg_kernel<<<(N_ + 3) / 4, 256, 0, stream>>>(q, k16, v16, row_start, ejs,
                                                       aggh, aggl, N_);
    oproj_mfma_kernel<<<(N_ + 63) / 64, 256, 0, stream>>>(aggh, aggl, x,
                                                          wth + 3 * 16384, wtl + 3 * 16384,
                                                          bo, g1, be1, hh, hl, N_);
    ffn_mfma_kernel<<<(N_ + 63) / 64, 256, 0, stream>>>(hh, hl,
                                                        wth + 4 * 16384, wtl + 4 * 16384,
                                                        wth + 5 * 16384, wtl + 5 * 16384,
                                                        bb1, bb2, g2, be2,
                                                        (float*)d_out, N_);
}

// Round 11
// 291.750 us; speedup vs baseline: 6.4040x; 1.0600x over previous
//
#include <hip/hip_runtime.h>
#include <hip/hip_bf16.h>
#include <math.h>

#define D 128
#define H 8
#define DH 16
#define SCAN_CHUNK 1024

typedef __attribute__((ext_vector_type(8))) short bf16x8;
typedef __attribute__((ext_vector_type(4))) float f32x4;

__device__ __forceinline__ float bf2f(ushort u) {
    unsigned int x = ((unsigned int)u) << 16;
    float f;
    __builtin_memcpy(&f, &x, 4);
    return f;
}
__device__ __forceinline__ ushort f2bf(float f) {
    __hip_bfloat16 h = __float2bfloat16(f);
    ushort u;
    __builtin_memcpy(&u, &h, 2);
    return u;
}

// Stage a 128x128 bf16 matrix (32KB) global -> LDS, XOR-swizzled 16B slots.
#define STAGE_W(SRC, LDSBUF)                                              \
    {                                                                      \
        _Pragma("unroll")                                                  \
        for (int it_ = 0; it_ < 8; ++it_) {                                \
            int idx16_ = t + it_ * 256;                                    \
            int row_ = idx16_ >> 4, c16_ = idx16_ & 15;                    \
            int d_ = (row_ << 7) + ((c16_ ^ (row_ & 7)) << 3);             \
            *(bf16x8*)((LDSBUF) + d_) = *(const bf16x8*)((SRC) + idx16_ * 8); \
        }                                                                  \
    }

// Swizzled LDS read offset (rn = B-row/out-col, kk = K-chunk); uses l4.
#define WOFF(rn, kk) (((rn) << 7) + ((((l4) + (kk) * 4) ^ ((rn) & 7)) << 3))

#define LOAD_A(SRCH, SRCL, BASE, AH, AL)                                   \
    _Pragma("unroll")                                                      \
    for (int kk_ = 0; kk_ < 4; ++kk_) {                                    \
        AH[kk_] = *(const bf16x8*)((SRCH) + (BASE) + kk_ * 32);            \
        AL[kk_] = *(const bf16x8*)((SRCL) + (BASE) + kk_ * 32);            \
    }

// 32-rows-per-wave MFMA tile: acc0 = rows base..+15, acc1 = rows base+16..+31
#define TILE_MFMA(AH0, AL0, AH1, AL1, WH, WL, ACC0, ACC1)                  \
    _Pragma("unroll")                                                      \
    for (int kk = 0; kk < 4; ++kk) {                                       \
        _Pragma("unroll")                                                  \
        for (int n = 0; n < 8; ++n) {                                      \
            int rn = n * 16 + l15;                                         \
            bf16x8 bh = *(const bf16x8*)((WH) + WOFF(rn, kk));             \
            bf16x8 bl = *(const bf16x8*)((WL) + WOFF(rn, kk));             \
            ACC0[n] = __builtin_amdgcn_mfma_f32_16x16x32_bf16(AH0[kk], bh, ACC0[n], 0, 0, 0); \
            ACC0[n] = __builtin_amdgcn_mfma_f32_16x16x32_bf16(AL0[kk], bh, ACC0[n], 0, 0, 0); \
            ACC0[n] = __builtin_amdgcn_mfma_f32_16x16x32_bf16(AH0[kk], bl, ACC0[n], 0, 0, 0); \
            ACC1[n] = __builtin_amdgcn_mfma_f32_16x16x32_bf16(AH1[kk], bh, ACC1[n], 0, 0, 0); \
            ACC1[n] = __builtin_amdgcn_mfma_f32_16x16x32_bf16(AL1[kk], bh, ACC1[n], 0, 0, 0); \
            ACC1[n] = __builtin_amdgcn_mfma_f32_16x16x32_bf16(AH1[kk], bl, ACC1[n], 0, 0, 0); \
        }                                                                  \
    }

// ---------------- K0: zero histogram ----------------

__global__ __launch_bounds__(256) void zero_kernel(int* __restrict__ count, int n) {
    int gid = blockIdx.x * blockDim.x + threadIdx.x;
    if (gid < n) count[gid] = 0;
}

// ---------------- prep_x: split x into bf16 hi/lo ----------------

__global__ __launch_bounds__(256) void prep_x_kernel(
    const float* __restrict__ x, ushort* __restrict__ xh, ushort* __restrict__ xl,
    int total4)
{
    int gid = blockIdx.x * blockDim.x + threadIdx.x;
    if (gid >= total4) return;
    float4 v = ((const float4*)x)[gid];
    ushort4 hv, lv;
    hv.x = f2bf(v.x); lv.x = f2bf(v.x - bf2f(hv.x));
    hv.y = f2bf(v.y); lv.y = f2bf(v.y - bf2f(hv.y));
    hv.z = f2bf(v.z); lv.z = f2bf(v.z - bf2f(hv.z));
    hv.w = f2bf(v.w); lv.w = f2bf(v.w - bf2f(hv.w));
    ((ushort4*)xh)[gid] = hv;
    ((ushort4*)xl)[gid] = lv;
}

// ---------------- prep_w: transpose + split 6 weight matrices ----------------

__global__ __launch_bounds__(256) void prep_w_kernel(
    const float* __restrict__ w0, const float* __restrict__ w1,
    const float* __restrict__ w2, const float* __restrict__ w3,
    const float* __restrict__ w4, const float* __restrict__ w5,
    ushort* __restrict__ wth, ushort* __restrict__ wtl)
{
    __shared__ __align__(16) float tile[128][132];
    const int m = blockIdx.x;
    const float* W = (m == 0) ? w0 : (m == 1) ? w1 : (m == 2) ? w2
                   : (m == 3) ? w3 : (m == 4) ? w4 : w5;
    const int t = threadIdx.x;
    const float4* wg = (const float4*)W;
    #pragma unroll
    for (int it = 0; it < 16; ++it) {
        int f4 = t + it * 256;
        int k = f4 >> 5, c4 = f4 & 31;
        *((float4*)&tile[k][c4 * 4]) = wg[f4];
    }
    __syncthreads();
    ushort* oh = wth + m * 16384;
    ushort* ol = wtl + m * 16384;
    #pragma unroll
    for (int it = 0; it < 64; ++it) {
        int idx = t + it * 256;
        int c = idx >> 7, k = idx & 127;
        float v = tile[k][c];
        ushort hb = f2bf(v);
        oh[idx] = hb;
        ol[idx] = f2bf(v - bf2f(hb));
    }
}

// ---------------- qkv: persistent W in LDS, barrier-free tile loop ----------
// grid (Gx, 3): blockIdx.y = matrix. 128-row tiles, 32 rows/wave.

__global__ __launch_bounds__(256) void gemm_qkv_kernel(
    const ushort* __restrict__ xh, const ushort* __restrict__ xl,
    const ushort* __restrict__ wth, const ushort* __restrict__ wtl,
    const float* __restrict__ bq, const float* __restrict__ bk,
    const float* __restrict__ bv,
    float* __restrict__ q, ushort* __restrict__ k16, ushort* __restrict__ v16,
    int n_rows)
{
    __shared__ __align__(16) ushort wh[16384];
    __shared__ __align__(16) ushort wl[16384];
    const int t = threadIdx.x;
    const int w = t >> 6, l = t & 63;
    const int l15 = l & 15, l4 = l >> 4;
    const int m = blockIdx.y;

    STAGE_W(wth + m * 16384, wh);
    STAGE_W(wtl + m * 16384, wl);

    const float* bias = (m == 0) ? bq : (m == 1) ? bk : bv;
    float bsv[8];
    #pragma unroll
    for (int n = 0; n < 8; ++n) bsv[n] = bias[n * 16 + l15];
    __syncthreads();

    const int ntiles = (n_rows + 127) >> 7;
    for (int tile = blockIdx.x; tile < ntiles; tile += gridDim.x) {
        const int rowb = tile * 128 + w * 32;
        const size_t a0 = (size_t)(rowb + l15) * D + l4 * 8;
        bf16x8 ah0[4], al0[4], ah1[4], al1[4];
        LOAD_A(xh, xl, a0, ah0, al0);
        LOAD_A(xh, xl, a0 + 16 * D, ah1, al1);
        f32x4 acc0[8], acc1[8];
        #pragma unroll
        for (int n = 0; n < 8; ++n) {
            acc0[n] = (f32x4){0.f, 0.f, 0.f, 0.f};
            acc1[n] = (f32x4){0.f, 0.f, 0.f, 0.f};
        }
        TILE_MFMA(ah0, al0, ah1, al1, wh, wl, acc0, acc1);
        #pragma unroll
        for (int n = 0; n < 8; ++n) {
            int col = n * 16 + l15;
            #pragma unroll
            for (int r = 0; r < 4; ++r) {
                int row0 = rowb + l4 * 4 + r;
                int row1 = row0 + 16;
                if (row0 < n_rows) {
                    float val = acc0[n][r] + bsv[n];
                    if (m == 0) q[(size_t)row0 * D + col] = val;
                    else if (m == 1) k16[(size_t)row0 * D + col] = f2bf(val);
                    else v16[(size_t)row0 * D + col] = f2bf(val);
                }
                if (row1 < n_rows) {
                    float val = acc1[n][r] + bsv[n];
                    if (m == 0) q[(size_t)row1 * D + col] = val;
                    else if (m == 1) k16[(size_t)row1 * D + col] = f2bf(val);
                    else v16[(size_t)row1 * D + col] = f2bf(val);
                }
            }
        }
    }
}

// ---------------- CSR build ----------------

__global__ __launch_bounds__(256) void hist_kernel(
    const int* __restrict__ idx_i, int* __restrict__ count, int n_edges)
{
    int e = blockIdx.x * blockDim.x + threadIdx.x;
    if (e < n_edges) atomicAdd(&count[idx_i[e]], 1);
}

__global__ __launch_bounds__(256) void scan_reduce_kernel(
    const int* __restrict__ count, int* __restrict__ bsum, int n)
{
    __shared__ int wsum[4];
    const int t = threadIdx.x, lane = t & 63, w = t >> 6;
    int base = blockIdx.x * SCAN_CHUNK + t * 4;
    int s = 0;
    #pragma unroll
    for (int i = 0; i < 4; ++i) {
        int idx = base + i;
        if (idx < n) s += count[idx];
    }
    #pragma unroll
    for (int off = 1; off < 64; off <<= 1) s += __shfl_xor(s, off);
    if (lane == 0) wsum[w] = s;
    __syncthreads();
    if (t == 0) bsum[blockIdx.x] = wsum[0] + wsum[1] + wsum[2] + wsum[3];
}

__global__ __launch_bounds__(64) void scan_bsum_kernel(
    int* __restrict__ bsum, int* __restrict__ row_start, int nb, int n)
{
    const int t = threadIdx.x;
    int iv = (t < nb) ? bsum[t] : 0;
    int vv = iv;
    #pragma unroll
    for (int off = 1; off < 64; off <<= 1) {
        int u = __shfl_up(vv, off);
        if (t >= off) vv += u;
    }
    if (t < nb) bsum[t] = vv - iv;     // exclusive
    if (t == 63) row_start[n] = vv;    // grand total
}

__global__ __launch_bounds__(256) void scan_write_kernel(
    const int* __restrict__ count, const int* __restrict__ bsum,
    int* __restrict__ row_start, int* __restrict__ cursor, int n)
{
    __shared__ int wtot[4];
    const int t = threadIdx.x, lane = t & 63, w = t >> 6;
    int base = blockIdx.x * SCAN_CHUNK + t * 4;
    int c0 = 0, c1 = 0, c2 = 0, c3 = 0;
    if (base + 0 < n) c0 = count[base + 0];
    if (base + 1 < n) c1 = count[base + 1];
    if (base + 2 < n) c2 = count[base + 2];
    if (base + 3 < n) c3 = count[base + 3];
    int tsum = c0 + c1 + c2 + c3;
    int inc = tsum;
    #pragma unroll
    for (int off = 1; off < 64; off <<= 1) {
        int u = __shfl_up(inc, off);
        if (lane >= off) inc += u;
    }
    if (lane == 63) wtot[w] = inc;
    __syncthreads();
    int wb = 0;
    for (int i = 0; i < w; ++i) wb += wtot[i];
    int start = bsum[blockIdx.x] + wb + inc - tsum;
    if (base + 0 < n) { row_start[base + 0] = start;            cursor[base + 0] = start; }
    if (base + 1 < n) { row_start[base + 1] = start + c0;       cursor[base + 1] = start + c0; }
    if (base + 2 < n) { row_start[base + 2] = start + c0 + c1;  cursor[base + 2] = start + c0 + c1; }
    if (base + 3 < n) { row_start[base + 3] = start + c0 + c1 + c2; cursor[base + 3] = start + c0 + c1 + c2; }
}

__global__ __launch_bounds__(256) void scatter_kernel(
    const int* __restrict__ idx_i, const int* __restrict__ idx_j,
    int* __restrict__ cursor, int* __restrict__ ejs, int n_edges)
{
    int e = blockIdx.x * blockDim.x + threadIdx.x;
    if (e < n_edges) {
        int i = idx_i[e];
        int pos = atomicAdd(&cursor[i], 1);
        ejs[pos] = idx_j[e];
    }
}

// ---------------- fused per-node attention (bf16 K/V, half-wave per edge) ----------------

__global__ __launch_bounds__(256) void fused_agg_kernel(
    const float* __restrict__ q, const ushort* __restrict__ k16,
    const ushort* __restrict__ v16, const int* __restrict__ row_start,
    const int* __restrict__ ejs,
    ushort* __restrict__ aggh, ushort* __restrict__ aggl, int n_nodes)
{
    const int lane = threadIdx.x & 63;
    const int node = (blockIdx.x * blockDim.x + threadIdx.x) >> 6;
    if (node >= n_nodes) return;
    const int beg = row_start[node], end = row_start[node + 1];
    const int half = lane >> 5, sl = lane & 31;
    const int c4 = sl * 4;

    if (beg >= end) {   // empty segment: agg row = 0
        if (half == 0) {
            ((uint2*)(aggh + (size_t)node * D))[sl] = make_uint2(0u, 0u);
            ((uint2*)(aggl + (size_t)node * D))[sl] = make_uint2(0u, 0u);
        }
        return;
    }

    const float4 qv = *(const float4*)&q[(size_t)node * D + c4];
    const float SC = 0.25f * 1.4426950408889634f;   // 1/sqrt(DH) * log2(e)
    float m = -INFINITY, l = 0.f;
    float a0 = 0.f, a1 = 0.f, a2 = 0.f, a3 = 0.f;

    int p = beg + half;
    uint2 kr0, vr0, kr1, vr1;
    if (p < end) {
        int j = ejs[p];
        kr0 = *(const uint2*)(k16 + (size_t)j * D + c4);
        vr0 = *(const uint2*)(v16 + (size_t)j * D + c4);
    }
    if (p + 2 < end) {
        int j = ejs[p + 2];
        kr1 = *(const uint2*)(k16 + (size_t)j * D + c4);
        vr1 = *(const uint2*)(v16 + (size_t)j * D + c4);
    }
    while (p < end) {
        uint2 kc = kr0, vc = vr0;
        kr0 = kr1; vr0 = vr1;
        if (p + 4 < end) {
            int j = ejs[p + 4];
            kr1 = *(const uint2*)(k16 + (size_t)j * D + c4);
            vr1 = *(const uint2*)(v16 + (size_t)j * D + c4);
        }
        float k0 = bf2f((ushort)kc.x), k1 = bf2f((ushort)(kc.x >> 16));
        float k2 = bf2f((ushort)kc.y), k3 = bf2f((ushort)(kc.y >> 16));
        float d = qv.x * k0 + qv.y * k1 + qv.z * k2 + qv.w * k3;
        d += __shfl_xor(d, 1);
        d += __shfl_xor(d, 2);
        float s = d * SC;
        float mn = fmaxf(m, s);
        float c  = exp2f(m - mn);      // first iter: exp2(-inf) = 0
        float pe = exp2f(s - mn);
        float v0 = bf2f((ushort)vc.x), v1 = bf2f((ushort)(vc.x >> 16));
        float v2 = bf2f((ushort)vc.y), v3 = bf2f((ushort)(vc.y >> 16));
        l  = l  * c + pe;
        a0 = a0 * c + pe * v0;
        a1 = a1 * c + pe * v1;
        a2 = a2 * c + pe * v2;
        a3 = a3 * c + pe * v3;
        m = mn;
        p += 2;
    }

    // merge halves
    float m2 = __shfl_xor(m, 32);
    float l2 = __shfl_xor(l, 32);
    float b0 = __shfl_xor(a0, 32);
    float b1 = __shfl_xor(a1, 32);
    float b2 = __shfl_xor(a2, 32);
    float b3 = __shfl_xor(a3, 32);
    float mm = fmaxf(m, m2);
    float cA = exp2f(m - mm);
    float cB = exp2f(m2 - mm);
    float L  = l * cA + l2 * cB;
    float A0 = a0 * cA + b0 * cB;
    float A1 = a1 * cA + b1 * cB;
    float A2 = a2 * cA + b2 * cB;
    float A3 = a3 * cA + b3 * cB;
    float invl = (L > 0.f) ? (1.0f / L) : 0.f;
    float o0 = A0 * invl, o1 = A1 * invl, o2 = A2 * invl, o3 = A3 * invl;

    ushort h0 = f2bf(o0), h1 = f2bf(o1), h2 = f2bf(o2), h3 = f2bf(o3);
    if (half == 0) {
        uint2 hv;
        hv.x = (unsigned int)h0 | ((unsigned int)h1 << 16);
        hv.y = (unsigned int)h2 | ((unsigned int)h3 << 16);
        ((uint2*)(aggh + (size_t)node * D))[sl] = hv;
    } else {
        ushort l0 = f2bf(o0 - bf2f(h0)), l1 = f2bf(o1 - bf2f(h1));
        ushort l2_ = f2bf(o2 - bf2f(h2)), l3 = f2bf(o3 - bf2f(h3));
        uint2 lv;
        lv.x = (unsigned int)l0 | ((unsigned int)l1 << 16);
        lv.y = (unsigned int)l2_ | ((unsigned int)l3 << 16);
        ((uint2*)(aggl + (size_t)node * D))[sl] = lv;
    }
}

// ---------------- oproj + LN1: persistent Wo; h = LN(x + agg@Wo + bo) -------

__global__ __launch_bounds__(256) void gemm_oproj_kernel(
    const ushort* __restrict__ aggh, const ushort* __restrict__ aggl,
    const float* __restrict__ x,
    const ushort* __restrict__ wth, const ushort* __restrict__ wtl,
    const float* __restrict__ bo, const float* __restrict__ g1,
    const float* __restrict__ be1,
    ushort* __restrict__ hh, ushort* __restrict__ hl, int n_rows)
{
    __shared__ __align__(16) ushort wh[16384];
    __shared__ __align__(16) ushort wl[16384];
    const int t = threadIdx.x;
    const int w = t >> 6, l = t & 63;
    const int l15 = l & 15, l4 = l >> 4;

    STAGE_W(wth, wh);
    STAGE_W(wtl, wl);
    float bsv[8], gv[8], bev[8];
    #pragma unroll
    for (int n = 0; n < 8; ++n) {
        int col = n * 16 + l15;
        bsv[n] = bo[col]; gv[n] = g1[col]; bev[n] = be1[col];
    }
    __syncthreads();

    const int ntiles = (n_rows + 127) >> 7;
    for (int tile = blockIdx.x; tile < ntiles; tile += gridDim.x) {
        const int rowb = tile * 128 + w * 32;
        const size_t a0 = (size_t)(rowb + l15) * D + l4 * 8;
        bf16x8 ah0[4], al0[4], ah1[4], al1[4];
        LOAD_A(aggh, aggl, a0, ah0, al0);
        LOAD_A(aggh, aggl, a0 + 16 * D, ah1, al1);
        f32x4 acc0[8], acc1[8];
        #pragma unroll
        for (int n = 0; n < 8; ++n) {
            acc0[n] = (f32x4){0.f, 0.f, 0.f, 0.f};
            acc1[n] = (f32x4){0.f, 0.f, 0.f, 0.f};
        }
        TILE_MFMA(ah0, al0, ah1, al1, wh, wl, acc0, acc1);
        // epilogue for both row groups
        #pragma unroll
        for (int g = 0; g < 2; ++g) {
            f32x4* acc = g ? acc1 : acc0;
            int rbase = rowb + g * 16;
            float vals[8][4];
            #pragma unroll
            for (int n = 0; n < 8; ++n) {
                int col = n * 16 + l15;
                #pragma unroll
                for (int r = 0; r < 4; ++r) {
                    int row = rbase + l4 * 4 + r;
                    float xr = (row < n_rows) ? x[(size_t)row * D + col] : 0.f;
                    vals[n][r] = acc[n][r] + bsv[n] + xr;
                }
            }
            #pragma unroll
            for (int r = 0; r < 4; ++r) {
                int row = rbase + l4 * 4 + r;
                float s = 0.f, ss = 0.f;
                #pragma unroll
                for (int n = 0; n < 8; ++n) { s += vals[n][r]; ss += vals[n][r] * vals[n][r]; }
                #pragma unroll
                for (int msk = 1; msk <= 8; msk <<= 1) {
                    s += __shfl_xor(s, msk);
                    ss += __shfl_xor(ss, msk);
                }
                float mean = s * (1.0f / D);
                float var = ss * (1.0f / D) - mean * mean;
                float inv = rsqrtf(var + 1e-5f);
                if (row < n_rows) {
                    #pragma unroll
                    for (int n = 0; n < 8; ++n) {
                        int col = n * 16 + l15;
                        float y = (vals[n][r] - mean) * inv * gv[n] + bev[n];
                        ushort hb = f2bf(y);
                        hh[(size_t)row * D + col] = hb;
                        hl[(size_t)row * D + col] = f2bf(y - bf2f(hb));
                    }
                }
            }
        }
    }
}

// ---------------- ffn1: t = relu(h@W1 + b1) -> th/tl (bf16 split) -----------

__global__ __launch_bounds__(256) void gemm_ffn1_kernel(
    const ushort* __restrict__ hh, const ushort* __restrict__ hl,
    const ushort* __restrict__ wth, const ushort* __restrict__ wtl,
    const float* __restrict__ bb1,
    ushort* __restrict__ th, ushort* __restrict__ tl, int n_rows)
{
    __shared__ __align__(16) ushort wh[16384];
    __shared__ __align__(16) ushort wl[16384];
    const int t = threadIdx.x;
    const int w = t >> 6, l = t & 63;
    const int l15 = l & 15, l4 = l >> 4;

    STAGE_W(wth, wh);
    STAGE_W(wtl, wl);
    float bsv[8];
    #pragma unroll
    for (int n = 0; n < 8; ++n) bsv[n] = bb1[n * 16 + l15];
    __syncthreads();

    const int ntiles = (n_rows + 127) >> 7;
    for (int tile = blockIdx.x; tile < ntiles; tile += gridDim.x) {
        const int rowb = tile * 128 + w * 32;
        const size_t a0 = (size_t)(rowb + l15) * D + l4 * 8;
        bf16x8 ah0[4], al0[4], ah1[4], al1[4];
        LOAD_A(hh, hl, a0, ah0, al0);
        LOAD_A(hh, hl, a0 + 16 * D, ah1, al1);
        f32x4 acc0[8], acc1[8];
        #pragma unroll
        for (int n = 0; n < 8; ++n) {
            acc0[n] = (f32x4){0.f, 0.f, 0.f, 0.f};
            acc1[n] = (f32x4){0.f, 0.f, 0.f, 0.f};
        }
        TILE_MFMA(ah0, al0, ah1, al1, wh, wl, acc0, acc1);
        #pragma unroll
        for (int n = 0; n < 8; ++n) {
            int col = n * 16 + l15;
            #pragma unroll
            for (int r = 0; r < 4; ++r) {
                int row0 = rowb + l4 * 4 + r;
                int row1 = row0 + 16;
                if (row0 < n_rows) {
                    float tv = fmaxf(acc0[n][r] + bsv[n], 0.f);
                    ushort hb = f2bf(tv);
                    th[(size_t)row0 * D + col] = hb;
                    tl[(size_t)row0 * D + col] = f2bf(tv - bf2f(hb));
                }
                if (row1 < n_rows) {
                    float tv = fmaxf(acc1[n][r] + bsv[n], 0.f);
                    ushort hb = f2bf(tv);
                    th[(size_t)row1 * D + col] = hb;
                    tl[(size_t)row1 * D + col] = f2bf(tv - bf2f(hb));
                }
            }
        }
    }
}

// ---------------- ffn2: out = LN(h + t@W2 + b2) -----------------------------

__global__ __launch_bounds__(256) void gemm_ffn2_kernel(
    const ushort* __restrict__ th, const ushort* __restrict__ tl,
    const ushort* __restrict__ hh, const ushort* __restrict__ hl,
    const ushort* __restrict__ wth, const ushort* __restrict__ wtl,
    const float* __restrict__ bb2, const float* __restrict__ g2,
    const float* __restrict__ be2,
    float* __restrict__ out, int n_rows)
{
    __shared__ __align__(16) ushort wh[16384];
    __shared__ __align__(16) ushort wl[16384];
    const int t = threadIdx.x;
    const int w = t >> 6, l = t & 63;
    const int l15 = l & 15, l4 = l >> 4;

    STAGE_W(wth, wh);
    STAGE_W(wtl, wl);
    float bsv[8], gv[8], bev[8];
    #pragma unroll
    for (int n = 0; n < 8; ++n) {
        int col = n * 16 + l15;
        bsv[n] = bb2[col]; gv[n] = g2[col]; bev[n] = be2[col];
    }
    __syncthreads();

    const int ntiles = (n_rows + 127) >> 7;
    for (int tile = blockIdx.x; tile < ntiles; tile += gridDim.x) {
        const int rowb = tile * 128 + w * 32;
        const size_t a0 = (size_t)(rowb + l15) * D + l4 * 8;
        bf16x8 ah0[4], al0[4], ah1[4], al1[4];
        LOAD_A(th, tl, a0, ah0, al0);
        LOAD_A(th, tl, a0 + 16 * D, ah1, al1);
        f32x4 acc0[8], acc1[8];
        #pragma unroll
        for (int n = 0; n < 8; ++n) {
            acc0[n] = (f32x4){0.f, 0.f, 0.f, 0.f};
            acc1[n] = (f32x4){0.f, 0.f, 0.f, 0.f};
        }
        TILE_MFMA(ah0, al0, ah1, al1, wh, wl, acc0, acc1);
        #pragma unroll
        for (int g = 0; g < 2; ++g) {
            f32x4* acc = g ? acc1 : acc0;
            int rbase = rowb + g * 16;
            float vals[8][4];
            #pragma unroll
            for (int n = 0; n < 8; ++n) {
                int col = n * 16 + l15;
                #pragma unroll
                for (int r = 0; r < 4; ++r) {
                    int row = rbase + l4 * 4 + r;
                    float hr = 0.f;
                    if (row < n_rows)
                        hr = bf2f(hh[(size_t)row * D + col]) + bf2f(hl[(size_t)row * D + col]);
                    vals[n][r] = acc[n][r] + bsv[n] + hr;
                }
            }
            #pragma unroll
            for (int r = 0; r < 4; ++r) {
                int row = rbase + l4 * 4 + r;
                float s = 0.f, ss = 0.f;
                #pragma unroll
                for (int n = 0; n < 8; ++n) { s += vals[n][r]; ss += vals[n][r] * vals[n][r]; }
                #pragma unroll
                for (int msk = 1; msk <= 8; msk <<= 1) {
                    s += __shfl_xor(s, msk);
                    ss += __shfl_xor(ss, msk);
                }
                float mean = s * (1.0f / D);
                float var = ss * (1.0f / D) - mean * mean;
                float inv = rsqrtf(var + 1e-5f);
                if (row < n_rows) {
                    #pragma unroll
                    for (int n = 0; n < 8; ++n) {
                        int col = n * 16 + l15;
                        out[(size_t)row * D + col] = (vals[n][r] - mean) * inv * gv[n] + bev[n];
                    }
                }
            }
        }
    }
}

// ---------------- launch ----------------

extern "C" void kernel_launch(void* const* d_in, const int* in_sizes, int n_in,
                              void* d_out, int out_size, void* d_ws, size_t ws_size,
                              hipStream_t stream) {
    const float* x     = (const float*)d_in[0];
    const int*   idx_i = (const int*)d_in[1];
    const int*   idx_j = (const int*)d_in[2];
    const float* Wq = (const float*)d_in[3];
    const float* bq = (const float*)d_in[4];
    const float* Wk = (const float*)d_in[5];
    const float* bk = (const float*)d_in[6];
    const float* Wv = (const float*)d_in[7];
    const float* bv = (const float*)d_in[8];
    const float* Wo = (const float*)d_in[9];
    const float* bo = (const float*)d_in[10];
    const float* g1 = (const float*)d_in[11];
    const float* be1 = (const float*)d_in[12];
    const float* W1 = (const float*)d_in[13];
    const float* bb1 = (const float*)d_in[14];
    const float* W2 = (const float*)d_in[15];
    const float* bb2 = (const float*)d_in[16];
    const float* g2 = (const float*)d_in[17];
    const float* be2 = (const float*)d_in[18];

    const int N_ = in_sizes[0] / D;
    const int E_ = in_sizes[1];
    const size_t ND = (size_t)N_ * D;
    const int nb = (N_ + SCAN_CHUNK - 1) / SCAN_CHUNK;   // 49 for N=50000 (<=64 required)

    float* ws = (float*)d_ws;
    float* q = ws;                         // ND f32 (later reused as hh/hl bf16 split)
    ushort* k16 = (ushort*)(q + ND);       // ND bf16 (later reused as th)
    ushort* v16 = k16 + ND;                // ND bf16 (later reused as tl)
    int* count     = (int*)(v16 + ND);     // N
    int* row_start = count + N_;           // N+1
    int* cursor    = row_start + N_ + 1;   // N
    int* bsum      = cursor + N_;          // 64
    int* ejs       = bsum + 64;            // E
    ushort* xh = (ushort*)(ejs + E_);      // ND bf16 (later reused as aggh)
    ushort* xl = xh + ND;                  // ND bf16 (later reused as aggl)
    ushort* wth = xl + ND;                 // 6*128*128
    ushort* wtl = wth + 6 * 16384;         // 6*128*128
    ushort* aggh = xh;
    ushort* aggl = xl;
    ushort* hh = (ushort*)q;
    ushort* hl = hh + ND;
    ushort* th = k16;                      // k16/v16 dead after fused_agg
    ushort* tl = v16;

    zero_kernel<<<(N_ + 255) / 256, 256, 0, stream>>>(count, N_);
    prep_x_kernel<<<((int)(ND / 4) + 255) / 256, 256, 0, stream>>>(x, xh, xl, (int)(ND / 4));
    prep_w_kernel<<<6, 256, 0, stream>>>(Wq, Wk, Wv, Wo, W1, W2, wth, wtl);
    {
        dim3 g(171, 3);
        gemm_qkv_kernel<<<g, 256, 0, stream>>>(xh, xl, wth, wtl,
                                               bq, bk, bv, q, k16, v16, N_);
    }
    hist_kernel<<<(E_ + 255) / 256, 256, 0, stream>>>(idx_i, count, E_);
    scan_reduce_kernel<<<nb, 256, 0, stream>>>(count, bsum, N_);
    scan_bsum_kernel<<<1, 64, 0, stream>>>(bsum, row_start, nb, N_);
    scan_write_kernel<<<nb, 256, 0, stream>>>(count, bsum, row_start, cursor, N_);
    scatter_kernel<<<(E_ + 255) / 256, 256, 0, stream>>>(idx_i, idx_j, cursor, ejs, E_);
    fused_agg_kernel<<<(N_ + 3) / 4, 256, 0, stream>>>(q, k16, v16, row_start, ejs,
                                                       aggh, aggl, N_);
    gemm_oproj_kernel<<<196, 256, 0, stream>>>(aggh, aggl, x,
                                               wth + 3 * 16384, wtl + 3 * 16384,
                                               bo, g1, be1, hh, hl, N_);
    gemm_ffn1_kernel<<<196, 256, 0, stream>>>(hh, hl,
                                              wth + 4 * 16384, wtl + 4 * 16384,
                                              bb1, th, tl, N_);
    gemm_ffn2_kernel<<<196, 256, 0, stream>>>(th, tl, hh, hl,
                                              wth + 5 * 16384, wtl + 5 * 16384,
                                              bb2, g2, be2, (float*)d_out, N_);
}